// Round 1
// baseline (7085.150 us; speedup 1.0000x reference)
//
#include <hip/hip_runtime.h>
#include <math.h>

#define SM_EPS 1e-16f

typedef unsigned short u16;
typedef unsigned int u32;

__device__ __forceinline__ u16 f2bf(float x) {
  u32 u = __float_as_uint(x);
  u32 lsb = (u >> 16) & 1u;
  u += 0x7fffu + lsb;
  return (u16)(u >> 16);
}
__device__ __forceinline__ float bf2f(u16 u) {
  return __uint_as_float(((u32)u) << 16);
}

// ---------------- h1 = x @ W1   [M,512]@[512,128] -------------------
__global__ __launch_bounds__(256) void k_gemm1(const float* __restrict__ A,
                                               const float* __restrict__ B,
                                               float* __restrict__ C, int M) {
  __shared__ float As[16][136];
  __shared__ float Bs[16][128];
  const int tid = threadIdx.x;
  const int m0 = blockIdx.x * 128;
  const int tm = tid >> 4, tn = tid & 15;
  const int am = tid & 127;
  const int akq0 = tid >> 7;
  const int row = m0 + am;
  float acc[8][8];
#pragma unroll
  for (int i = 0; i < 8; ++i)
#pragma unroll
    for (int j = 0; j < 8; ++j) acc[i][j] = 0.f;

  for (int k0 = 0; k0 < 512; k0 += 16) {
#pragma unroll
    for (int t = 0; t < 2; ++t) {
      const int kq = akq0 + 2 * t;
      float4 v = make_float4(0.f, 0.f, 0.f, 0.f);
      if (row < M) v = *reinterpret_cast<const float4*>(&A[(size_t)row * 512 + k0 + kq * 4]);
      As[kq * 4 + 0][am] = v.x; As[kq * 4 + 1][am] = v.y;
      As[kq * 4 + 2][am] = v.z; As[kq * 4 + 3][am] = v.w;
    }
#pragma unroll
    for (int t = 0; t < 2; ++t) {
      const int s = tid + 256 * t;
      const int kk = s >> 5, n4 = s & 31;
      *reinterpret_cast<float4*>(&Bs[kk][n4 * 4]) =
          *reinterpret_cast<const float4*>(&B[(size_t)(k0 + kk) * 128 + n4 * 4]);
    }
    __syncthreads();
#pragma unroll
    for (int kk = 0; kk < 16; ++kk) {
      float a[8], b[8];
      *reinterpret_cast<float4*>(&a[0]) = *reinterpret_cast<const float4*>(&As[kk][tm * 8]);
      *reinterpret_cast<float4*>(&a[4]) = *reinterpret_cast<const float4*>(&As[kk][tm * 8 + 4]);
      *reinterpret_cast<float4*>(&b[0]) = *reinterpret_cast<const float4*>(&Bs[kk][tn * 8]);
      *reinterpret_cast<float4*>(&b[4]) = *reinterpret_cast<const float4*>(&Bs[kk][tn * 8 + 4]);
#pragma unroll
      for (int i = 0; i < 8; ++i)
#pragma unroll
        for (int j = 0; j < 8; ++j) acc[i][j] = fmaf(a[i], b[j], acc[i][j]);
    }
    __syncthreads();
  }
#pragma unroll
  for (int i = 0; i < 8; ++i) {
    const int r = m0 + tm * 8 + i;
    if (r < M) {
      *reinterpret_cast<float4*>(&C[(size_t)r * 128 + tn * 8]) =
          make_float4(acc[i][0], acc[i][1], acc[i][2], acc[i][3]);
      *reinterpret_cast<float4*>(&C[(size_t)r * 128 + tn * 8 + 4]) =
          make_float4(acc[i][4], acc[i][5], acc[i][6], acc[i][7]);
    }
  }
}

// ------------- fused 16->128->128 MLP over rows (edges or nodes) ----------
// MODE 0: edge path: logit -> exp -> store bf16 ew, atomicAdd s[src]
// MODE 1: pw path:   logit -> lrelu(0.01) -> store f32
template <int MODE>
__global__ __launch_bounds__(256) void k_mlp128(
    const float* __restrict__ inp, const int* __restrict__ srcIdx,
    const float* __restrict__ Wa, const float* __restrict__ Wb,
    const float* __restrict__ bbias, u16* __restrict__ ewOut,
    float* __restrict__ sAcc, float* __restrict__ pwOut, int R) {
  __shared__ float Wa_s[16][128];
  __shared__ float Ut[16][136];
  __shared__ float Wbt[16][128];
  const int tid = threadIdx.x;
  const int r0 = blockIdx.x * 128;
  const int m = tid & 127;
  const int half = tid >> 7;
  const int tm = tid >> 4, tn = tid & 15;

#pragma unroll
  for (int t = 0; t < 2; ++t) {
    const int s = tid + 256 * t;
    const int kk = s >> 5, n4 = s & 31;
    *reinterpret_cast<float4*>(&Wa_s[kk][n4 * 4]) =
        *reinterpret_cast<const float4*>(&Wa[(size_t)kk * 128 + n4 * 4]);
  }
  float kreg[16];
  {
    const int rr = r0 + m;
    if (rr < R) {
#pragma unroll
      for (int t = 0; t < 4; ++t)
        *reinterpret_cast<float4*>(&kreg[t * 4]) =
            *reinterpret_cast<const float4*>(&inp[(size_t)rr * 16 + t * 4]);
    } else {
#pragma unroll
      for (int j = 0; j < 16; ++j) kreg[j] = 0.f;
    }
  }
  float acc[8][8];
#pragma unroll
  for (int i = 0; i < 8; ++i)
#pragma unroll
    for (int j = 0; j < 8; ++j) acc[i][j] = 0.f;
  __syncthreads();  // Wa_s ready

  for (int c0 = 0; c0 < 128; c0 += 16) {
    // stage 1: U chunk (u-dims c0..c0+15), lrelu(0.2)
#pragma unroll
    for (int t = 0; t < 8; ++t) {
      const int kk = half + 2 * t;
      const int c = c0 + kk;
      float u = 0.f;
#pragma unroll
      for (int j = 0; j < 16; ++j) u = fmaf(kreg[j], Wa_s[j][c], u);
      u = (u >= 0.f) ? u : 0.2f * u;
      Ut[kk][m] = u;
    }
    // stream Wb rows c0..c0+15
#pragma unroll
    for (int t = 0; t < 2; ++t) {
      const int s = tid + 256 * t;
      const int kk = s >> 5, n4 = s & 31;
      *reinterpret_cast<float4*>(&Wbt[kk][n4 * 4]) =
          *reinterpret_cast<const float4*>(&Wb[(size_t)(c0 + kk) * 128 + n4 * 4]);
    }
    __syncthreads();
#pragma unroll
    for (int kk = 0; kk < 16; ++kk) {
      float a[8], b[8];
      *reinterpret_cast<float4*>(&a[0]) = *reinterpret_cast<const float4*>(&Ut[kk][tm * 8]);
      *reinterpret_cast<float4*>(&a[4]) = *reinterpret_cast<const float4*>(&Ut[kk][tm * 8 + 4]);
      *reinterpret_cast<float4*>(&b[0]) = *reinterpret_cast<const float4*>(&Wbt[kk][tn * 8]);
      *reinterpret_cast<float4*>(&b[4]) = *reinterpret_cast<const float4*>(&Wbt[kk][tn * 8 + 4]);
#pragma unroll
      for (int i = 0; i < 8; ++i)
#pragma unroll
        for (int j = 0; j < 8; ++j) acc[i][j] = fmaf(a[i], b[j], acc[i][j]);
    }
    __syncthreads();
  }

  float bv[8];
  *reinterpret_cast<float4*>(&bv[0]) = *reinterpret_cast<const float4*>(&bbias[tn * 8]);
  *reinterpret_cast<float4*>(&bv[4]) = *reinterpret_cast<const float4*>(&bbias[tn * 8 + 4]);
#pragma unroll
  for (int i = 0; i < 8; ++i) {
    const int r = r0 + tm * 8 + i;
    if (r >= R) continue;
    if (MODE == 0) {
      const int sn = srcIdx[r];
      float ex[8];
#pragma unroll
      for (int j = 0; j < 8; ++j) ex[j] = __expf(acc[i][j] + bv[j]);
      u32 pk[4];
#pragma unroll
      for (int j2 = 0; j2 < 4; ++j2)
        pk[j2] = (u32)f2bf(ex[2 * j2]) | ((u32)f2bf(ex[2 * j2 + 1]) << 16);
      *reinterpret_cast<uint4*>(&ewOut[(size_t)r * 128 + tn * 8]) =
          make_uint4(pk[0], pk[1], pk[2], pk[3]);
#pragma unroll
      for (int j = 0; j < 8; ++j)
        atomicAdd(&sAcc[(size_t)sn * 128 + tn * 8 + j], ex[j]);
    } else {
      float o[8];
#pragma unroll
      for (int j = 0; j < 8; ++j) {
        float v = acc[i][j] + bv[j];
        o[j] = (v >= 0.f) ? v : 0.01f * v;
      }
      *reinterpret_cast<float4*>(&pwOut[(size_t)r * 128 + tn * 8]) =
          make_float4(o[0], o[1], o[2], o[3]);
      *reinterpret_cast<float4*>(&pwOut[(size_t)r * 128 + tn * 8 + 4]) =
          make_float4(o[4], o[5], o[6], o[7]);
    }
  }
}

// ------------- fused 16->40->40 MLP, one row per thread ----------
template <int MODE>
__global__ __launch_bounds__(256) void k_mlp40(
    const float* __restrict__ inp, const int* __restrict__ srcIdx,
    const float* __restrict__ Wa, const float* __restrict__ Wb,
    const float* __restrict__ bbias, u16* __restrict__ ewOut,
    float* __restrict__ sAcc, float* __restrict__ pwOut, int R) {
  __shared__ float Wa_s[16 * 40];
  __shared__ float Wb_s[40 * 40];
  __shared__ float bb_s[40];
  const int tid = threadIdx.x;
  for (int i = tid; i < 640; i += 256) Wa_s[i] = Wa[i];
  for (int i = tid; i < 1600; i += 256) Wb_s[i] = Wb[i];
  if (tid < 40) bb_s[tid] = bbias[tid];
  __syncthreads();
  const int r = blockIdx.x * 256 + tid;
  if (r >= R) return;

  float kreg[16];
#pragma unroll
  for (int t = 0; t < 4; ++t)
    *reinterpret_cast<float4*>(&kreg[t * 4]) =
        *reinterpret_cast<const float4*>(&inp[(size_t)r * 16 + t * 4]);

  float u[40];
#pragma unroll
  for (int c = 0; c < 40; ++c) u[c] = 0.f;
#pragma unroll
  for (int j = 0; j < 16; ++j) {
    const float kj = kreg[j];
#pragma unroll
    for (int c4 = 0; c4 < 10; ++c4) {
      const float4 w = *reinterpret_cast<const float4*>(&Wa_s[j * 40 + c4 * 4]);
      u[c4 * 4 + 0] = fmaf(kj, w.x, u[c4 * 4 + 0]);
      u[c4 * 4 + 1] = fmaf(kj, w.y, u[c4 * 4 + 1]);
      u[c4 * 4 + 2] = fmaf(kj, w.z, u[c4 * 4 + 2]);
      u[c4 * 4 + 3] = fmaf(kj, w.w, u[c4 * 4 + 3]);
    }
  }
#pragma unroll
  for (int c = 0; c < 40; ++c) u[c] = (u[c] >= 0.f) ? u[c] : 0.2f * u[c];

  float o[40];
#pragma unroll
  for (int c = 0; c < 40; ++c) o[c] = bb_s[c];
#pragma unroll
  for (int j = 0; j < 40; ++j) {
    const float uj = u[j];
#pragma unroll
    for (int c4 = 0; c4 < 10; ++c4) {
      const float4 w = *reinterpret_cast<const float4*>(&Wb_s[j * 40 + c4 * 4]);
      o[c4 * 4 + 0] = fmaf(uj, w.x, o[c4 * 4 + 0]);
      o[c4 * 4 + 1] = fmaf(uj, w.y, o[c4 * 4 + 1]);
      o[c4 * 4 + 2] = fmaf(uj, w.z, o[c4 * 4 + 2]);
      o[c4 * 4 + 3] = fmaf(uj, w.w, o[c4 * 4 + 3]);
    }
  }
  if (MODE == 0) {
    const int sn = srcIdx[r];
#pragma unroll
    for (int c = 0; c < 40; ++c) o[c] = __expf(o[c]);
#pragma unroll
    for (int c2 = 0; c2 < 20; ++c2) {
      u32 pk = (u32)f2bf(o[2 * c2]) | ((u32)f2bf(o[2 * c2 + 1]) << 16);
      *reinterpret_cast<u32*>(&ewOut[(size_t)r * 40 + c2 * 2]) = pk;
    }
#pragma unroll
    for (int c = 0; c < 40; ++c) atomicAdd(&sAcc[(size_t)sn * 40 + c], o[c]);
  } else {
#pragma unroll
    for (int c = 0; c < 40; ++c) { float v = o[c]; o[c] = (v >= 0.f) ? v : 0.01f * v; }
#pragma unroll
    for (int c4 = 0; c4 < 10; ++c4)
      *reinterpret_cast<float4*>(&pwOut[(size_t)r * 40 + c4 * 4]) =
          make_float4(o[c4 * 4], o[c4 * 4 + 1], o[c4 * 4 + 2], o[c4 * 4 + 3]);
  }
}

// ------------- h2 = y1 @ W2  [M,128]@[128,40] ----------
__global__ __launch_bounds__(256) void k_gemm2(const float* __restrict__ A,
                                               const float* __restrict__ B,
                                               float* __restrict__ C, int M) {
  __shared__ float Bs[128 * 40];
  const int tid = threadIdx.x;
  for (int i = tid; i < 5120; i += 256) Bs[i] = B[i];
  __syncthreads();
  const int r = blockIdx.x * 6 + tid / 40;
  const int c = tid % 40;
  if (tid >= 240 || r >= M) return;
  const float* arow = &A[(size_t)r * 128];
  float acc = 0.f;
#pragma unroll
  for (int k4 = 0; k4 < 32; ++k4) {
    const float4 av = *reinterpret_cast<const float4*>(&arow[k4 * 4]);
    acc = fmaf(av.x, Bs[(k4 * 4 + 0) * 40 + c], acc);
    acc = fmaf(av.y, Bs[(k4 * 4 + 1) * 40 + c], acc);
    acc = fmaf(av.z, Bs[(k4 * 4 + 2) * 40 + c], acc);
    acc = fmaf(av.w, Bs[(k4 * 4 + 3) * 40 + c], acc);
  }
  C[(size_t)r * 40 + c] = acc;
}

// ------------- g = h / (s + eps), in place on h ----------
__global__ __launch_bounds__(256) void k_gdiv(float* __restrict__ h,
                                              const float* __restrict__ s, int total4) {
  const int i = blockIdx.x * 256 + threadIdx.x;
  if (i >= total4) return;
  float4 hv = reinterpret_cast<float4*>(h)[i];
  const float4 sv = reinterpret_cast<const float4*>(s)[i];
  hv.x /= (sv.x + SM_EPS); hv.y /= (sv.y + SM_EPS);
  hv.z /= (sv.z + SM_EPS); hv.w /= (sv.w + SM_EPS);
  reinterpret_cast<float4*>(h)[i] = hv;
}

// ------------- scatter-aggregate: acc[dst] += ew * g[src]  (C=128) ----------
__global__ __launch_bounds__(256) void k_agg1(const u16* __restrict__ ew,
                                              const int* __restrict__ src,
                                              const int* __restrict__ dst,
                                              const float* __restrict__ g,
                                              float* __restrict__ acc, int E) {
  const int i = blockIdx.x * 256 + threadIdx.x;
  if (i >= E * 32) return;
  const int e = i >> 5;
  const int c4 = i & 31;
  const int sn = src[e], dn = dst[e];
  const uint2 p = *reinterpret_cast<const uint2*>(&ew[(size_t)e * 128 + c4 * 4]);
  const float4 gv = *reinterpret_cast<const float4*>(&g[(size_t)sn * 128 + c4 * 4]);
  float* ap = &acc[(size_t)dn * 128 + c4 * 4];
  atomicAdd(ap + 0, bf2f((u16)(p.x & 0xffffu)) * gv.x);
  atomicAdd(ap + 1, bf2f((u16)(p.x >> 16)) * gv.y);
  atomicAdd(ap + 2, bf2f((u16)(p.y & 0xffffu)) * gv.z);
  atomicAdd(ap + 3, bf2f((u16)(p.y >> 16)) * gv.w);
}

// ------------- same for C=40 ----------
__global__ __launch_bounds__(256) void k_agg2(const u16* __restrict__ ew,
                                              const int* __restrict__ src,
                                              const int* __restrict__ dst,
                                              const float* __restrict__ g,
                                              float* __restrict__ acc, int E) {
  const int i = blockIdx.x * 256 + threadIdx.x;
  if (i >= E * 10) return;
  const int e = i / 10;
  const int c4 = i - e * 10;
  const int sn = src[e], dn = dst[e];
  const uint2 p = *reinterpret_cast<const uint2*>(&ew[(size_t)e * 40 + c4 * 4]);
  const float4 gv = *reinterpret_cast<const float4*>(&g[(size_t)sn * 40 + c4 * 4]);
  float* ap = &acc[(size_t)dn * 40 + c4 * 4];
  atomicAdd(ap + 0, bf2f((u16)(p.x & 0xffffu)) * gv.x);
  atomicAdd(ap + 1, bf2f((u16)(p.x >> 16)) * gv.y);
  atomicAdd(ap + 2, bf2f((u16)(p.y & 0xffffu)) * gv.z);
  atomicAdd(ap + 3, bf2f((u16)(p.y >> 16)) * gv.w);
}

// ------------- y1 = elu(acc + b1 + alpha*pw1), C=128 ----------
__global__ __launch_bounds__(256) void k_final1(const float* __restrict__ acc,
                                                const float* __restrict__ pw,
                                                const float* __restrict__ b,
                                                const float* __restrict__ alpha_p,
                                                float* __restrict__ y, int total4) {
  const int i = blockIdx.x * 256 + threadIdx.x;
  if (i >= total4) return;
  const int c4 = i & 31;
  const float al = alpha_p[0];
  const float4 a = reinterpret_cast<const float4*>(acc)[i];
  const float4 p = reinterpret_cast<const float4*>(pw)[i];
  const float4 bb = *reinterpret_cast<const float4*>(&b[c4 * 4]);
  float v0 = a.x + bb.x + al * p.x;
  float v1 = a.y + bb.y + al * p.y;
  float v2 = a.z + bb.z + al * p.z;
  float v3 = a.w + bb.w + al * p.w;
  v0 = (v0 > 0.f) ? v0 : expm1f(v0);
  v1 = (v1 > 0.f) ? v1 : expm1f(v1);
  v2 = (v2 > 0.f) ? v2 : expm1f(v2);
  v3 = (v3 > 0.f) ? v3 : expm1f(v3);
  reinterpret_cast<float4*>(y)[i] = make_float4(v0, v1, v2, v3);
}

// ------------- out = acc + b2 + alpha*pw2, C=40 ----------
__global__ __launch_bounds__(256) void k_final2(const float* __restrict__ acc,
                                                const float* __restrict__ pw,
                                                const float* __restrict__ b,
                                                const float* __restrict__ alpha_p,
                                                float* __restrict__ y, int total4) {
  const int i = blockIdx.x * 256 + threadIdx.x;
  if (i >= total4) return;
  const int c4 = i % 10;
  const float al = alpha_p[0];
  const float4 a = reinterpret_cast<const float4*>(acc)[i];
  const float4 p = reinterpret_cast<const float4*>(pw)[i];
  const float4 bb = *reinterpret_cast<const float4*>(&b[c4 * 4]);
  reinterpret_cast<float4*>(y)[i] = make_float4(
      a.x + bb.x + al * p.x, a.y + bb.y + al * p.y,
      a.z + bb.z + al * p.z, a.w + bb.w + al * p.w);
}

extern "C" void kernel_launch(void* const* d_in, const int* in_sizes, int n_in,
                              void* d_out, int out_size, void* d_ws, size_t ws_size,
                              hipStream_t stream) {
  const float* x    = (const float*)d_in[0];
  const int*   ei   = (const int*)d_in[1];
  const float* kric = (const float*)d_in[2];
  const float* epoi = (const float*)d_in[3];
  const float* alpha= (const float*)d_in[4];
  const float* W1   = (const float*)d_in[5];
  const float* Wa1  = (const float*)d_in[6];
  const float* Wb1  = (const float*)d_in[7];
  const float* bb1  = (const float*)d_in[8];
  const float* Wc1  = (const float*)d_in[9];
  const float* Wd1  = (const float*)d_in[10];
  const float* bd1  = (const float*)d_in[11];
  const float* b1   = (const float*)d_in[12];
  const float* W2   = (const float*)d_in[13];
  const float* Wa2  = (const float*)d_in[14];
  const float* Wb2  = (const float*)d_in[15];
  const float* bb2  = (const float*)d_in[16];
  const float* Wc2  = (const float*)d_in[17];
  const float* Wd2  = (const float*)d_in[18];
  const float* bd2  = (const float*)d_in[19];
  const float* b2   = (const float*)d_in[20];

  const int N = in_sizes[0] / 512;
  const int E = in_sizes[1] / 2;
  const int* srcI = ei;
  const int* dstI = ei + E;

  float* wsf = (float*)d_ws;
  float* s1   = wsf;
  float* acc1 = s1 + (size_t)N * 128;
  float* s2   = acc1 + (size_t)N * 128;
  float* acc2 = s2 + (size_t)N * 40;
  float* h1   = acc2 + (size_t)N * 40;   // becomes g1 in place
  float* y1   = h1 + (size_t)N * 128;
  float* h2   = y1 + (size_t)N * 128;    // becomes g2 in place
  float* pw1  = h2 + (size_t)N * 40;
  float* pw2  = pw1 + (size_t)N * 128;
  u16*   ew   = (u16*)(pw2 + (size_t)N * 40);  // E*128 bf16, reused for E*40 in layer 2

  // zero accumulators (s1, acc1, s2, acc2 are contiguous)
  hipMemsetAsync(wsf, 0, (size_t)(2 * (size_t)N * 128 + 2 * (size_t)N * 40) * 4, stream);

  // ---------------- layer 1 ----------------
  k_gemm1<<<(N + 127) / 128, 256, 0, stream>>>(x, W1, h1, N);
  k_mlp128<0><<<(E + 127) / 128, 256, 0, stream>>>(kric, srcI, Wa1, Wb1, bb1, ew, s1, nullptr, E);
  k_mlp128<1><<<(N + 127) / 128, 256, 0, stream>>>(epoi, nullptr, Wc1, Wd1, bd1, nullptr, nullptr, pw1, N);
  k_gdiv<<<((N * 32) + 255) / 256, 256, 0, stream>>>(h1, s1, N * 32);
  k_agg1<<<((E * 32) + 255) / 256, 256, 0, stream>>>(ew, srcI, dstI, h1, acc1, E);
  k_final1<<<((N * 32) + 255) / 256, 256, 0, stream>>>(acc1, pw1, b1, alpha, y1, N * 32);

  // ---------------- layer 2 ----------------
  k_gemm2<<<(N + 5) / 6, 256, 0, stream>>>(y1, W2, h2, N);
  k_mlp40<0><<<(E + 255) / 256, 256, 0, stream>>>(kric, srcI, Wa2, Wb2, bb2, ew, s2, nullptr, E);
  k_mlp40<1><<<(N + 255) / 256, 256, 0, stream>>>(epoi, nullptr, Wc2, Wd2, bd2, nullptr, nullptr, pw2, N);
  k_gdiv<<<((N * 10) + 255) / 256, 256, 0, stream>>>(h2, s2, N * 10);
  k_agg2<<<((E * 10) + 255) / 256, 256, 0, stream>>>(ew, srcI, dstI, h2, acc2, E);
  k_final2<<<((N * 10) + 255) / 256, 256, 0, stream>>>(acc2, pw2, b2, alpha, (float*)d_out, N * 10);
}

// Round 2
// 1588.546 us; speedup vs baseline: 4.4601x; 4.4601x over previous
//
#include <hip/hip_runtime.h>
#include <math.h>

#define SM_EPS 1e-16f

typedef unsigned short u16;
typedef unsigned int u32;

__device__ __forceinline__ u16 f2bf(float x) {
  u32 u = __float_as_uint(x);
  u32 lsb = (u >> 16) & 1u;
  u += 0x7fffu + lsb;
  return (u16)(u >> 16);
}
__device__ __forceinline__ float bf2f(u16 u) {
  return __uint_as_float(((u32)u) << 16);
}

// ---------------- h1 = x @ W1   [M,512]@[512,128] -------------------
__global__ __launch_bounds__(256) void k_gemm1(const float* __restrict__ A,
                                               const float* __restrict__ B,
                                               float* __restrict__ C, int M) {
  __shared__ float As[16][136];
  __shared__ float Bs[16][128];
  const int tid = threadIdx.x;
  const int m0 = blockIdx.x * 128;
  const int tm = tid >> 4, tn = tid & 15;
  const int am = tid & 127;
  const int akq0 = tid >> 7;
  const int row = m0 + am;
  float acc[8][8];
#pragma unroll
  for (int i = 0; i < 8; ++i)
#pragma unroll
    for (int j = 0; j < 8; ++j) acc[i][j] = 0.f;

  for (int k0 = 0; k0 < 512; k0 += 16) {
#pragma unroll
    for (int t = 0; t < 2; ++t) {
      const int kq = akq0 + 2 * t;
      float4 v = make_float4(0.f, 0.f, 0.f, 0.f);
      if (row < M) v = *reinterpret_cast<const float4*>(&A[(size_t)row * 512 + k0 + kq * 4]);
      As[kq * 4 + 0][am] = v.x; As[kq * 4 + 1][am] = v.y;
      As[kq * 4 + 2][am] = v.z; As[kq * 4 + 3][am] = v.w;
    }
#pragma unroll
    for (int t = 0; t < 2; ++t) {
      const int s = tid + 256 * t;
      const int kk = s >> 5, n4 = s & 31;
      *reinterpret_cast<float4*>(&Bs[kk][n4 * 4]) =
          *reinterpret_cast<const float4*>(&B[(size_t)(k0 + kk) * 128 + n4 * 4]);
    }
    __syncthreads();
#pragma unroll
    for (int kk = 0; kk < 16; ++kk) {
      float a[8], b[8];
      *reinterpret_cast<float4*>(&a[0]) = *reinterpret_cast<const float4*>(&As[kk][tm * 8]);
      *reinterpret_cast<float4*>(&a[4]) = *reinterpret_cast<const float4*>(&As[kk][tm * 8 + 4]);
      *reinterpret_cast<float4*>(&b[0]) = *reinterpret_cast<const float4*>(&Bs[kk][tn * 8]);
      *reinterpret_cast<float4*>(&b[4]) = *reinterpret_cast<const float4*>(&Bs[kk][tn * 8 + 4]);
#pragma unroll
      for (int i = 0; i < 8; ++i)
#pragma unroll
        for (int j = 0; j < 8; ++j) acc[i][j] = fmaf(a[i], b[j], acc[i][j]);
    }
    __syncthreads();
  }
#pragma unroll
  for (int i = 0; i < 8; ++i) {
    const int r = m0 + tm * 8 + i;
    if (r < M) {
      *reinterpret_cast<float4*>(&C[(size_t)r * 128 + tn * 8]) =
          make_float4(acc[i][0], acc[i][1], acc[i][2], acc[i][3]);
      *reinterpret_cast<float4*>(&C[(size_t)r * 128 + tn * 8 + 4]) =
          make_float4(acc[i][4], acc[i][5], acc[i][6], acc[i][7]);
    }
  }
}

// ------------- fused 16->128->128 MLP over rows (edges or nodes) ----------
// MODE 0: edge path: logit -> exp -> store bf16 ew
// MODE 1: pw path:   logit -> lrelu(0.01) -> store f32
template <int MODE>
__global__ __launch_bounds__(256) void k_mlp128(
    const float* __restrict__ inp,
    const float* __restrict__ Wa, const float* __restrict__ Wb,
    const float* __restrict__ bbias, u16* __restrict__ ewOut,
    float* __restrict__ pwOut, int R) {
  __shared__ float Wa_s[16][128];
  __shared__ float Ut[16][136];
  __shared__ float Wbt[16][128];
  const int tid = threadIdx.x;
  const int r0 = blockIdx.x * 128;
  const int m = tid & 127;
  const int half = tid >> 7;
  const int tm = tid >> 4, tn = tid & 15;

#pragma unroll
  for (int t = 0; t < 2; ++t) {
    const int s = tid + 256 * t;
    const int kk = s >> 5, n4 = s & 31;
    *reinterpret_cast<float4*>(&Wa_s[kk][n4 * 4]) =
        *reinterpret_cast<const float4*>(&Wa[(size_t)kk * 128 + n4 * 4]);
  }
  float kreg[16];
  {
    const int rr = r0 + m;
    if (rr < R) {
#pragma unroll
      for (int t = 0; t < 4; ++t)
        *reinterpret_cast<float4*>(&kreg[t * 4]) =
            *reinterpret_cast<const float4*>(&inp[(size_t)rr * 16 + t * 4]);
    } else {
#pragma unroll
      for (int j = 0; j < 16; ++j) kreg[j] = 0.f;
    }
  }
  float acc[8][8];
#pragma unroll
  for (int i = 0; i < 8; ++i)
#pragma unroll
    for (int j = 0; j < 8; ++j) acc[i][j] = 0.f;
  __syncthreads();  // Wa_s ready

  for (int c0 = 0; c0 < 128; c0 += 16) {
#pragma unroll
    for (int t = 0; t < 8; ++t) {
      const int kk = half + 2 * t;
      const int c = c0 + kk;
      float u = 0.f;
#pragma unroll
      for (int j = 0; j < 16; ++j) u = fmaf(kreg[j], Wa_s[j][c], u);
      u = (u >= 0.f) ? u : 0.2f * u;
      Ut[kk][m] = u;
    }
#pragma unroll
    for (int t = 0; t < 2; ++t) {
      const int s = tid + 256 * t;
      const int kk = s >> 5, n4 = s & 31;
      *reinterpret_cast<float4*>(&Wbt[kk][n4 * 4]) =
          *reinterpret_cast<const float4*>(&Wb[(size_t)(c0 + kk) * 128 + n4 * 4]);
    }
    __syncthreads();
#pragma unroll
    for (int kk = 0; kk < 16; ++kk) {
      float a[8], b[8];
      *reinterpret_cast<float4*>(&a[0]) = *reinterpret_cast<const float4*>(&Ut[kk][tm * 8]);
      *reinterpret_cast<float4*>(&a[4]) = *reinterpret_cast<const float4*>(&Ut[kk][tm * 8 + 4]);
      *reinterpret_cast<float4*>(&b[0]) = *reinterpret_cast<const float4*>(&Wbt[kk][tn * 8]);
      *reinterpret_cast<float4*>(&b[4]) = *reinterpret_cast<const float4*>(&Wbt[kk][tn * 8 + 4]);
#pragma unroll
      for (int i = 0; i < 8; ++i)
#pragma unroll
        for (int j = 0; j < 8; ++j) acc[i][j] = fmaf(a[i], b[j], acc[i][j]);
    }
    __syncthreads();
  }

  float bv[8];
  *reinterpret_cast<float4*>(&bv[0]) = *reinterpret_cast<const float4*>(&bbias[tn * 8]);
  *reinterpret_cast<float4*>(&bv[4]) = *reinterpret_cast<const float4*>(&bbias[tn * 8 + 4]);
#pragma unroll
  for (int i = 0; i < 8; ++i) {
    const int r = r0 + tm * 8 + i;
    if (r >= R) continue;
    if (MODE == 0) {
      float ex[8];
#pragma unroll
      for (int j = 0; j < 8; ++j) ex[j] = __expf(acc[i][j] + bv[j]);
      u32 pk[4];
#pragma unroll
      for (int j2 = 0; j2 < 4; ++j2)
        pk[j2] = (u32)f2bf(ex[2 * j2]) | ((u32)f2bf(ex[2 * j2 + 1]) << 16);
      *reinterpret_cast<uint4*>(&ewOut[(size_t)r * 128 + tn * 8]) =
          make_uint4(pk[0], pk[1], pk[2], pk[3]);
    } else {
      float o[8];
#pragma unroll
      for (int j = 0; j < 8; ++j) {
        float v = acc[i][j] + bv[j];
        o[j] = (v >= 0.f) ? v : 0.01f * v;
      }
      *reinterpret_cast<float4*>(&pwOut[(size_t)r * 128 + tn * 8]) =
          make_float4(o[0], o[1], o[2], o[3]);
      *reinterpret_cast<float4*>(&pwOut[(size_t)r * 128 + tn * 8 + 4]) =
          make_float4(o[4], o[5], o[6], o[7]);
    }
  }
}

// ------------- fused 16->40->40 MLP, one row per thread ----------
template <int MODE>
__global__ __launch_bounds__(256) void k_mlp40(
    const float* __restrict__ inp,
    const float* __restrict__ Wa, const float* __restrict__ Wb,
    const float* __restrict__ bbias, u16* __restrict__ ewOut,
    float* __restrict__ pwOut, int R) {
  __shared__ float Wa_s[16 * 40];
  __shared__ float Wb_s[40 * 40];
  __shared__ float bb_s[40];
  const int tid = threadIdx.x;
  for (int i = tid; i < 640; i += 256) Wa_s[i] = Wa[i];
  for (int i = tid; i < 1600; i += 256) Wb_s[i] = Wb[i];
  if (tid < 40) bb_s[tid] = bbias[tid];
  __syncthreads();
  const int r = blockIdx.x * 256 + tid;
  if (r >= R) return;

  float kreg[16];
#pragma unroll
  for (int t = 0; t < 4; ++t)
    *reinterpret_cast<float4*>(&kreg[t * 4]) =
        *reinterpret_cast<const float4*>(&inp[(size_t)r * 16 + t * 4]);

  float u[40];
#pragma unroll
  for (int c = 0; c < 40; ++c) u[c] = 0.f;
#pragma unroll
  for (int j = 0; j < 16; ++j) {
    const float kj = kreg[j];
#pragma unroll
    for (int c4 = 0; c4 < 10; ++c4) {
      const float4 w = *reinterpret_cast<const float4*>(&Wa_s[j * 40 + c4 * 4]);
      u[c4 * 4 + 0] = fmaf(kj, w.x, u[c4 * 4 + 0]);
      u[c4 * 4 + 1] = fmaf(kj, w.y, u[c4 * 4 + 1]);
      u[c4 * 4 + 2] = fmaf(kj, w.z, u[c4 * 4 + 2]);
      u[c4 * 4 + 3] = fmaf(kj, w.w, u[c4 * 4 + 3]);
    }
  }
#pragma unroll
  for (int c = 0; c < 40; ++c) u[c] = (u[c] >= 0.f) ? u[c] : 0.2f * u[c];

  float o[40];
#pragma unroll
  for (int c = 0; c < 40; ++c) o[c] = bb_s[c];
#pragma unroll
  for (int j = 0; j < 40; ++j) {
    const float uj = u[j];
#pragma unroll
    for (int c4 = 0; c4 < 10; ++c4) {
      const float4 w = *reinterpret_cast<const float4*>(&Wb_s[j * 40 + c4 * 4]);
      o[c4 * 4 + 0] = fmaf(uj, w.x, o[c4 * 4 + 0]);
      o[c4 * 4 + 1] = fmaf(uj, w.y, o[c4 * 4 + 1]);
      o[c4 * 4 + 2] = fmaf(uj, w.z, o[c4 * 4 + 2]);
      o[c4 * 4 + 3] = fmaf(uj, w.w, o[c4 * 4 + 3]);
    }
  }
  if (MODE == 0) {
#pragma unroll
    for (int c = 0; c < 40; ++c) o[c] = __expf(o[c]);
#pragma unroll
    for (int c2 = 0; c2 < 20; ++c2) {
      u32 pk = (u32)f2bf(o[2 * c2]) | ((u32)f2bf(o[2 * c2 + 1]) << 16);
      *reinterpret_cast<u32*>(&ewOut[(size_t)r * 40 + c2 * 2]) = pk;
    }
  } else {
#pragma unroll
    for (int c = 0; c < 40; ++c) { float v = o[c]; o[c] = (v >= 0.f) ? v : 0.01f * v; }
#pragma unroll
    for (int c4 = 0; c4 < 10; ++c4)
      *reinterpret_cast<float4*>(&pwOut[(size_t)r * 40 + c4 * 4]) =
          make_float4(o[c4 * 4], o[c4 * 4 + 1], o[c4 * 4 + 2], o[c4 * 4 + 3]);
  }
}

// ------------- h2 = y1 @ W2  [M,128]@[128,40] ----------
__global__ __launch_bounds__(256) void k_gemm2(const float* __restrict__ A,
                                               const float* __restrict__ B,
                                               float* __restrict__ C, int M) {
  __shared__ float Bs[128 * 40];
  const int tid = threadIdx.x;
  for (int i = tid; i < 5120; i += 256) Bs[i] = B[i];
  __syncthreads();
  const int r = blockIdx.x * 6 + tid / 40;
  const int c = tid % 40;
  if (tid >= 240 || r >= M) return;
  const float* arow = &A[(size_t)r * 128];
  float acc = 0.f;
#pragma unroll
  for (int k4 = 0; k4 < 32; ++k4) {
    const float4 av = *reinterpret_cast<const float4*>(&arow[k4 * 4]);
    acc = fmaf(av.x, Bs[(k4 * 4 + 0) * 40 + c], acc);
    acc = fmaf(av.y, Bs[(k4 * 4 + 1) * 40 + c], acc);
    acc = fmaf(av.z, Bs[(k4 * 4 + 2) * 40 + c], acc);
    acc = fmaf(av.w, Bs[(k4 * 4 + 3) * 40 + c], acc);
  }
  C[(size_t)r * 40 + c] = acc;
}

// ================= CSR build =================
__global__ __launch_bounds__(256) void k_hist(const int* __restrict__ src,
                                              const int* __restrict__ dst,
                                              int* __restrict__ cnt, int N, int E) {
  const int e = blockIdx.x * 256 + threadIdx.x;
  if (e >= E) return;
  atomicAdd(&cnt[src[e]], 1);
  atomicAdd(&cnt[N + dst[e]], 1);
}

__global__ __launch_bounds__(256) void k_scanA(const int* __restrict__ cnt,
                                               int* __restrict__ bsum, int N, int NB) {
  const int arr = blockIdx.x / NB, bb = blockIdx.x % NB;
  const int g = bb * 256 + threadIdx.x;
  int v = (g < N) ? cnt[arr * N + g] : 0;
  __shared__ int sd[256];
  sd[threadIdx.x] = v;
  __syncthreads();
  for (int off = 128; off > 0; off >>= 1) {
    if (threadIdx.x < off) sd[threadIdx.x] += sd[threadIdx.x + off];
    __syncthreads();
  }
  if (threadIdx.x == 0) bsum[arr * 256 + bb] = sd[0];
}

__global__ __launch_bounds__(256) void k_scanB(const int* __restrict__ bsum,
                                               int* __restrict__ boff, int NB) {
  __shared__ int sd[256];
  for (int arr = 0; arr < 2; ++arr) {
    const int v = (threadIdx.x < NB) ? bsum[arr * 256 + threadIdx.x] : 0;
    sd[threadIdx.x] = v;
    __syncthreads();
    for (int off = 1; off < 256; off <<= 1) {
      const int t = (threadIdx.x >= off) ? sd[threadIdx.x - off] : 0;
      __syncthreads();
      sd[threadIdx.x] += t;
      __syncthreads();
    }
    if (threadIdx.x < NB) boff[arr * 256 + threadIdx.x] = sd[threadIdx.x] - v;
    __syncthreads();
  }
}

__global__ __launch_bounds__(256) void k_scanC(const int* __restrict__ cnt,
                                               const int* __restrict__ boff,
                                               int* __restrict__ row_src,
                                               int* __restrict__ row_dst,
                                               int* __restrict__ cur, int N, int NB) {
  const int arr = blockIdx.x / NB, bb = blockIdx.x % NB;
  const int g = bb * 256 + threadIdx.x;
  const int v = (g < N) ? cnt[arr * N + g] : 0;
  __shared__ int sd[256];
  sd[threadIdx.x] = v;
  __syncthreads();
  for (int off = 1; off < 256; off <<= 1) {
    const int t = (threadIdx.x >= off) ? sd[threadIdx.x - off] : 0;
    __syncthreads();
    sd[threadIdx.x] += t;
    __syncthreads();
  }
  const int incl = sd[threadIdx.x];
  const int base = boff[arr * 256 + bb];
  int* row = arr ? row_dst : row_src;
  if (g < N) {
    row[g] = base + incl - v;
    cur[arr * N + g] = base + incl - v;
    if (g == N - 1) row[N] = base + incl;
  }
}

__global__ __launch_bounds__(256) void k_scatter(const int* __restrict__ src,
                                                 const int* __restrict__ dst,
                                                 int* __restrict__ cur,
                                                 int* __restrict__ eid_src,
                                                 int* __restrict__ eid_dst,
                                                 int* __restrict__ srcb, int N, int E) {
  const int e = blockIdx.x * 256 + threadIdx.x;
  if (e >= E) return;
  const int s = src[e], d = dst[e];
  const int ps = atomicAdd(&cur[s], 1);
  eid_src[ps] = e;
  const int pd = atomicAdd(&cur[N + d], 1);
  eid_dst[pd] = e;
  srcb[pd] = s;
}

// ===== s = segsum(ew) over src-CSR, then g = h/(s+eps) in place =====
template <int C>
__global__ __launch_bounds__(256) void k_norm(const int* __restrict__ rowp,
                                              const int* __restrict__ eid,
                                              const u16* __restrict__ ew,
                                              float* __restrict__ h, int N) {
  const int CW = (C == 128) ? 128 : 64;
  const int grp = threadIdx.x / CW;
  const int c = threadIdx.x % CW;
  const int n = blockIdx.x * (256 / CW) + grp;
  if (n >= N || c >= C) return;
  const int r0 = rowp[n], r1 = rowp[n + 1];
  float s = 0.f;
  for (int p = r0; p < r1; ++p) {
    const int e = eid[p];
    s += bf2f(ew[(size_t)e * C + c]);
  }
  const size_t o = (size_t)n * C + c;
  h[o] = h[o] / (s + SM_EPS);
}

// ===== out[n] = (sum over in-edges ew*g[src]) + b + alpha*pw, opt ELU =====
template <int C, int DO_ELU>
__global__ __launch_bounds__(256) void k_aggf(const int* __restrict__ rowp,
                                              const int* __restrict__ eid,
                                              const int* __restrict__ srcb,
                                              const u16* __restrict__ ew,
                                              const float* __restrict__ g,
                                              const float* __restrict__ pw,
                                              const float* __restrict__ bias,
                                              const float* __restrict__ alpha_p,
                                              float* __restrict__ out, int N) {
  const int CW = (C == 128) ? 128 : 64;
  const int grp = threadIdx.x / CW;
  const int c = threadIdx.x % CW;
  const int n = blockIdx.x * (256 / CW) + grp;
  if (n >= N || c >= C) return;
  const int r0 = rowp[n], r1 = rowp[n + 1];
  float acc = 0.f;
  for (int p = r0; p < r1; ++p) {
    const int e = eid[p];
    const int sn = srcb[p];
    acc = fmaf(bf2f(ew[(size_t)e * C + c]), g[(size_t)sn * C + c], acc);
  }
  float v = acc + bias[c] + alpha_p[0] * pw[(size_t)n * C + c];
  if (DO_ELU) v = (v > 0.f) ? v : expm1f(v);
  out[(size_t)n * C + c] = v;
}

extern "C" void kernel_launch(void* const* d_in, const int* in_sizes, int n_in,
                              void* d_out, int out_size, void* d_ws, size_t ws_size,
                              hipStream_t stream) {
  const float* x    = (const float*)d_in[0];
  const int*   ei   = (const int*)d_in[1];
  const float* kric = (const float*)d_in[2];
  const float* epoi = (const float*)d_in[3];
  const float* alpha= (const float*)d_in[4];
  const float* W1   = (const float*)d_in[5];
  const float* Wa1  = (const float*)d_in[6];
  const float* Wb1  = (const float*)d_in[7];
  const float* bb1  = (const float*)d_in[8];
  const float* Wc1  = (const float*)d_in[9];
  const float* Wd1  = (const float*)d_in[10];
  const float* bd1  = (const float*)d_in[11];
  const float* b1   = (const float*)d_in[12];
  const float* W2   = (const float*)d_in[13];
  const float* Wa2  = (const float*)d_in[14];
  const float* Wb2  = (const float*)d_in[15];
  const float* bb2  = (const float*)d_in[16];
  const float* Wc2  = (const float*)d_in[17];
  const float* Wd2  = (const float*)d_in[18];
  const float* bd2  = (const float*)d_in[19];
  const float* b2   = (const float*)d_in[20];

  const int N = in_sizes[0] / 512;
  const int E = in_sizes[1] / 2;
  const int* srcI = ei;
  const int* dstI = ei + E;
  const int NB = (N + 255) / 256;

  // ---- workspace layout ----
  char* p = (char*)d_ws;
  int* cnt      = (int*)p; p += (size_t)2 * N * 4;
  int* cur      = (int*)p; p += (size_t)2 * N * 4;
  int* bsum     = (int*)p; p += 512 * 4;
  int* boff     = (int*)p; p += 512 * 4;
  int* row_src  = (int*)p; p += (size_t)(N + 1) * 4;
  int* row_dst  = (int*)p; p += (size_t)(N + 1) * 4;
  int* eid_src  = (int*)p; p += (size_t)E * 4;
  int* eid_dst  = (int*)p; p += (size_t)E * 4;
  int* srcb     = (int*)p; p += (size_t)E * 4;
  p = (char*)(((uintptr_t)p + 255) & ~(uintptr_t)255);
  float* h1  = (float*)p; p += (size_t)N * 128 * 4;  // becomes g1 in place
  float* y1  = (float*)p; p += (size_t)N * 128 * 4;
  float* h2  = (float*)p; p += (size_t)N * 40 * 4;   // becomes g2 in place
  float* pw1 = (float*)p; p += (size_t)N * 128 * 4;
  float* pw2 = (float*)p; p += (size_t)N * 40 * 4;
  u16* ew    = (u16*)p;  // E*128 bf16 (layer 1), reused E*40 (layer 2)

  // ---- CSR build (once, reused by both layers) ----
  hipMemsetAsync(cnt, 0, (size_t)2 * N * 4, stream);
  k_hist<<<(E + 255) / 256, 256, 0, stream>>>(srcI, dstI, cnt, N, E);
  k_scanA<<<2 * NB, 256, 0, stream>>>(cnt, bsum, N, NB);
  k_scanB<<<1, 256, 0, stream>>>(bsum, boff, NB);
  k_scanC<<<2 * NB, 256, 0, stream>>>(cnt, boff, row_src, row_dst, cur, N, NB);
  k_scatter<<<(E + 255) / 256, 256, 0, stream>>>(srcI, dstI, cur, eid_src, eid_dst, srcb, N, E);

  // ---------------- layer 1 ----------------
  k_gemm1<<<(N + 127) / 128, 256, 0, stream>>>(x, W1, h1, N);
  k_mlp128<0><<<(E + 127) / 128, 256, 0, stream>>>(kric, Wa1, Wb1, bb1, ew, nullptr, E);
  k_mlp128<1><<<(N + 127) / 128, 256, 0, stream>>>(epoi, Wc1, Wd1, bd1, nullptr, pw1, N);
  k_norm<128><<<(N + 1) / 2, 256, 0, stream>>>(row_src, eid_src, ew, h1, N);
  k_aggf<128, 1><<<(N + 1) / 2, 256, 0, stream>>>(row_dst, eid_dst, srcb, ew, h1, pw1, b1, alpha, y1, N);

  // ---------------- layer 2 ----------------
  k_gemm2<<<(N + 5) / 6, 256, 0, stream>>>(y1, W2, h2, N);
  k_mlp40<0><<<(E + 255) / 256, 256, 0, stream>>>(kric, Wa2, Wb2, bb2, ew, nullptr, E);
  k_mlp40<1><<<(N + 255) / 256, 256, 0, stream>>>(epoi, Wc2, Wd2, bd2, nullptr, pw2, N);
  k_norm<40><<<(N + 3) / 4, 256, 0, stream>>>(row_src, eid_src, ew, h2, N);
  k_aggf<40, 0><<<(N + 3) / 4, 256, 0, stream>>>(row_dst, eid_dst, srcb, ew, h2, pw2, b2, alpha, (float*)d_out, N);
}

// Round 3
// 1232.359 us; speedup vs baseline: 5.7493x; 1.2890x over previous
//
#include <hip/hip_runtime.h>
#include <math.h>

#define SM_EPS 1e-16f

typedef unsigned short u16;
typedef unsigned int u32;
typedef short s16x8 __attribute__((ext_vector_type(8)));
typedef float f32x4 __attribute__((ext_vector_type(4)));

__device__ __forceinline__ u16 f2bfh(float x) {
  __bf16 b = (__bf16)x;                    // RNE, compiler emits v_cvt_pk_bf16_f32 pairs
  return __builtin_bit_cast(unsigned short, b);
}
__device__ __forceinline__ float bf2f(u16 u) {
  return __uint_as_float(((u32)u) << 16);
}

// ---------------- h1 = x @ W1   [M,512]@[512,128] -------------------
__global__ __launch_bounds__(256) void k_gemm1(const float* __restrict__ A,
                                               const float* __restrict__ B,
                                               float* __restrict__ C, int M) {
  __shared__ float As[16][136];
  __shared__ float Bs[16][128];
  const int tid = threadIdx.x;
  const int m0 = blockIdx.x * 128;
  const int tm = tid >> 4, tn = tid & 15;
  const int am = tid & 127;
  const int akq0 = tid >> 7;
  const int row = m0 + am;
  float acc[8][8];
#pragma unroll
  for (int i = 0; i < 8; ++i)
#pragma unroll
    for (int j = 0; j < 8; ++j) acc[i][j] = 0.f;

  for (int k0 = 0; k0 < 512; k0 += 16) {
#pragma unroll
    for (int t = 0; t < 2; ++t) {
      const int kq = akq0 + 2 * t;
      float4 v = make_float4(0.f, 0.f, 0.f, 0.f);
      if (row < M) v = *reinterpret_cast<const float4*>(&A[(size_t)row * 512 + k0 + kq * 4]);
      As[kq * 4 + 0][am] = v.x; As[kq * 4 + 1][am] = v.y;
      As[kq * 4 + 2][am] = v.z; As[kq * 4 + 3][am] = v.w;
    }
#pragma unroll
    for (int t = 0; t < 2; ++t) {
      const int s = tid + 256 * t;
      const int kk = s >> 5, n4 = s & 31;
      *reinterpret_cast<float4*>(&Bs[kk][n4 * 4]) =
          *reinterpret_cast<const float4*>(&B[(size_t)(k0 + kk) * 128 + n4 * 4]);
    }
    __syncthreads();
#pragma unroll
    for (int kk = 0; kk < 16; ++kk) {
      float a[8], b[8];
      *reinterpret_cast<float4*>(&a[0]) = *reinterpret_cast<const float4*>(&As[kk][tm * 8]);
      *reinterpret_cast<float4*>(&a[4]) = *reinterpret_cast<const float4*>(&As[kk][tm * 8 + 4]);
      *reinterpret_cast<float4*>(&b[0]) = *reinterpret_cast<const float4*>(&Bs[kk][tn * 8]);
      *reinterpret_cast<float4*>(&b[4]) = *reinterpret_cast<const float4*>(&Bs[kk][tn * 8 + 4]);
#pragma unroll
      for (int i = 0; i < 8; ++i)
#pragma unroll
        for (int j = 0; j < 8; ++j) acc[i][j] = fmaf(a[i], b[j], acc[i][j]);
    }
    __syncthreads();
  }
#pragma unroll
  for (int i = 0; i < 8; ++i) {
    const int r = m0 + tm * 8 + i;
    if (r < M) {
      *reinterpret_cast<float4*>(&C[(size_t)r * 128 + tn * 8]) =
          make_float4(acc[i][0], acc[i][1], acc[i][2], acc[i][3]);
      *reinterpret_cast<float4*>(&C[(size_t)r * 128 + tn * 8 + 4]) =
          make_float4(acc[i][4], acc[i][5], acc[i][6], acc[i][7]);
    }
  }
}

// -------- weight prep: transpose + bf16 convert (once per call) --------
// WaTg[n*16+k]  = bf16(Wa[k*128+n])   (16x128 -> [128][16])
// WbTg[n*128+k] = bf16(Wb[k*128+n])   (128x128 -> [128][128])
__global__ __launch_bounds__(256) void k_prep(const float* __restrict__ Wa,
                                              const float* __restrict__ Wb,
                                              const float* __restrict__ Wc,
                                              const float* __restrict__ Wd,
                                              u16* __restrict__ WaTg, u16* __restrict__ WbTg,
                                              u16* __restrict__ WcTg, u16* __restrict__ WdTg) {
  const int idx = blockIdx.x * 256 + threadIdx.x;
  if (idx < 2048) {
    const int n = idx >> 4, k = idx & 15;
    WaTg[idx] = f2bfh(Wa[k * 128 + n]);
  } else if (idx < 18432) {
    const int t = idx - 2048;
    const int n = t >> 7, k = t & 127;
    WbTg[t] = f2bfh(Wb[k * 128 + n]);
  } else if (idx < 20480) {
    const int t = idx - 18432;
    const int n = t >> 4, k = t & 15;
    WcTg[t] = f2bfh(Wc[k * 128 + n]);
  } else if (idx < 36864) {
    const int t = idx - 20480;
    const int n = t >> 7, k = t & 127;
    WdTg[t] = f2bfh(Wd[k * 128 + n]);
  }
}

// ------- MFMA fused 16->128->128 MLP over rows (edges or nodes) -------
// MODE 0: logit -> exp -> bf16 ew store.  MODE 1: logit -> lrelu(0.01) -> f32 store.
// Block: 128 rows x 128 cols, 4 waves, each wave a 64x64 quadrant (4x4 MFMA tiles).
template <int MODE>
__global__ __launch_bounds__(256) void k_emlp(
    const float* __restrict__ inp,            // [R,16] f32
    const u16* __restrict__ WaTg,             // [128][16] bf16 (n,k)
    const u16* __restrict__ WbTg,             // [128][128] bf16 (n,k)
    const float* __restrict__ bbias,          // [128]
    u16* __restrict__ ewOut, float* __restrict__ pwOut, int R) {
  __shared__ __align__(16) unsigned char sWb[32768];  // XOR-16 swizzled [n][k] bf16
  __shared__ __align__(16) unsigned char sU[32768];   // XOR-16 swizzled [row][col] bf16
  __shared__ __align__(16) u16 sWa[2048];             // [n][16] bf16, linear
  const int tid = threadIdx.x;
  const int lane = tid & 63;
  const int w = tid >> 6;
  const int wr = w >> 1, wc = w & 1;
  const int lg = lane >> 4;   // 0..3 (k-group)
  const int lm = lane & 15;   // row/col within tile
  const int r0 = blockIdx.x * 128;

  // ---- stage WaT (4KB) + WbT (32KB, swizzled) into LDS ----
  {
    const int n = tid >> 1, half = tid & 1;
    *reinterpret_cast<uint4*>(&sWa[n * 16 + half * 8]) =
        *reinterpret_cast<const uint4*>(&WaTg[n * 16 + half * 8]);
  }
#pragma unroll
  for (int it = 0; it < 8; ++it) {
    const int idx = tid + it * 256;
    const int n = idx >> 4, c = idx & 15;
    const uint4 v = *reinterpret_cast<const uint4*>(&WbTg[n * 128 + c * 8]);
    *reinterpret_cast<uint4*>(&sWb[n * 256 + ((c ^ (n & 15)) << 4)]) = v;
  }

  // ---- stage-1 A frags from global (K=16 zero-padded to 32) ----
  s16x8 afr[4];
#pragma unroll
  for (int i = 0; i < 4; ++i) {
    s16x8 a = (s16x8)0;
    if (lg < 2) {
      const int r = r0 + (wr * 4 + i) * 16 + lm;
      if (r < R) {
        const float4 f0 = *reinterpret_cast<const float4*>(&inp[(size_t)r * 16 + lg * 8]);
        const float4 f1 = *reinterpret_cast<const float4*>(&inp[(size_t)r * 16 + lg * 8 + 4]);
        a[0] = (short)f2bfh(f0.x); a[1] = (short)f2bfh(f0.y);
        a[2] = (short)f2bfh(f0.z); a[3] = (short)f2bfh(f0.w);
        a[4] = (short)f2bfh(f1.x); a[5] = (short)f2bfh(f1.y);
        a[6] = (short)f2bfh(f1.z); a[7] = (short)f2bfh(f1.w);
      }
    }
    afr[i] = a;
  }
  __syncthreads();  // sWa/sWb ready

  // ---- stage 1: U = lrelu(K @ Wa), K=16 ----
  const f32x4 z4 = {0.f, 0.f, 0.f, 0.f};
  s16x8 bfr1[4];
#pragma unroll
  for (int j = 0; j < 4; ++j) {
    s16x8 b = (s16x8)0;
    if (lg < 2) {
      const int n = (wc * 4 + j) * 16 + lm;
      b = *reinterpret_cast<const s16x8*>(&sWa[n * 16 + lg * 8]);
    }
    bfr1[j] = b;
  }
  f32x4 acc1[4][4];
#pragma unroll
  for (int i = 0; i < 4; ++i)
#pragma unroll
    for (int j = 0; j < 4; ++j) acc1[i][j] = z4;
#pragma unroll
  for (int i = 0; i < 4; ++i)
#pragma unroll
    for (int j = 0; j < 4; ++j)
      acc1[i][j] = __builtin_amdgcn_mfma_f32_16x16x32_bf16(afr[i], bfr1[j], acc1[i][j], 0, 0, 0);

  // write U to LDS (bf16, swizzled); C layout: col=lane&15, row=(lane>>4)*4+reg
#pragma unroll
  for (int i = 0; i < 4; ++i) {
#pragma unroll
    for (int j = 0; j < 4; ++j) {
#pragma unroll
      for (int rr = 0; rr < 4; ++rr) {
        float v = acc1[i][j][rr];
        v = (v >= 0.f) ? v : 0.2f * v;
        const int grow = (wr * 4 + i) * 16 + lg * 4 + rr;
        const int gcol = (wc * 4 + j) * 16 + lm;
        const int byte = grow * 256 + ((((gcol >> 3) ^ (grow & 15))) << 4) + (gcol & 7) * 2;
        *reinterpret_cast<u16*>(&sU[byte]) = f2bfh(v);
      }
    }
  }
  __syncthreads();  // U ready

  // ---- stage 2: logit = U @ Wb, K=128 ----
  f32x4 acc[4][4];
#pragma unroll
  for (int i = 0; i < 4; ++i)
#pragma unroll
    for (int j = 0; j < 4; ++j) acc[i][j] = z4;
#pragma unroll
  for (int kb = 0; kb < 4; ++kb) {
    s16x8 af[4], bf_[4];
    const int ch = kb * 4 + lg;
#pragma unroll
    for (int i = 0; i < 4; ++i) {
      const int row = (wr * 4 + i) * 16 + lm;
      af[i] = *reinterpret_cast<const s16x8*>(&sU[row * 256 + ((ch ^ (row & 15)) << 4)]);
    }
#pragma unroll
    for (int j = 0; j < 4; ++j) {
      const int n = (wc * 4 + j) * 16 + lm;
      bf_[j] = *reinterpret_cast<const s16x8*>(&sWb[n * 256 + ((ch ^ (n & 15)) << 4)]);
    }
#pragma unroll
    for (int i = 0; i < 4; ++i)
#pragma unroll
      for (int j = 0; j < 4; ++j)
        acc[i][j] = __builtin_amdgcn_mfma_f32_16x16x32_bf16(af[i], bf_[j], acc[i][j], 0, 0, 0);
  }

  // ---- epilogue ----
  float bv[4];
#pragma unroll
  for (int j = 0; j < 4; ++j) bv[j] = bbias[(wc * 4 + j) * 16 + lm];
#pragma unroll
  for (int i = 0; i < 4; ++i) {
#pragma unroll
    for (int rr = 0; rr < 4; ++rr) {
      const int grow = r0 + (wr * 4 + i) * 16 + lg * 4 + rr;
      if (grow < R) {
        if (MODE == 0) {
#pragma unroll
          for (int j = 0; j < 4; ++j) {
            const float v = __expf(acc[i][j][rr] + bv[j]);
            ewOut[(size_t)grow * 128 + (wc * 4 + j) * 16 + lm] = f2bfh(v);
          }
        } else {
#pragma unroll
          for (int j = 0; j < 4; ++j) {
            float v = acc[i][j][rr] + bv[j];
            v = (v >= 0.f) ? v : 0.01f * v;
            pwOut[(size_t)grow * 128 + (wc * 4 + j) * 16 + lm] = v;
          }
        }
      }
    }
  }
}

// ------------- fused 16->40->40 MLP, one row per thread ----------
template <int MODE>
__global__ __launch_bounds__(256) void k_mlp40(
    const float* __restrict__ inp,
    const float* __restrict__ Wa, const float* __restrict__ Wb,
    const float* __restrict__ bbias, u16* __restrict__ ewOut,
    float* __restrict__ pwOut, int R) {
  __shared__ float Wa_s[16 * 40];
  __shared__ float Wb_s[40 * 40];
  __shared__ float bb_s[40];
  const int tid = threadIdx.x;
  for (int i = tid; i < 640; i += 256) Wa_s[i] = Wa[i];
  for (int i = tid; i < 1600; i += 256) Wb_s[i] = Wb[i];
  if (tid < 40) bb_s[tid] = bbias[tid];
  __syncthreads();
  const int r = blockIdx.x * 256 + tid;
  if (r >= R) return;

  float kreg[16];
#pragma unroll
  for (int t = 0; t < 4; ++t)
    *reinterpret_cast<float4*>(&kreg[t * 4]) =
        *reinterpret_cast<const float4*>(&inp[(size_t)r * 16 + t * 4]);

  float u[40];
#pragma unroll
  for (int c = 0; c < 40; ++c) u[c] = 0.f;
#pragma unroll
  for (int j = 0; j < 16; ++j) {
    const float kj = kreg[j];
#pragma unroll
    for (int c4 = 0; c4 < 10; ++c4) {
      const float4 w = *reinterpret_cast<const float4*>(&Wa_s[j * 40 + c4 * 4]);
      u[c4 * 4 + 0] = fmaf(kj, w.x, u[c4 * 4 + 0]);
      u[c4 * 4 + 1] = fmaf(kj, w.y, u[c4 * 4 + 1]);
      u[c4 * 4 + 2] = fmaf(kj, w.z, u[c4 * 4 + 2]);
      u[c4 * 4 + 3] = fmaf(kj, w.w, u[c4 * 4 + 3]);
    }
  }
#pragma unroll
  for (int c = 0; c < 40; ++c) u[c] = (u[c] >= 0.f) ? u[c] : 0.2f * u[c];

  float o[40];
#pragma unroll
  for (int c = 0; c < 40; ++c) o[c] = bb_s[c];
#pragma unroll
  for (int j = 0; j < 40; ++j) {
    const float uj = u[j];
#pragma unroll
    for (int c4 = 0; c4 < 10; ++c4) {
      const float4 w = *reinterpret_cast<const float4*>(&Wb_s[j * 40 + c4 * 4]);
      o[c4 * 4 + 0] = fmaf(uj, w.x, o[c4 * 4 + 0]);
      o[c4 * 4 + 1] = fmaf(uj, w.y, o[c4 * 4 + 1]);
      o[c4 * 4 + 2] = fmaf(uj, w.z, o[c4 * 4 + 2]);
      o[c4 * 4 + 3] = fmaf(uj, w.w, o[c4 * 4 + 3]);
    }
  }
  if (MODE == 0) {
#pragma unroll
    for (int c = 0; c < 40; ++c) o[c] = __expf(o[c]);
#pragma unroll
    for (int c2 = 0; c2 < 20; ++c2) {
      u32 pk = (u32)f2bfh(o[2 * c2]) | ((u32)f2bfh(o[2 * c2 + 1]) << 16);
      *reinterpret_cast<u32*>(&ewOut[(size_t)r * 40 + c2 * 2]) = pk;
    }
  } else {
#pragma unroll
    for (int c = 0; c < 40; ++c) { float v = o[c]; o[c] = (v >= 0.f) ? v : 0.01f * v; }
#pragma unroll
    for (int c4 = 0; c4 < 10; ++c4)
      *reinterpret_cast<float4*>(&pwOut[(size_t)r * 40 + c4 * 4]) =
          make_float4(o[c4 * 4], o[c4 * 4 + 1], o[c4 * 4 + 2], o[c4 * 4 + 3]);
  }
}

// ------------- h2 = y1 @ W2  [M,128]@[128,40] ----------
__global__ __launch_bounds__(256) void k_gemm2(const float* __restrict__ A,
                                               const float* __restrict__ B,
                                               float* __restrict__ C, int M) {
  __shared__ float Bs[128 * 40];
  const int tid = threadIdx.x;
  for (int i = tid; i < 5120; i += 256) Bs[i] = B[i];
  __syncthreads();
  const int r = blockIdx.x * 6 + tid / 40;
  const int c = tid % 40;
  if (tid >= 240 || r >= M) return;
  const float* arow = &A[(size_t)r * 128];
  float acc = 0.f;
#pragma unroll
  for (int k4 = 0; k4 < 32; ++k4) {
    const float4 av = *reinterpret_cast<const float4*>(&arow[k4 * 4]);
    acc = fmaf(av.x, Bs[(k4 * 4 + 0) * 40 + c], acc);
    acc = fmaf(av.y, Bs[(k4 * 4 + 1) * 40 + c], acc);
    acc = fmaf(av.z, Bs[(k4 * 4 + 2) * 40 + c], acc);
    acc = fmaf(av.w, Bs[(k4 * 4 + 3) * 40 + c], acc);
  }
  C[(size_t)r * 40 + c] = acc;
}

// ================= CSR build =================
__global__ __launch_bounds__(256) void k_hist(const int* __restrict__ src,
                                              const int* __restrict__ dst,
                                              int* __restrict__ cnt, int N, int E) {
  const int e = blockIdx.x * 256 + threadIdx.x;
  if (e >= E) return;
  atomicAdd(&cnt[src[e]], 1);
  atomicAdd(&cnt[N + dst[e]], 1);
}

__global__ __launch_bounds__(256) void k_scanA(const int* __restrict__ cnt,
                                               int* __restrict__ bsum, int N, int NB) {
  const int arr = blockIdx.x / NB, bb = blockIdx.x % NB;
  const int g = bb * 256 + threadIdx.x;
  int v = (g < N) ? cnt[arr * N + g] : 0;
  __shared__ int sd[256];
  sd[threadIdx.x] = v;
  __syncthreads();
  for (int off = 128; off > 0; off >>= 1) {
    if (threadIdx.x < off) sd[threadIdx.x] += sd[threadIdx.x + off];
    __syncthreads();
  }
  if (threadIdx.x == 0) bsum[arr * 256 + bb] = sd[0];
}

__global__ __launch_bounds__(256) void k_scanB(const int* __restrict__ bsum,
                                               int* __restrict__ boff, int NB) {
  __shared__ int sd[256];
  for (int arr = 0; arr < 2; ++arr) {
    const int v = (threadIdx.x < NB) ? bsum[arr * 256 + threadIdx.x] : 0;
    sd[threadIdx.x] = v;
    __syncthreads();
    for (int off = 1; off < 256; off <<= 1) {
      const int t = (threadIdx.x >= off) ? sd[threadIdx.x - off] : 0;
      __syncthreads();
      sd[threadIdx.x] += t;
      __syncthreads();
    }
    if (threadIdx.x < NB) boff[arr * 256 + threadIdx.x] = sd[threadIdx.x] - v;
    __syncthreads();
  }
}

__global__ __launch_bounds__(256) void k_scanC(const int* __restrict__ cnt,
                                               const int* __restrict__ boff,
                                               int* __restrict__ row_src,
                                               int* __restrict__ row_dst,
                                               int* __restrict__ cur, int N, int NB) {
  const int arr = blockIdx.x / NB, bb = blockIdx.x % NB;
  const int g = bb * 256 + threadIdx.x;
  const int v = (g < N) ? cnt[arr * N + g] : 0;
  __shared__ int sd[256];
  sd[threadIdx.x] = v;
  __syncthreads();
  for (int off = 1; off < 256; off <<= 1) {
    const int t = (threadIdx.x >= off) ? sd[threadIdx.x - off] : 0;
    __syncthreads();
    sd[threadIdx.x] += t;
    __syncthreads();
  }
  const int incl = sd[threadIdx.x];
  const int base = boff[arr * 256 + bb];
  int* row = arr ? row_dst : row_src;
  if (g < N) {
    row[g] = base + incl - v;
    cur[arr * N + g] = base + incl - v;
    if (g == N - 1) row[N] = base + incl;
  }
}

__global__ __launch_bounds__(256) void k_scatter(const int* __restrict__ src,
                                                 const int* __restrict__ dst,
                                                 int* __restrict__ cur,
                                                 int* __restrict__ eid_src,
                                                 int* __restrict__ eid_dst,
                                                 int* __restrict__ srcb, int N, int E) {
  const int e = blockIdx.x * 256 + threadIdx.x;
  if (e >= E) return;
  const int s = src[e], d = dst[e];
  const int ps = atomicAdd(&cur[s], 1);
  eid_src[ps] = e;
  const int pd = atomicAdd(&cur[N + d], 1);
  eid_dst[pd] = e;
  srcb[pd] = s;
}

// ===== s = segsum(ew) over src-CSR, then g = h/(s+eps) in place =====
template <int C>
__global__ __launch_bounds__(256) void k_norm(const int* __restrict__ rowp,
                                              const int* __restrict__ eid,
                                              const u16* __restrict__ ew,
                                              float* __restrict__ h, int N) {
  const int CW = (C == 128) ? 128 : 64;
  const int grp = threadIdx.x / CW;
  const int c = threadIdx.x % CW;
  const int n = blockIdx.x * (256 / CW) + grp;
  if (n >= N || c >= C) return;
  const int r0 = rowp[n], r1 = rowp[n + 1];
  float s = 0.f;
  for (int p = r0; p < r1; ++p) {
    const int e = eid[p];
    s += bf2f(ew[(size_t)e * C + c]);
  }
  const size_t o = (size_t)n * C + c;
  h[o] = h[o] / (s + SM_EPS);
}

// ===== out[n] = (sum over in-edges ew*g[src]) + b + alpha*pw, opt ELU =====
template <int C, int DO_ELU>
__global__ __launch_bounds__(256) void k_aggf(const int* __restrict__ rowp,
                                              const int* __restrict__ eid,
                                              const int* __restrict__ srcb,
                                              const u16* __restrict__ ew,
                                              const float* __restrict__ g,
                                              const float* __restrict__ pw,
                                              const float* __restrict__ bias,
                                              const float* __restrict__ alpha_p,
                                              float* __restrict__ out, int N) {
  const int CW = (C == 128) ? 128 : 64;
  const int grp = threadIdx.x / CW;
  const int c = threadIdx.x % CW;
  const int n = blockIdx.x * (256 / CW) + grp;
  if (n >= N || c >= C) return;
  const int r0 = rowp[n], r1 = rowp[n + 1];
  float acc = 0.f;
  for (int p = r0; p < r1; ++p) {
    const int e = eid[p];
    const int sn = srcb[p];
    acc = fmaf(bf2f(ew[(size_t)e * C + c]), g[(size_t)sn * C + c], acc);
  }
  float v = acc + bias[c] + alpha_p[0] * pw[(size_t)n * C + c];
  if (DO_ELU) v = (v > 0.f) ? v : expm1f(v);
  out[(size_t)n * C + c] = v;
}

extern "C" void kernel_launch(void* const* d_in, const int* in_sizes, int n_in,
                              void* d_out, int out_size, void* d_ws, size_t ws_size,
                              hipStream_t stream) {
  const float* x    = (const float*)d_in[0];
  const int*   ei   = (const int*)d_in[1];
  const float* kric = (const float*)d_in[2];
  const float* epoi = (const float*)d_in[3];
  const float* alpha= (const float*)d_in[4];
  const float* W1   = (const float*)d_in[5];
  const float* Wa1  = (const float*)d_in[6];
  const float* Wb1  = (const float*)d_in[7];
  const float* bb1  = (const float*)d_in[8];
  const float* Wc1  = (const float*)d_in[9];
  const float* Wd1  = (const float*)d_in[10];
  const float* bd1  = (const float*)d_in[11];
  const float* b1   = (const float*)d_in[12];
  const float* W2   = (const float*)d_in[13];
  const float* Wa2  = (const float*)d_in[14];
  const float* Wb2  = (const float*)d_in[15];
  const float* bb2  = (const float*)d_in[16];
  const float* Wc2  = (const float*)d_in[17];
  const float* Wd2  = (const float*)d_in[18];
  const float* bd2  = (const float*)d_in[19];
  const float* b2   = (const float*)d_in[20];

  const int N = in_sizes[0] / 512;
  const int E = in_sizes[1] / 2;
  const int* srcI = ei;
  const int* dstI = ei + E;
  const int NB = (N + 255) / 256;

  // ---- workspace layout ----
  char* p = (char*)d_ws;
  int* cnt      = (int*)p; p += (size_t)2 * N * 4;
  int* cur      = (int*)p; p += (size_t)2 * N * 4;
  int* bsum     = (int*)p; p += 512 * 4;
  int* boff     = (int*)p; p += 512 * 4;
  int* row_src  = (int*)p; p += (size_t)(N + 1) * 4;
  int* row_dst  = (int*)p; p += (size_t)(N + 1) * 4;
  int* eid_src  = (int*)p; p += (size_t)E * 4;
  int* eid_dst  = (int*)p; p += (size_t)E * 4;
  int* srcb     = (int*)p; p += (size_t)E * 4;
  p = (char*)(((uintptr_t)p + 255) & ~(uintptr_t)255);
  u16* WaT1g = (u16*)p; p += 2048 * 2;
  u16* WbT1g = (u16*)p; p += 16384 * 2;
  u16* WcT1g = (u16*)p; p += 2048 * 2;
  u16* WdT1g = (u16*)p; p += 16384 * 2;
  p = (char*)(((uintptr_t)p + 255) & ~(uintptr_t)255);
  float* h1  = (float*)p; p += (size_t)N * 128 * 4;  // becomes g1 in place
  float* y1  = (float*)p; p += (size_t)N * 128 * 4;
  float* h2  = (float*)p; p += (size_t)N * 40 * 4;   // becomes g2 in place
  float* pw1 = (float*)p; p += (size_t)N * 128 * 4;
  float* pw2 = (float*)p; p += (size_t)N * 40 * 4;
  u16* ew    = (u16*)p;  // E*128 bf16 (layer 1), reused E*40 (layer 2)

  // ---- CSR build (once, reused by both layers) + weight prep ----
  hipMemsetAsync(cnt, 0, (size_t)2 * N * 4, stream);
  k_prep<<<144, 256, 0, stream>>>(Wa1, Wb1, Wc1, Wd1, WaT1g, WbT1g, WcT1g, WdT1g);
  k_hist<<<(E + 255) / 256, 256, 0, stream>>>(srcI, dstI, cnt, N, E);
  k_scanA<<<2 * NB, 256, 0, stream>>>(cnt, bsum, N, NB);
  k_scanB<<<1, 256, 0, stream>>>(bsum, boff, NB);
  k_scanC<<<2 * NB, 256, 0, stream>>>(cnt, boff, row_src, row_dst, cur, N, NB);
  k_scatter<<<(E + 255) / 256, 256, 0, stream>>>(srcI, dstI, cur, eid_src, eid_dst, srcb, N, E);

  // ---------------- layer 1 ----------------
  k_gemm1<<<(N + 127) / 128, 256, 0, stream>>>(x, W1, h1, N);
  k_emlp<0><<<(E + 127) / 128, 256, 0, stream>>>(kric, WaT1g, WbT1g, bb1, ew, nullptr, E);
  k_emlp<1><<<(N + 127) / 128, 256, 0, stream>>>(epoi, WcT1g, WdT1g, bd1, nullptr, pw1, N);
  k_norm<128><<<(N + 1) / 2, 256, 0, stream>>>(row_src, eid_src, ew, h1, N);
  k_aggf<128, 1><<<(N + 1) / 2, 256, 0, stream>>>(row_dst, eid_dst, srcb, ew, h1, pw1, b1, alpha, y1, N);

  // ---------------- layer 2 ----------------
  k_gemm2<<<(N + 5) / 6, 256, 0, stream>>>(y1, W2, h2, N);
  k_mlp40<0><<<(E + 255) / 256, 256, 0, stream>>>(kric, Wa2, Wb2, bb2, ew, nullptr, E);
  k_mlp40<1><<<(N + 255) / 256, 256, 0, stream>>>(epoi, Wc2, Wd2, bd2, nullptr, pw2, N);
  k_norm<40><<<(N + 3) / 4, 256, 0, stream>>>(row_src, eid_src, ew, h2, N);
  k_aggf<40, 0><<<(N + 3) / 4, 256, 0, stream>>>(row_dst, eid_dst, srcb, ew, h2, pw2, b2, alpha, (float*)d_out, N);
}

// Round 4
// 893.745 us; speedup vs baseline: 7.9275x; 1.3789x over previous
//
#include <hip/hip_runtime.h>
#include <math.h>

#define SM_EPS 1e-16f

typedef unsigned short u16;
typedef unsigned int u32;
typedef short s16x8 __attribute__((ext_vector_type(8)));
typedef float f32x4 __attribute__((ext_vector_type(4)));

__device__ __forceinline__ u16 f2bfh(float x) {
  __bf16 b = (__bf16)x;
  return __builtin_bit_cast(unsigned short, b);
}
__device__ __forceinline__ float bf2f(u16 u) {
  return __uint_as_float(((u32)u) << 16);
}

// ---------------- h1 = x @ W1   [M,512]@[512,128] -------------------
__global__ __launch_bounds__(256) void k_gemm1(const float* __restrict__ A,
                                               const float* __restrict__ B,
                                               float* __restrict__ C, int M) {
  __shared__ float As[16][136];
  __shared__ float Bs[16][128];
  const int tid = threadIdx.x;
  const int m0 = blockIdx.x * 128;
  const int tm = tid >> 4, tn = tid & 15;
  const int am = tid & 127;
  const int akq0 = tid >> 7;
  const int row = m0 + am;
  float acc[8][8];
#pragma unroll
  for (int i = 0; i < 8; ++i)
#pragma unroll
    for (int j = 0; j < 8; ++j) acc[i][j] = 0.f;

  for (int k0 = 0; k0 < 512; k0 += 16) {
#pragma unroll
    for (int t = 0; t < 2; ++t) {
      const int kq = akq0 + 2 * t;
      float4 v = make_float4(0.f, 0.f, 0.f, 0.f);
      if (row < M) v = *reinterpret_cast<const float4*>(&A[(size_t)row * 512 + k0 + kq * 4]);
      As[kq * 4 + 0][am] = v.x; As[kq * 4 + 1][am] = v.y;
      As[kq * 4 + 2][am] = v.z; As[kq * 4 + 3][am] = v.w;
    }
#pragma unroll
    for (int t = 0; t < 2; ++t) {
      const int s = tid + 256 * t;
      const int kk = s >> 5, n4 = s & 31;
      *reinterpret_cast<float4*>(&Bs[kk][n4 * 4]) =
          *reinterpret_cast<const float4*>(&B[(size_t)(k0 + kk) * 128 + n4 * 4]);
    }
    __syncthreads();
#pragma unroll
    for (int kk = 0; kk < 16; ++kk) {
      float a[8], b[8];
      *reinterpret_cast<float4*>(&a[0]) = *reinterpret_cast<const float4*>(&As[kk][tm * 8]);
      *reinterpret_cast<float4*>(&a[4]) = *reinterpret_cast<const float4*>(&As[kk][tm * 8 + 4]);
      *reinterpret_cast<float4*>(&b[0]) = *reinterpret_cast<const float4*>(&Bs[kk][tn * 8]);
      *reinterpret_cast<float4*>(&b[4]) = *reinterpret_cast<const float4*>(&Bs[kk][tn * 8 + 4]);
#pragma unroll
      for (int i = 0; i < 8; ++i)
#pragma unroll
        for (int j = 0; j < 8; ++j) acc[i][j] = fmaf(a[i], b[j], acc[i][j]);
    }
    __syncthreads();
  }
#pragma unroll
  for (int i = 0; i < 8; ++i) {
    const int r = m0 + tm * 8 + i;
    if (r < M) {
      *reinterpret_cast<float4*>(&C[(size_t)r * 128 + tn * 8]) =
          make_float4(acc[i][0], acc[i][1], acc[i][2], acc[i][3]);
      *reinterpret_cast<float4*>(&C[(size_t)r * 128 + tn * 8 + 4]) =
          make_float4(acc[i][4], acc[i][5], acc[i][6], acc[i][7]);
    }
  }
}

// -------- weight prep: transpose + bf16 convert (once per call) --------
__global__ __launch_bounds__(256) void k_prep(const float* __restrict__ Wa,
                                              const float* __restrict__ Wb,
                                              const float* __restrict__ Wc,
                                              const float* __restrict__ Wd,
                                              u16* __restrict__ WaTg, u16* __restrict__ WbTg,
                                              u16* __restrict__ WcTg, u16* __restrict__ WdTg) {
  const int idx = blockIdx.x * 256 + threadIdx.x;
  if (idx < 2048) {
    const int n = idx >> 4, k = idx & 15;
    WaTg[idx] = f2bfh(Wa[k * 128 + n]);
  } else if (idx < 18432) {
    const int t = idx - 2048;
    const int n = t >> 7, k = t & 127;
    WbTg[t] = f2bfh(Wb[k * 128 + n]);
  } else if (idx < 20480) {
    const int t = idx - 18432;
    const int n = t >> 4, k = t & 15;
    WcTg[t] = f2bfh(Wc[k * 128 + n]);
  } else if (idx < 36864) {
    const int t = idx - 20480;
    const int n = t >> 7, k = t & 127;
    WdTg[t] = f2bfh(Wd[k * 128 + n]);
  }
}

// ------- MFMA fused 16->128->128 MLP over rows -------
// eid != nullptr: row r computes input row eid[r] (src-CSR permuted), output at r.
// MODE 0: logit -> exp -> bf16 ew store.  MODE 1: logit -> lrelu(0.01) -> f32 store.
template <int MODE>
__global__ __launch_bounds__(256) void k_emlp(
    const float* __restrict__ inp, const int* __restrict__ eid,
    const u16* __restrict__ WaTg, const u16* __restrict__ WbTg,
    const float* __restrict__ bbias,
    u16* __restrict__ ewOut, float* __restrict__ pwOut, int R) {
  __shared__ __align__(16) unsigned char sWb[32768];
  __shared__ __align__(16) unsigned char sU[32768];
  __shared__ __align__(16) u16 sWa[2048];
  const int tid = threadIdx.x;
  const int lane = tid & 63;
  const int w = tid >> 6;
  const int wr = w >> 1, wc = w & 1;
  const int lg = lane >> 4;
  const int lm = lane & 15;
  const int r0 = blockIdx.x * 128;

  {
    const int n = tid >> 1, half = tid & 1;
    *reinterpret_cast<uint4*>(&sWa[n * 16 + half * 8]) =
        *reinterpret_cast<const uint4*>(&WaTg[n * 16 + half * 8]);
  }
#pragma unroll
  for (int it = 0; it < 8; ++it) {
    const int idx = tid + it * 256;
    const int n = idx >> 4, c = idx & 15;
    const uint4 v = *reinterpret_cast<const uint4*>(&WbTg[n * 128 + c * 8]);
    *reinterpret_cast<uint4*>(&sWb[n * 256 + ((c ^ (n & 15)) << 4)]) = v;
  }

  s16x8 afr[4];
#pragma unroll
  for (int i = 0; i < 4; ++i) {
    s16x8 a = (s16x8)0;
    if (lg < 2) {
      const int r = r0 + (wr * 4 + i) * 16 + lm;
      if (r < R) {
        const int e = eid ? eid[r] : r;
        const float4 f0 = *reinterpret_cast<const float4*>(&inp[(size_t)e * 16 + lg * 8]);
        const float4 f1 = *reinterpret_cast<const float4*>(&inp[(size_t)e * 16 + lg * 8 + 4]);
        a[0] = (short)f2bfh(f0.x); a[1] = (short)f2bfh(f0.y);
        a[2] = (short)f2bfh(f0.z); a[3] = (short)f2bfh(f0.w);
        a[4] = (short)f2bfh(f1.x); a[5] = (short)f2bfh(f1.y);
        a[6] = (short)f2bfh(f1.z); a[7] = (short)f2bfh(f1.w);
      }
    }
    afr[i] = a;
  }
  __syncthreads();

  const f32x4 z4 = {0.f, 0.f, 0.f, 0.f};
  s16x8 bfr1[4];
#pragma unroll
  for (int j = 0; j < 4; ++j) {
    s16x8 b = (s16x8)0;
    if (lg < 2) {
      const int n = (wc * 4 + j) * 16 + lm;
      b = *reinterpret_cast<const s16x8*>(&sWa[n * 16 + lg * 8]);
    }
    bfr1[j] = b;
  }
  f32x4 acc1[4][4];
#pragma unroll
  for (int i = 0; i < 4; ++i)
#pragma unroll
    for (int j = 0; j < 4; ++j) acc1[i][j] = z4;
#pragma unroll
  for (int i = 0; i < 4; ++i)
#pragma unroll
    for (int j = 0; j < 4; ++j)
      acc1[i][j] = __builtin_amdgcn_mfma_f32_16x16x32_bf16(afr[i], bfr1[j], acc1[i][j], 0, 0, 0);

#pragma unroll
  for (int i = 0; i < 4; ++i) {
#pragma unroll
    for (int j = 0; j < 4; ++j) {
#pragma unroll
      for (int rr = 0; rr < 4; ++rr) {
        float v = acc1[i][j][rr];
        v = (v >= 0.f) ? v : 0.2f * v;
        const int grow = (wr * 4 + i) * 16 + lg * 4 + rr;
        const int gcol = (wc * 4 + j) * 16 + lm;
        const int byte = grow * 256 + ((((gcol >> 3) ^ (grow & 15))) << 4) + (gcol & 7) * 2;
        *reinterpret_cast<u16*>(&sU[byte]) = f2bfh(v);
      }
    }
  }
  __syncthreads();

  f32x4 acc[4][4];
#pragma unroll
  for (int i = 0; i < 4; ++i)
#pragma unroll
    for (int j = 0; j < 4; ++j) acc[i][j] = z4;
#pragma unroll
  for (int kb = 0; kb < 4; ++kb) {
    s16x8 af[4], bf_[4];
    const int ch = kb * 4 + lg;
#pragma unroll
    for (int i = 0; i < 4; ++i) {
      const int row = (wr * 4 + i) * 16 + lm;
      af[i] = *reinterpret_cast<const s16x8*>(&sU[row * 256 + ((ch ^ (row & 15)) << 4)]);
    }
#pragma unroll
    for (int j = 0; j < 4; ++j) {
      const int n = (wc * 4 + j) * 16 + lm;
      bf_[j] = *reinterpret_cast<const s16x8*>(&sWb[n * 256 + ((ch ^ (n & 15)) << 4)]);
    }
#pragma unroll
    for (int i = 0; i < 4; ++i)
#pragma unroll
      for (int j = 0; j < 4; ++j)
        acc[i][j] = __builtin_amdgcn_mfma_f32_16x16x32_bf16(af[i], bf_[j], acc[i][j], 0, 0, 0);
  }

  float bv[4];
#pragma unroll
  for (int j = 0; j < 4; ++j) bv[j] = bbias[(wc * 4 + j) * 16 + lm];
#pragma unroll
  for (int i = 0; i < 4; ++i) {
#pragma unroll
    for (int rr = 0; rr < 4; ++rr) {
      const int grow = r0 + (wr * 4 + i) * 16 + lg * 4 + rr;
      if (grow < R) {
        if (MODE == 0) {
#pragma unroll
          for (int j = 0; j < 4; ++j) {
            const float v = __expf(acc[i][j][rr] + bv[j]);
            ewOut[(size_t)grow * 128 + (wc * 4 + j) * 16 + lm] = f2bfh(v);
          }
        } else {
#pragma unroll
          for (int j = 0; j < 4; ++j) {
            float v = acc[i][j][rr] + bv[j];
            v = (v >= 0.f) ? v : 0.01f * v;
            pwOut[(size_t)grow * 128 + (wc * 4 + j) * 16 + lm] = v;
          }
        }
      }
    }
  }
}

// ------------- fused 16->40->40 MLP, one row per thread ----------
template <int MODE>
__global__ __launch_bounds__(256) void k_mlp40(
    const float* __restrict__ inp, const int* __restrict__ eid,
    const float* __restrict__ Wa, const float* __restrict__ Wb,
    const float* __restrict__ bbias, u16* __restrict__ ewOut,
    float* __restrict__ pwOut, int R) {
  __shared__ float Wa_s[16 * 40];
  __shared__ float Wb_s[40 * 40];
  __shared__ float bb_s[40];
  const int tid = threadIdx.x;
  for (int i = tid; i < 640; i += 256) Wa_s[i] = Wa[i];
  for (int i = tid; i < 1600; i += 256) Wb_s[i] = Wb[i];
  if (tid < 40) bb_s[tid] = bbias[tid];
  __syncthreads();
  const int r = blockIdx.x * 256 + tid;
  if (r >= R) return;
  const int e = eid ? eid[r] : r;

  float kreg[16];
#pragma unroll
  for (int t = 0; t < 4; ++t)
    *reinterpret_cast<float4*>(&kreg[t * 4]) =
        *reinterpret_cast<const float4*>(&inp[(size_t)e * 16 + t * 4]);

  float u[40];
#pragma unroll
  for (int c = 0; c < 40; ++c) u[c] = 0.f;
#pragma unroll
  for (int j = 0; j < 16; ++j) {
    const float kj = kreg[j];
#pragma unroll
    for (int c4 = 0; c4 < 10; ++c4) {
      const float4 w = *reinterpret_cast<const float4*>(&Wa_s[j * 40 + c4 * 4]);
      u[c4 * 4 + 0] = fmaf(kj, w.x, u[c4 * 4 + 0]);
      u[c4 * 4 + 1] = fmaf(kj, w.y, u[c4 * 4 + 1]);
      u[c4 * 4 + 2] = fmaf(kj, w.z, u[c4 * 4 + 2]);
      u[c4 * 4 + 3] = fmaf(kj, w.w, u[c4 * 4 + 3]);
    }
  }
#pragma unroll
  for (int c = 0; c < 40; ++c) u[c] = (u[c] >= 0.f) ? u[c] : 0.2f * u[c];

  float o[40];
#pragma unroll
  for (int c = 0; c < 40; ++c) o[c] = bb_s[c];
#pragma unroll
  for (int j = 0; j < 40; ++j) {
    const float uj = u[j];
#pragma unroll
    for (int c4 = 0; c4 < 10; ++c4) {
      const float4 w = *reinterpret_cast<const float4*>(&Wb_s[j * 40 + c4 * 4]);
      o[c4 * 4 + 0] = fmaf(uj, w.x, o[c4 * 4 + 0]);
      o[c4 * 4 + 1] = fmaf(uj, w.y, o[c4 * 4 + 1]);
      o[c4 * 4 + 2] = fmaf(uj, w.z, o[c4 * 4 + 2]);
      o[c4 * 4 + 3] = fmaf(uj, w.w, o[c4 * 4 + 3]);
    }
  }
  if (MODE == 0) {
#pragma unroll
    for (int c = 0; c < 40; ++c) o[c] = __expf(o[c]);
#pragma unroll
    for (int c2 = 0; c2 < 20; ++c2) {
      u32 pk = (u32)f2bfh(o[2 * c2]) | ((u32)f2bfh(o[2 * c2 + 1]) << 16);
      *reinterpret_cast<u32*>(&ewOut[(size_t)r * 40 + c2 * 2]) = pk;
    }
  } else {
#pragma unroll
    for (int c = 0; c < 40; ++c) { float v = o[c]; o[c] = (v >= 0.f) ? v : 0.01f * v; }
#pragma unroll
    for (int c4 = 0; c4 < 10; ++c4)
      *reinterpret_cast<float4*>(&pwOut[(size_t)r * 40 + c4 * 4]) =
          make_float4(o[c4 * 4], o[c4 * 4 + 1], o[c4 * 4 + 2], o[c4 * 4 + 3]);
  }
}

// ------------- h2 = y1 @ W2  [M,128]@[128,40] ----------
__global__ __launch_bounds__(256) void k_gemm2(const float* __restrict__ A,
                                               const float* __restrict__ B,
                                               float* __restrict__ C, int M) {
  __shared__ float Bs[128 * 40];
  const int tid = threadIdx.x;
  for (int i = tid; i < 5120; i += 256) Bs[i] = B[i];
  __syncthreads();
  const int r = blockIdx.x * 6 + tid / 40;
  const int c = tid % 40;
  if (tid >= 240 || r >= M) return;
  const float* arow = &A[(size_t)r * 128];
  float acc = 0.f;
#pragma unroll
  for (int k4 = 0; k4 < 32; ++k4) {
    const float4 av = *reinterpret_cast<const float4*>(&arow[k4 * 4]);
    acc = fmaf(av.x, Bs[(k4 * 4 + 0) * 40 + c], acc);
    acc = fmaf(av.y, Bs[(k4 * 4 + 1) * 40 + c], acc);
    acc = fmaf(av.z, Bs[(k4 * 4 + 2) * 40 + c], acc);
    acc = fmaf(av.w, Bs[(k4 * 4 + 3) * 40 + c], acc);
  }
  C[(size_t)r * 40 + c] = acc;
}

// ================= CSR build =================
__global__ __launch_bounds__(256) void k_hist(const int* __restrict__ src,
                                              const int* __restrict__ dst,
                                              int* __restrict__ cnt, int N, int E) {
  const int e = blockIdx.x * 256 + threadIdx.x;
  if (e >= E) return;
  atomicAdd(&cnt[src[e]], 1);
  atomicAdd(&cnt[N + dst[e]], 1);
}

__global__ __launch_bounds__(256) void k_scanA(const int* __restrict__ cnt,
                                               int* __restrict__ bsum, int N, int NB) {
  const int arr = blockIdx.x / NB, bb = blockIdx.x % NB;
  const int g = bb * 256 + threadIdx.x;
  int v = (g < N) ? cnt[arr * N + g] : 0;
  __shared__ int sd[256];
  sd[threadIdx.x] = v;
  __syncthreads();
  for (int off = 128; off > 0; off >>= 1) {
    if (threadIdx.x < off) sd[threadIdx.x] += sd[threadIdx.x + off];
    __syncthreads();
  }
  if (threadIdx.x == 0) bsum[arr * 256 + bb] = sd[0];
}

__global__ __launch_bounds__(256) void k_scanB(const int* __restrict__ bsum,
                                               int* __restrict__ boff, int NB) {
  __shared__ int sd[256];
  for (int arr = 0; arr < 2; ++arr) {
    const int v = (threadIdx.x < NB) ? bsum[arr * 256 + threadIdx.x] : 0;
    sd[threadIdx.x] = v;
    __syncthreads();
    for (int off = 1; off < 256; off <<= 1) {
      const int t = (threadIdx.x >= off) ? sd[threadIdx.x - off] : 0;
      __syncthreads();
      sd[threadIdx.x] += t;
      __syncthreads();
    }
    if (threadIdx.x < NB) boff[arr * 256 + threadIdx.x] = sd[threadIdx.x] - v;
    __syncthreads();
  }
}

__global__ __launch_bounds__(256) void k_scanC(const int* __restrict__ cnt,
                                               const int* __restrict__ boff,
                                               int* __restrict__ row_src,
                                               int* __restrict__ row_dst,
                                               int* __restrict__ cur, int N, int NB) {
  const int arr = blockIdx.x / NB, bb = blockIdx.x % NB;
  const int g = bb * 256 + threadIdx.x;
  const int v = (g < N) ? cnt[arr * N + g] : 0;
  __shared__ int sd[256];
  sd[threadIdx.x] = v;
  __syncthreads();
  for (int off = 1; off < 256; off <<= 1) {
    const int t = (threadIdx.x >= off) ? sd[threadIdx.x - off] : 0;
    __syncthreads();
    sd[threadIdx.x] += t;
    __syncthreads();
  }
  const int incl = sd[threadIdx.x];
  const int base = boff[arr * 256 + bb];
  int* row = arr ? row_dst : row_src;
  if (g < N) {
    row[g] = base + incl - v;
    cur[arr * N + g] = base + incl - v;
    if (g == N - 1) row[N] = base + incl;
  }
}

// per-edge: ps = src-order position, pd = dst-order position
__global__ __launch_bounds__(256) void k_scatter(const int* __restrict__ src,
                                                 const int* __restrict__ dst,
                                                 int* __restrict__ cur,
                                                 int* __restrict__ eid_src,
                                                 int* __restrict__ possD,
                                                 int* __restrict__ srcb, int N, int E) {
  const int e = blockIdx.x * 256 + threadIdx.x;
  if (e >= E) return;
  const int s = src[e], d = dst[e];
  const int ps = atomicAdd(&cur[s], 1);
  eid_src[ps] = e;
  const int pd = atomicAdd(&cur[N + d], 1);
  possD[pd] = ps;
  srcb[pd] = s;
}

// ===== streaming: s = sum of ew rows [r0,r1) (src-CSR-ordered), g = h/(s+eps) =====
template <int C>
__global__ __launch_bounds__(256) void k_norm(const int* __restrict__ rowp,
                                              const u16* __restrict__ ew,
                                              float* __restrict__ h, int N) {
  const int lane = threadIdx.x & 63;
  const int wv = threadIdx.x >> 6;
  const int n = blockIdx.x * 4 + wv;
  if (n >= N) return;
  constexpr int CPL = (C == 128) ? 2 : 1;
  const int c0 = lane * CPL;
  if (c0 >= C) return;
  const int r0 = rowp[n], r1 = rowp[n + 1];
  float a0 = 0.f, a1 = 0.f;
  int p = r0;
  if (CPL == 2) {
    for (; p + 2 <= r1; p += 2) {
      const u32 w0 = *reinterpret_cast<const u32*>(&ew[(size_t)p * C + c0]);
      const u32 w1 = *reinterpret_cast<const u32*>(&ew[(size_t)(p + 1) * C + c0]);
      a0 += bf2f((u16)(w0 & 0xffffu)) + bf2f((u16)(w1 & 0xffffu));
      a1 += bf2f((u16)(w0 >> 16)) + bf2f((u16)(w1 >> 16));
    }
    for (; p < r1; ++p) {
      const u32 w0 = *reinterpret_cast<const u32*>(&ew[(size_t)p * C + c0]);
      a0 += bf2f((u16)(w0 & 0xffffu));
      a1 += bf2f((u16)(w0 >> 16));
    }
    float2 hv = *reinterpret_cast<const float2*>(&h[(size_t)n * C + c0]);
    hv.x /= (a0 + SM_EPS);
    hv.y /= (a1 + SM_EPS);
    *reinterpret_cast<float2*>(&h[(size_t)n * C + c0]) = hv;
  } else {
    for (; p + 2 <= r1; p += 2)
      a0 += bf2f(ew[(size_t)p * C + c0]) + bf2f(ew[(size_t)(p + 1) * C + c0]);
    for (; p < r1; ++p) a0 += bf2f(ew[(size_t)p * C + c0]);
    h[(size_t)n * C + c0] /= (a0 + SM_EPS);
  }
}

// ===== out[n] = sum_{in-edges} ew[poss[p]] * g[srcb[p]] + b + alpha*pw, opt ELU =====
template <int C, int DO_ELU>
__global__ __launch_bounds__(256) void k_aggf(const int* __restrict__ rowp,
                                              const int* __restrict__ poss,
                                              const int* __restrict__ srcb,
                                              const u16* __restrict__ ew,
                                              const float* __restrict__ g,
                                              const float* __restrict__ pw,
                                              const float* __restrict__ bias,
                                              const float* __restrict__ alpha_p,
                                              float* __restrict__ out, int N) {
  const int lane = threadIdx.x & 63;
  const int wv = threadIdx.x >> 6;
  const int n = blockIdx.x * 4 + wv;
  if (n >= N) return;
  constexpr int CPL = (C == 128) ? 2 : 1;
  const int c0 = lane * CPL;
  if (c0 >= C) return;
  const int r0 = rowp[n], r1 = rowp[n + 1];
  float a0 = 0.f, a1 = 0.f;
  int p = r0;
  if (CPL == 2) {
    for (; p + 4 <= r1; p += 4) {
      const int s0 = srcb[p + 0], s1 = srcb[p + 1], s2 = srcb[p + 2], s3 = srcb[p + 3];
      const int q0 = poss[p + 0], q1 = poss[p + 1], q2 = poss[p + 2], q3 = poss[p + 3];
      const u32 w0 = *reinterpret_cast<const u32*>(&ew[(size_t)q0 * C + c0]);
      const u32 w1 = *reinterpret_cast<const u32*>(&ew[(size_t)q1 * C + c0]);
      const u32 w2 = *reinterpret_cast<const u32*>(&ew[(size_t)q2 * C + c0]);
      const u32 w3 = *reinterpret_cast<const u32*>(&ew[(size_t)q3 * C + c0]);
      const float2 g0 = *reinterpret_cast<const float2*>(&g[(size_t)s0 * C + c0]);
      const float2 g1 = *reinterpret_cast<const float2*>(&g[(size_t)s1 * C + c0]);
      const float2 g2 = *reinterpret_cast<const float2*>(&g[(size_t)s2 * C + c0]);
      const float2 g3 = *reinterpret_cast<const float2*>(&g[(size_t)s3 * C + c0]);
      a0 = fmaf(bf2f((u16)(w0 & 0xffffu)), g0.x, a0);
      a1 = fmaf(bf2f((u16)(w0 >> 16)), g0.y, a1);
      a0 = fmaf(bf2f((u16)(w1 & 0xffffu)), g1.x, a0);
      a1 = fmaf(bf2f((u16)(w1 >> 16)), g1.y, a1);
      a0 = fmaf(bf2f((u16)(w2 & 0xffffu)), g2.x, a0);
      a1 = fmaf(bf2f((u16)(w2 >> 16)), g2.y, a1);
      a0 = fmaf(bf2f((u16)(w3 & 0xffffu)), g3.x, a0);
      a1 = fmaf(bf2f((u16)(w3 >> 16)), g3.y, a1);
    }
    for (; p < r1; ++p) {
      const int s0 = srcb[p];
      const int q0 = poss[p];
      const u32 w0 = *reinterpret_cast<const u32*>(&ew[(size_t)q0 * C + c0]);
      const float2 g0 = *reinterpret_cast<const float2*>(&g[(size_t)s0 * C + c0]);
      a0 = fmaf(bf2f((u16)(w0 & 0xffffu)), g0.x, a0);
      a1 = fmaf(bf2f((u16)(w0 >> 16)), g0.y, a1);
    }
    const float al = alpha_p[0];
    const float2 pv = *reinterpret_cast<const float2*>(&pw[(size_t)n * C + c0]);
    float v0 = a0 + bias[c0] + al * pv.x;
    float v1 = a1 + bias[c0 + 1] + al * pv.y;
    if (DO_ELU) {
      v0 = (v0 > 0.f) ? v0 : expm1f(v0);
      v1 = (v1 > 0.f) ? v1 : expm1f(v1);
    }
    *reinterpret_cast<float2*>(&out[(size_t)n * C + c0]) = make_float2(v0, v1);
  } else {
    for (; p + 4 <= r1; p += 4) {
      const int s0 = srcb[p + 0], s1 = srcb[p + 1], s2 = srcb[p + 2], s3 = srcb[p + 3];
      const int q0 = poss[p + 0], q1 = poss[p + 1], q2 = poss[p + 2], q3 = poss[p + 3];
      const float w0 = bf2f(ew[(size_t)q0 * C + c0]);
      const float w1 = bf2f(ew[(size_t)q1 * C + c0]);
      const float w2 = bf2f(ew[(size_t)q2 * C + c0]);
      const float w3 = bf2f(ew[(size_t)q3 * C + c0]);
      const float g0 = g[(size_t)s0 * C + c0];
      const float g1 = g[(size_t)s1 * C + c0];
      const float g2 = g[(size_t)s2 * C + c0];
      const float g3 = g[(size_t)s3 * C + c0];
      a0 = fmaf(w0, g0, a0);
      a0 = fmaf(w1, g1, a0);
      a0 = fmaf(w2, g2, a0);
      a0 = fmaf(w3, g3, a0);
    }
    for (; p < r1; ++p)
      a0 = fmaf(bf2f(ew[(size_t)poss[p] * C + c0]), g[(size_t)srcb[p] * C + c0], a0);
    float v = a0 + bias[c0] + alpha_p[0] * pw[(size_t)n * C + c0];
    if (DO_ELU) v = (v > 0.f) ? v : expm1f(v);
    out[(size_t)n * C + c0] = v;
  }
}

extern "C" void kernel_launch(void* const* d_in, const int* in_sizes, int n_in,
                              void* d_out, int out_size, void* d_ws, size_t ws_size,
                              hipStream_t stream) {
  const float* x    = (const float*)d_in[0];
  const int*   ei   = (const int*)d_in[1];
  const float* kric = (const float*)d_in[2];
  const float* epoi = (const float*)d_in[3];
  const float* alpha= (const float*)d_in[4];
  const float* W1   = (const float*)d_in[5];
  const float* Wa1  = (const float*)d_in[6];
  const float* Wb1  = (const float*)d_in[7];
  const float* bb1  = (const float*)d_in[8];
  const float* Wc1  = (const float*)d_in[9];
  const float* Wd1  = (const float*)d_in[10];
  const float* bd1  = (const float*)d_in[11];
  const float* b1   = (const float*)d_in[12];
  const float* W2   = (const float*)d_in[13];
  const float* Wa2  = (const float*)d_in[14];
  const float* Wb2  = (const float*)d_in[15];
  const float* bb2  = (const float*)d_in[16];
  const float* Wc2  = (const float*)d_in[17];
  const float* Wd2  = (const float*)d_in[18];
  const float* bd2  = (const float*)d_in[19];
  const float* b2   = (const float*)d_in[20];

  const int N = in_sizes[0] / 512;
  const int E = in_sizes[1] / 2;
  const int* srcI = ei;
  const int* dstI = ei + E;
  const int NB = (N + 255) / 256;

  // ---- workspace layout ----
  char* p = (char*)d_ws;
  int* cnt      = (int*)p; p += (size_t)2 * N * 4;
  int* cur      = (int*)p; p += (size_t)2 * N * 4;
  int* bsum     = (int*)p; p += 512 * 4;
  int* boff     = (int*)p; p += 512 * 4;
  int* row_src  = (int*)p; p += (size_t)(N + 1) * 4;
  int* row_dst  = (int*)p; p += (size_t)(N + 1) * 4;
  int* eid_src  = (int*)p; p += (size_t)E * 4;
  int* possD    = (int*)p; p += (size_t)E * 4;
  int* srcb     = (int*)p; p += (size_t)E * 4;
  p = (char*)(((uintptr_t)p + 255) & ~(uintptr_t)255);
  u16* WaT1g = (u16*)p; p += 2048 * 2;
  u16* WbT1g = (u16*)p; p += 16384 * 2;
  u16* WcT1g = (u16*)p; p += 2048 * 2;
  u16* WdT1g = (u16*)p; p += 16384 * 2;
  p = (char*)(((uintptr_t)p + 255) & ~(uintptr_t)255);
  float* h1  = (float*)p; p += (size_t)N * 128 * 4;  // becomes g1 in place
  float* y1  = (float*)p; p += (size_t)N * 128 * 4;
  float* h2  = (float*)p; p += (size_t)N * 40 * 4;   // becomes g2 in place
  float* pw1 = (float*)p; p += (size_t)N * 128 * 4;
  float* pw2 = (float*)p; p += (size_t)N * 40 * 4;
  u16* ew    = (u16*)p;  // E*128 bf16 (layer 1), reused E*40 (layer 2); src-CSR order

  // ---- CSR build (once, reused by both layers) + weight prep ----
  hipMemsetAsync(cnt, 0, (size_t)2 * N * 4, stream);
  k_prep<<<144, 256, 0, stream>>>(Wa1, Wb1, Wc1, Wd1, WaT1g, WbT1g, WcT1g, WdT1g);
  k_hist<<<(E + 255) / 256, 256, 0, stream>>>(srcI, dstI, cnt, N, E);
  k_scanA<<<2 * NB, 256, 0, stream>>>(cnt, bsum, N, NB);
  k_scanB<<<1, 256, 0, stream>>>(bsum, boff, NB);
  k_scanC<<<2 * NB, 256, 0, stream>>>(cnt, boff, row_src, row_dst, cur, N, NB);
  k_scatter<<<(E + 255) / 256, 256, 0, stream>>>(srcI, dstI, cur, eid_src, possD, srcb, N, E);

  // ---------------- layer 1 ----------------
  k_gemm1<<<(N + 127) / 128, 256, 0, stream>>>(x, W1, h1, N);
  k_emlp<0><<<(E + 127) / 128, 256, 0, stream>>>(kric, eid_src, WaT1g, WbT1g, bb1, ew, nullptr, E);
  k_emlp<1><<<(N + 127) / 128, 256, 0, stream>>>(epoi, nullptr, WcT1g, WdT1g, bd1, nullptr, pw1, N);
  k_norm<128><<<(N + 3) / 4, 256, 0, stream>>>(row_src, ew, h1, N);
  k_aggf<128, 1><<<(N + 3) / 4, 256, 0, stream>>>(row_dst, possD, srcb, ew, h1, pw1, b1, alpha, y1, N);

  // ---------------- layer 2 ----------------
  k_gemm2<<<(N + 5) / 6, 256, 0, stream>>>(y1, W2, h2, N);
  k_mlp40<0><<<(E + 255) / 256, 256, 0, stream>>>(kric, eid_src, Wa2, Wb2, bb2, ew, nullptr, E);
  k_mlp40<1><<<(N + 255) / 256, 256, 0, stream>>>(epoi, nullptr, Wc2, Wd2, bd2, nullptr, pw2, N);
  k_norm<40><<<(N + 3) / 4, 256, 0, stream>>>(row_src, ew, h2, N);
  k_aggf<40, 0><<<(N + 3) / 4, 256, 0, stream>>>(row_dst, possD, srcb, ew, h2, pw2, b2, alpha, (float*)d_out, N);
}

// Round 5
// 881.893 us; speedup vs baseline: 8.0340x; 1.0134x over previous
//
#include <hip/hip_runtime.h>
#include <math.h>

#define SM_EPS 1e-16f

typedef unsigned short u16;
typedef unsigned int u32;
typedef short s16x8 __attribute__((ext_vector_type(8)));
typedef float f32x4 __attribute__((ext_vector_type(4)));

__device__ __forceinline__ u16 f2bfh(float x) {
  __bf16 b = (__bf16)x;
  return __builtin_bit_cast(unsigned short, b);
}
__device__ __forceinline__ float bf2f(u16 u) {
  return __uint_as_float(((u32)u) << 16);
}

// ---------------- h1 = x @ W1   [M,512]@[512,128] -------------------
__global__ __launch_bounds__(256) void k_gemm1(const float* __restrict__ A,
                                               const float* __restrict__ B,
                                               float* __restrict__ C, int M) {
  __shared__ float As[16][136];
  __shared__ float Bs[16][128];
  const int tid = threadIdx.x;
  const int m0 = blockIdx.x * 128;
  const int tm = tid >> 4, tn = tid & 15;
  const int am = tid & 127;
  const int akq0 = tid >> 7;
  const int row = m0 + am;
  float acc[8][8];
#pragma unroll
  for (int i = 0; i < 8; ++i)
#pragma unroll
    for (int j = 0; j < 8; ++j) acc[i][j] = 0.f;

  for (int k0 = 0; k0 < 512; k0 += 16) {
#pragma unroll
    for (int t = 0; t < 2; ++t) {
      const int kq = akq0 + 2 * t;
      float4 v = make_float4(0.f, 0.f, 0.f, 0.f);
      if (row < M) v = *reinterpret_cast<const float4*>(&A[(size_t)row * 512 + k0 + kq * 4]);
      As[kq * 4 + 0][am] = v.x; As[kq * 4 + 1][am] = v.y;
      As[kq * 4 + 2][am] = v.z; As[kq * 4 + 3][am] = v.w;
    }
#pragma unroll
    for (int t = 0; t < 2; ++t) {
      const int s = tid + 256 * t;
      const int kk = s >> 5, n4 = s & 31;
      *reinterpret_cast<float4*>(&Bs[kk][n4 * 4]) =
          *reinterpret_cast<const float4*>(&B[(size_t)(k0 + kk) * 128 + n4 * 4]);
    }
    __syncthreads();
#pragma unroll
    for (int kk = 0; kk < 16; ++kk) {
      float a[8], b[8];
      *reinterpret_cast<float4*>(&a[0]) = *reinterpret_cast<const float4*>(&As[kk][tm * 8]);
      *reinterpret_cast<float4*>(&a[4]) = *reinterpret_cast<const float4*>(&As[kk][tm * 8 + 4]);
      *reinterpret_cast<float4*>(&b[0]) = *reinterpret_cast<const float4*>(&Bs[kk][tn * 8]);
      *reinterpret_cast<float4*>(&b[4]) = *reinterpret_cast<const float4*>(&Bs[kk][tn * 8 + 4]);
#pragma unroll
      for (int i = 0; i < 8; ++i)
#pragma unroll
        for (int j = 0; j < 8; ++j) acc[i][j] = fmaf(a[i], b[j], acc[i][j]);
    }
    __syncthreads();
  }
#pragma unroll
  for (int i = 0; i < 8; ++i) {
    const int r = m0 + tm * 8 + i;
    if (r < M) {
      *reinterpret_cast<float4*>(&C[(size_t)r * 128 + tn * 8]) =
          make_float4(acc[i][0], acc[i][1], acc[i][2], acc[i][3]);
      *reinterpret_cast<float4*>(&C[(size_t)r * 128 + tn * 8 + 4]) =
          make_float4(acc[i][4], acc[i][5], acc[i][6], acc[i][7]);
    }
  }
}

// -------- weight prep: transpose + bf16 convert (once per call) --------
__global__ __launch_bounds__(256) void k_prep(const float* __restrict__ Wa,
                                              const float* __restrict__ Wb,
                                              const float* __restrict__ Wc,
                                              const float* __restrict__ Wd,
                                              u16* __restrict__ WaTg, u16* __restrict__ WbTg,
                                              u16* __restrict__ WcTg, u16* __restrict__ WdTg) {
  const int idx = blockIdx.x * 256 + threadIdx.x;
  if (idx < 2048) {
    const int n = idx >> 4, k = idx & 15;
    WaTg[idx] = f2bfh(Wa[k * 128 + n]);
  } else if (idx < 18432) {
    const int t = idx - 2048;
    const int n = t >> 7, k = t & 127;
    WbTg[t] = f2bfh(Wb[k * 128 + n]);
  } else if (idx < 20480) {
    const int t = idx - 18432;
    const int n = t >> 4, k = t & 15;
    WcTg[t] = f2bfh(Wc[k * 128 + n]);
  } else if (idx < 36864) {
    const int t = idx - 20480;
    const int n = t >> 7, k = t & 127;
    WdTg[t] = f2bfh(Wd[k * 128 + n]);
  }
}

// ------- MFMA fused 16->128->128 MLP over rows -------
// eid != nullptr: row r computes input row eid[r] (src-CSR permuted), output at r.
// MODE 0: logit -> exp -> bf16 ew store.  MODE 1: logit -> lrelu(0.01) -> f32 store.
// Weights read directly from global (L2-resident); only the U transpose uses LDS.
template <int MODE>
__global__ __launch_bounds__(256) void k_emlp(
    const float* __restrict__ inp, const int* __restrict__ eid,
    const u16* __restrict__ WaTg, const u16* __restrict__ WbTg,
    const float* __restrict__ bbias,
    u16* __restrict__ ewOut, float* __restrict__ pwOut, int R) {
  __shared__ __align__(16) unsigned char sU[32768];
  const int tid = threadIdx.x;
  const int lane = tid & 63;
  const int w = tid >> 6;
  const int wr = w >> 1, wc = w & 1;
  const int lg = lane >> 4;
  const int lm = lane & 15;
  const int r0 = blockIdx.x * 128;

  // ---- stage-1 A frags from global (K=16 zero-padded to 32) ----
  s16x8 afr[4];
#pragma unroll
  for (int i = 0; i < 4; ++i) {
    s16x8 a = (s16x8)0;
    if (lg < 2) {
      const int r = r0 + (wr * 4 + i) * 16 + lm;
      if (r < R) {
        const int e = eid ? eid[r] : r;
        const float4 f0 = *reinterpret_cast<const float4*>(&inp[(size_t)e * 16 + lg * 8]);
        const float4 f1 = *reinterpret_cast<const float4*>(&inp[(size_t)e * 16 + lg * 8 + 4]);
        a[0] = (short)f2bfh(f0.x); a[1] = (short)f2bfh(f0.y);
        a[2] = (short)f2bfh(f0.z); a[3] = (short)f2bfh(f0.w);
        a[4] = (short)f2bfh(f1.x); a[5] = (short)f2bfh(f1.y);
        a[6] = (short)f2bfh(f1.z); a[7] = (short)f2bfh(f1.w);
      }
    }
    afr[i] = a;
  }

  // ---- stage-1 B frags direct from global (Wa: [128][16] bf16) ----
  const f32x4 z4 = {0.f, 0.f, 0.f, 0.f};
  s16x8 bfr1[4];
#pragma unroll
  for (int j = 0; j < 4; ++j) {
    s16x8 b = (s16x8)0;
    if (lg < 2) {
      const int n = (wc * 4 + j) * 16 + lm;
      b = *reinterpret_cast<const s16x8*>(&WaTg[n * 16 + lg * 8]);
    }
    bfr1[j] = b;
  }

  // ---- stage 1: U = lrelu(K @ Wa) ----
  f32x4 acc1[4][4];
#pragma unroll
  for (int i = 0; i < 4; ++i)
#pragma unroll
    for (int j = 0; j < 4; ++j) acc1[i][j] = z4;
#pragma unroll
  for (int i = 0; i < 4; ++i)
#pragma unroll
    for (int j = 0; j < 4; ++j)
      acc1[i][j] = __builtin_amdgcn_mfma_f32_16x16x32_bf16(afr[i], bfr1[j], acc1[i][j], 0, 0, 0);

  // write U to LDS (bf16, XOR-16 swizzled); C layout: col=lane&15, row=(lane>>4)*4+reg
#pragma unroll
  for (int i = 0; i < 4; ++i) {
#pragma unroll
    for (int j = 0; j < 4; ++j) {
#pragma unroll
      for (int rr = 0; rr < 4; ++rr) {
        float v = acc1[i][j][rr];
        v = (v >= 0.f) ? v : 0.2f * v;
        const int grow = (wr * 4 + i) * 16 + lg * 4 + rr;
        const int gcol = (wc * 4 + j) * 16 + lm;
        const int byte = grow * 256 + ((((gcol >> 3) ^ (grow & 15))) << 4) + (gcol & 7) * 2;
        *reinterpret_cast<u16*>(&sU[byte]) = f2bfh(v);
      }
    }
  }
  __syncthreads();

  // ---- stage 2: logit = U @ Wb (A from LDS, B direct from global L2) ----
  f32x4 acc[4][4];
#pragma unroll
  for (int i = 0; i < 4; ++i)
#pragma unroll
    for (int j = 0; j < 4; ++j) acc[i][j] = z4;
#pragma unroll
  for (int kb = 0; kb < 4; ++kb) {
    s16x8 af[4], bf_[4];
    const int ch = kb * 4 + lg;
#pragma unroll
    for (int j = 0; j < 4; ++j) {
      const int n = (wc * 4 + j) * 16 + lm;
      bf_[j] = *reinterpret_cast<const s16x8*>(&WbTg[n * 128 + ch * 8]);
    }
#pragma unroll
    for (int i = 0; i < 4; ++i) {
      const int row = (wr * 4 + i) * 16 + lm;
      af[i] = *reinterpret_cast<const s16x8*>(&sU[row * 256 + ((ch ^ (row & 15)) << 4)]);
    }
#pragma unroll
    for (int i = 0; i < 4; ++i)
#pragma unroll
      for (int j = 0; j < 4; ++j)
        acc[i][j] = __builtin_amdgcn_mfma_f32_16x16x32_bf16(af[i], bf_[j], acc[i][j], 0, 0, 0);
  }

  // ---- epilogue ----
  float bv[4];
#pragma unroll
  for (int j = 0; j < 4; ++j) bv[j] = bbias[(wc * 4 + j) * 16 + lm];
#pragma unroll
  for (int i = 0; i < 4; ++i) {
#pragma unroll
    for (int rr = 0; rr < 4; ++rr) {
      const int grow = r0 + (wr * 4 + i) * 16 + lg * 4 + rr;
      if (grow < R) {
        if (MODE == 0) {
#pragma unroll
          for (int j = 0; j < 4; ++j) {
            const float v = __expf(acc[i][j][rr] + bv[j]);
            ewOut[(size_t)grow * 128 + (wc * 4 + j) * 16 + lm] = f2bfh(v);
          }
        } else {
#pragma unroll
          for (int j = 0; j < 4; ++j) {
            float v = acc[i][j][rr] + bv[j];
            v = (v >= 0.f) ? v : 0.01f * v;
            pwOut[(size_t)grow * 128 + (wc * 4 + j) * 16 + lm] = v;
          }
        }
      }
    }
  }
}

// ------------- fused 16->40->40 MLP, one row per thread ----------
template <int MODE>
__global__ __launch_bounds__(256) void k_mlp40(
    const float* __restrict__ inp, const int* __restrict__ eid,
    const float* __restrict__ Wa, const float* __restrict__ Wb,
    const float* __restrict__ bbias, u16* __restrict__ ewOut,
    float* __restrict__ pwOut, int R) {
  __shared__ float Wa_s[16 * 40];
  __shared__ float Wb_s[40 * 40];
  __shared__ float bb_s[40];
  const int tid = threadIdx.x;
  for (int i = tid; i < 640; i += 256) Wa_s[i] = Wa[i];
  for (int i = tid; i < 1600; i += 256) Wb_s[i] = Wb[i];
  if (tid < 40) bb_s[tid] = bbias[tid];
  __syncthreads();
  const int r = blockIdx.x * 256 + tid;
  if (r >= R) return;
  const int e = eid ? eid[r] : r;

  float kreg[16];
#pragma unroll
  for (int t = 0; t < 4; ++t)
    *reinterpret_cast<float4*>(&kreg[t * 4]) =
        *reinterpret_cast<const float4*>(&inp[(size_t)e * 16 + t * 4]);

  float u[40];
#pragma unroll
  for (int c = 0; c < 40; ++c) u[c] = 0.f;
#pragma unroll
  for (int j = 0; j < 16; ++j) {
    const float kj = kreg[j];
#pragma unroll
    for (int c4 = 0; c4 < 10; ++c4) {
      const float4 w = *reinterpret_cast<const float4*>(&Wa_s[j * 40 + c4 * 4]);
      u[c4 * 4 + 0] = fmaf(kj, w.x, u[c4 * 4 + 0]);
      u[c4 * 4 + 1] = fmaf(kj, w.y, u[c4 * 4 + 1]);
      u[c4 * 4 + 2] = fmaf(kj, w.z, u[c4 * 4 + 2]);
      u[c4 * 4 + 3] = fmaf(kj, w.w, u[c4 * 4 + 3]);
    }
  }
#pragma unroll
  for (int c = 0; c < 40; ++c) u[c] = (u[c] >= 0.f) ? u[c] : 0.2f * u[c];

  float o[40];
#pragma unroll
  for (int c = 0; c < 40; ++c) o[c] = bb_s[c];
#pragma unroll
  for (int j = 0; j < 40; ++j) {
    const float uj = u[j];
#pragma unroll
    for (int c4 = 0; c4 < 10; ++c4) {
      const float4 w = *reinterpret_cast<const float4*>(&Wb_s[j * 40 + c4 * 4]);
      o[c4 * 4 + 0] = fmaf(uj, w.x, o[c4 * 4 + 0]);
      o[c4 * 4 + 1] = fmaf(uj, w.y, o[c4 * 4 + 1]);
      o[c4 * 4 + 2] = fmaf(uj, w.z, o[c4 * 4 + 2]);
      o[c4 * 4 + 3] = fmaf(uj, w.w, o[c4 * 4 + 3]);
    }
  }
  if (MODE == 0) {
#pragma unroll
    for (int c = 0; c < 40; ++c) o[c] = __expf(o[c]);
#pragma unroll
    for (int c2 = 0; c2 < 20; ++c2) {
      u32 pk = (u32)f2bfh(o[2 * c2]) | ((u32)f2bfh(o[2 * c2 + 1]) << 16);
      *reinterpret_cast<u32*>(&ewOut[(size_t)r * 40 + c2 * 2]) = pk;
    }
  } else {
#pragma unroll
    for (int c = 0; c < 40; ++c) { float v = o[c]; o[c] = (v >= 0.f) ? v : 0.01f * v; }
#pragma unroll
    for (int c4 = 0; c4 < 10; ++c4)
      *reinterpret_cast<float4*>(&pwOut[(size_t)r * 40 + c4 * 4]) =
          make_float4(o[c4 * 4], o[c4 * 4 + 1], o[c4 * 4 + 2], o[c4 * 4 + 3]);
  }
}

// ------------- h2 = y1 @ W2  [M,128]@[128,40] ----------
__global__ __launch_bounds__(256) void k_gemm2(const float* __restrict__ A,
                                               const float* __restrict__ B,
                                               float* __restrict__ C, int M) {
  __shared__ float Bs[128 * 40];
  const int tid = threadIdx.x;
  for (int i = tid; i < 5120; i += 256) Bs[i] = B[i];
  __syncthreads();
  const int r = blockIdx.x * 6 + tid / 40;
  const int c = tid % 40;
  if (tid >= 240 || r >= M) return;
  const float* arow = &A[(size_t)r * 128];
  float acc = 0.f;
#pragma unroll
  for (int k4 = 0; k4 < 32; ++k4) {
    const float4 av = *reinterpret_cast<const float4*>(&arow[k4 * 4]);
    acc = fmaf(av.x, Bs[(k4 * 4 + 0) * 40 + c], acc);
    acc = fmaf(av.y, Bs[(k4 * 4 + 1) * 40 + c], acc);
    acc = fmaf(av.z, Bs[(k4 * 4 + 2) * 40 + c], acc);
    acc = fmaf(av.w, Bs[(k4 * 4 + 3) * 40 + c], acc);
  }
  C[(size_t)r * 40 + c] = acc;
}

// ================= CSR build =================
__global__ __launch_bounds__(256) void k_hist(const int* __restrict__ src,
                                              const int* __restrict__ dst,
                                              int* __restrict__ cnt, int N, int E) {
  const int e = blockIdx.x * 256 + threadIdx.x;
  if (e >= E) return;
  atomicAdd(&cnt[src[e]], 1);
  atomicAdd(&cnt[N + dst[e]], 1);
}

__global__ __launch_bounds__(256) void k_scanA(const int* __restrict__ cnt,
                                               int* __restrict__ bsum, int N, int NB) {
  const int arr = blockIdx.x / NB, bb = blockIdx.x % NB;
  const int g = bb * 256 + threadIdx.x;
  int v = (g < N) ? cnt[arr * N + g] : 0;
  __shared__ int sd[256];
  sd[threadIdx.x] = v;
  __syncthreads();
  for (int off = 128; off > 0; off >>= 1) {
    if (threadIdx.x < off) sd[threadIdx.x] += sd[threadIdx.x + off];
    __syncthreads();
  }
  if (threadIdx.x == 0) bsum[arr * 256 + bb] = sd[0];
}

__global__ __launch_bounds__(256) void k_scanB(const int* __restrict__ bsum,
                                               int* __restrict__ boff, int NB) {
  __shared__ int sd[256];
  for (int arr = 0; arr < 2; ++arr) {
    const int v = (threadIdx.x < NB) ? bsum[arr * 256 + threadIdx.x] : 0;
    sd[threadIdx.x] = v;
    __syncthreads();
    for (int off = 1; off < 256; off <<= 1) {
      const int t = (threadIdx.x >= off) ? sd[threadIdx.x - off] : 0;
      __syncthreads();
      sd[threadIdx.x] += t;
      __syncthreads();
    }
    if (threadIdx.x < NB) boff[arr * 256 + threadIdx.x] = sd[threadIdx.x] - v;
    __syncthreads();
  }
}

__global__ __launch_bounds__(256) void k_scanC(const int* __restrict__ cnt,
                                               const int* __restrict__ boff,
                                               int* __restrict__ row_src,
                                               int* __restrict__ row_dst,
                                               int* __restrict__ cur, int N, int NB) {
  const int arr = blockIdx.x / NB, bb = blockIdx.x % NB;
  const int g = bb * 256 + threadIdx.x;
  const int v = (g < N) ? cnt[arr * N + g] : 0;
  __shared__ int sd[256];
  sd[threadIdx.x] = v;
  __syncthreads();
  for (int off = 1; off < 256; off <<= 1) {
    const int t = (threadIdx.x >= off) ? sd[threadIdx.x - off] : 0;
    __syncthreads();
    sd[threadIdx.x] += t;
    __syncthreads();
  }
  const int incl = sd[threadIdx.x];
  const int base = boff[arr * 256 + bb];
  int* row = arr ? row_dst : row_src;
  if (g < N) {
    row[g] = base + incl - v;
    cur[arr * N + g] = base + incl - v;
    if (g == N - 1) row[N] = base + incl;
  }
}

// per-edge: ps = src-order position, pd = dst-order position
__global__ __launch_bounds__(256) void k_scatter(const int* __restrict__ src,
                                                 const int* __restrict__ dst,
                                                 int* __restrict__ cur,
                                                 int* __restrict__ eid_src,
                                                 int* __restrict__ possD,
                                                 int* __restrict__ srcb, int N, int E) {
  const int e = blockIdx.x * 256 + threadIdx.x;
  if (e >= E) return;
  const int s = src[e], d = dst[e];
  const int ps = atomicAdd(&cur[s], 1);
  eid_src[ps] = e;
  const int pd = atomicAdd(&cur[N + d], 1);
  possD[pd] = ps;
  srcb[pd] = s;
}

// ===== streaming: s = sum of ew rows [r0,r1) (src-CSR-ordered), g = h/(s+eps) =====
template <int C>
__global__ __launch_bounds__(256) void k_norm(const int* __restrict__ rowp,
                                              const u16* __restrict__ ew,
                                              float* __restrict__ h, int N) {
  const int lane = threadIdx.x & 63;
  const int wv = threadIdx.x >> 6;
  const int n = blockIdx.x * 4 + wv;
  if (n >= N) return;
  constexpr int CPL = (C == 128) ? 2 : 1;
  const int c0 = lane * CPL;
  if (c0 >= C) return;
  const int r0 = rowp[n], r1 = rowp[n + 1];
  float a0 = 0.f, a1 = 0.f;
  int p = r0;
  if (CPL == 2) {
    for (; p + 2 <= r1; p += 2) {
      const u32 w0 = *reinterpret_cast<const u32*>(&ew[(size_t)p * C + c0]);
      const u32 w1 = *reinterpret_cast<const u32*>(&ew[(size_t)(p + 1) * C + c0]);
      a0 += bf2f((u16)(w0 & 0xffffu)) + bf2f((u16)(w1 & 0xffffu));
      a1 += bf2f((u16)(w0 >> 16)) + bf2f((u16)(w1 >> 16));
    }
    for (; p < r1; ++p) {
      const u32 w0 = *reinterpret_cast<const u32*>(&ew[(size_t)p * C + c0]);
      a0 += bf2f((u16)(w0 & 0xffffu));
      a1 += bf2f((u16)(w0 >> 16));
    }
    float2 hv = *reinterpret_cast<const float2*>(&h[(size_t)n * C + c0]);
    hv.x /= (a0 + SM_EPS);
    hv.y /= (a1 + SM_EPS);
    *reinterpret_cast<float2*>(&h[(size_t)n * C + c0]) = hv;
  } else {
    for (; p + 2 <= r1; p += 2)
      a0 += bf2f(ew[(size_t)p * C + c0]) + bf2f(ew[(size_t)(p + 1) * C + c0]);
    for (; p < r1; ++p) a0 += bf2f(ew[(size_t)p * C + c0]);
    h[(size_t)n * C + c0] /= (a0 + SM_EPS);
  }
}

// ===== out[n] = sum_{in-edges} ew[poss[p]] * g[srcb[p]] + b + alpha*pw, opt ELU =====
template <int C, int DO_ELU>
__global__ __launch_bounds__(256) void k_aggf(const int* __restrict__ rowp,
                                              const int* __restrict__ poss,
                                              const int* __restrict__ srcb,
                                              const u16* __restrict__ ew,
                                              const float* __restrict__ g,
                                              const float* __restrict__ pw,
                                              const float* __restrict__ bias,
                                              const float* __restrict__ alpha_p,
                                              float* __restrict__ out, int N) {
  const int lane = threadIdx.x & 63;
  const int wv = threadIdx.x >> 6;
  const int n = blockIdx.x * 4 + wv;
  if (n >= N) return;
  constexpr int CPL = (C == 128) ? 2 : 1;
  const int c0 = lane * CPL;
  if (c0 >= C) return;
  const int r0 = rowp[n], r1 = rowp[n + 1];
  float a0 = 0.f, a1 = 0.f;
  int p = r0;
  if (CPL == 2) {
    for (; p + 4 <= r1; p += 4) {
      const int s0 = srcb[p + 0], s1 = srcb[p + 1], s2 = srcb[p + 2], s3 = srcb[p + 3];
      const int q0 = poss[p + 0], q1 = poss[p + 1], q2 = poss[p + 2], q3 = poss[p + 3];
      const u32 w0 = *reinterpret_cast<const u32*>(&ew[(size_t)q0 * C + c0]);
      const u32 w1 = *reinterpret_cast<const u32*>(&ew[(size_t)q1 * C + c0]);
      const u32 w2 = *reinterpret_cast<const u32*>(&ew[(size_t)q2 * C + c0]);
      const u32 w3 = *reinterpret_cast<const u32*>(&ew[(size_t)q3 * C + c0]);
      const float2 g0 = *reinterpret_cast<const float2*>(&g[(size_t)s0 * C + c0]);
      const float2 g1 = *reinterpret_cast<const float2*>(&g[(size_t)s1 * C + c0]);
      const float2 g2 = *reinterpret_cast<const float2*>(&g[(size_t)s2 * C + c0]);
      const float2 g3 = *reinterpret_cast<const float2*>(&g[(size_t)s3 * C + c0]);
      a0 = fmaf(bf2f((u16)(w0 & 0xffffu)), g0.x, a0);
      a1 = fmaf(bf2f((u16)(w0 >> 16)), g0.y, a1);
      a0 = fmaf(bf2f((u16)(w1 & 0xffffu)), g1.x, a0);
      a1 = fmaf(bf2f((u16)(w1 >> 16)), g1.y, a1);
      a0 = fmaf(bf2f((u16)(w2 & 0xffffu)), g2.x, a0);
      a1 = fmaf(bf2f((u16)(w2 >> 16)), g2.y, a1);
      a0 = fmaf(bf2f((u16)(w3 & 0xffffu)), g3.x, a0);
      a1 = fmaf(bf2f((u16)(w3 >> 16)), g3.y, a1);
    }
    for (; p < r1; ++p) {
      const int s0 = srcb[p];
      const int q0 = poss[p];
      const u32 w0 = *reinterpret_cast<const u32*>(&ew[(size_t)q0 * C + c0]);
      const float2 g0 = *reinterpret_cast<const float2*>(&g[(size_t)s0 * C + c0]);
      a0 = fmaf(bf2f((u16)(w0 & 0xffffu)), g0.x, a0);
      a1 = fmaf(bf2f((u16)(w0 >> 16)), g0.y, a1);
    }
    const float al = alpha_p[0];
    const float2 pv = *reinterpret_cast<const float2*>(&pw[(size_t)n * C + c0]);
    float v0 = a0 + bias[c0] + al * pv.x;
    float v1 = a1 + bias[c0 + 1] + al * pv.y;
    if (DO_ELU) {
      v0 = (v0 > 0.f) ? v0 : expm1f(v0);
      v1 = (v1 > 0.f) ? v1 : expm1f(v1);
    }
    *reinterpret_cast<float2*>(&out[(size_t)n * C + c0]) = make_float2(v0, v1);
  } else {
    for (; p + 4 <= r1; p += 4) {
      const int s0 = srcb[p + 0], s1 = srcb[p + 1], s2 = srcb[p + 2], s3 = srcb[p + 3];
      const int q0 = poss[p + 0], q1 = poss[p + 1], q2 = poss[p + 2], q3 = poss[p + 3];
      const float w0 = bf2f(ew[(size_t)q0 * C + c0]);
      const float w1 = bf2f(ew[(size_t)q1 * C + c0]);
      const float w2 = bf2f(ew[(size_t)q2 * C + c0]);
      const float w3 = bf2f(ew[(size_t)q3 * C + c0]);
      const float g0 = g[(size_t)s0 * C + c0];
      const float g1 = g[(size_t)s1 * C + c0];
      const float g2 = g[(size_t)s2 * C + c0];
      const float g3 = g[(size_t)s3 * C + c0];
      a0 = fmaf(w0, g0, a0);
      a0 = fmaf(w1, g1, a0);
      a0 = fmaf(w2, g2, a0);
      a0 = fmaf(w3, g3, a0);
    }
    for (; p < r1; ++p)
      a0 = fmaf(bf2f(ew[(size_t)poss[p] * C + c0]), g[(size_t)srcb[p] * C + c0], a0);
    float v = a0 + bias[c0] + alpha_p[0] * pw[(size_t)n * C + c0];
    if (DO_ELU) v = (v > 0.f) ? v : expm1f(v);
    out[(size_t)n * C + c0] = v;
  }
}

extern "C" void kernel_launch(void* const* d_in, const int* in_sizes, int n_in,
                              void* d_out, int out_size, void* d_ws, size_t ws_size,
                              hipStream_t stream) {
  const float* x    = (const float*)d_in[0];
  const int*   ei   = (const int*)d_in[1];
  const float* kric = (const float*)d_in[2];
  const float* epoi = (const float*)d_in[3];
  const float* alpha= (const float*)d_in[4];
  const float* W1   = (const float*)d_in[5];
  const float* Wa1  = (const float*)d_in[6];
  const float* Wb1  = (const float*)d_in[7];
  const float* bb1  = (const float*)d_in[8];
  const float* Wc1  = (const float*)d_in[9];
  const float* Wd1  = (const float*)d_in[10];
  const float* bd1  = (const float*)d_in[11];
  const float* b1   = (const float*)d_in[12];
  const float* W2   = (const float*)d_in[13];
  const float* Wa2  = (const float*)d_in[14];
  const float* Wb2  = (const float*)d_in[15];
  const float* bb2  = (const float*)d_in[16];
  const float* Wc2  = (const float*)d_in[17];
  const float* Wd2  = (const float*)d_in[18];
  const float* bd2  = (const float*)d_in[19];
  const float* b2   = (const float*)d_in[20];

  const int N = in_sizes[0] / 512;
  const int E = in_sizes[1] / 2;
  const int* srcI = ei;
  const int* dstI = ei + E;
  const int NB = (N + 255) / 256;

  // ---- workspace layout ----
  char* p = (char*)d_ws;
  int* cnt      = (int*)p; p += (size_t)2 * N * 4;
  int* cur      = (int*)p; p += (size_t)2 * N * 4;
  int* bsum     = (int*)p; p += 512 * 4;
  int* boff     = (int*)p; p += 512 * 4;
  int* row_src  = (int*)p; p += (size_t)(N + 1) * 4;
  int* row_dst  = (int*)p; p += (size_t)(N + 1) * 4;
  int* eid_src  = (int*)p; p += (size_t)E * 4;
  int* possD    = (int*)p; p += (size_t)E * 4;
  int* srcb     = (int*)p; p += (size_t)E * 4;
  p = (char*)(((uintptr_t)p + 255) & ~(uintptr_t)255);
  u16* WaT1g = (u16*)p; p += 2048 * 2;
  u16* WbT1g = (u16*)p; p += 16384 * 2;
  u16* WcT1g = (u16*)p; p += 2048 * 2;
  u16* WdT1g = (u16*)p; p += 16384 * 2;
  p = (char*)(((uintptr_t)p + 255) & ~(uintptr_t)255);
  float* h1  = (float*)p; p += (size_t)N * 128 * 4;  // becomes g1 in place
  float* y1  = (float*)p; p += (size_t)N * 128 * 4;
  float* h2  = (float*)p; p += (size_t)N * 40 * 4;   // becomes g2 in place
  float* pw1 = (float*)p; p += (size_t)N * 128 * 4;
  float* pw2 = (float*)p; p += (size_t)N * 40 * 4;
  u16* ew    = (u16*)p;  // E*128 bf16 (layer 1), reused E*40 (layer 2); src-CSR order

  // ---- CSR build (once, reused by both layers) + weight prep ----
  hipMemsetAsync(cnt, 0, (size_t)2 * N * 4, stream);
  k_prep<<<144, 256, 0, stream>>>(Wa1, Wb1, Wc1, Wd1, WaT1g, WbT1g, WcT1g, WdT1g);
  k_hist<<<(E + 255) / 256, 256, 0, stream>>>(srcI, dstI, cnt, N, E);
  k_scanA<<<2 * NB, 256, 0, stream>>>(cnt, bsum, N, NB);
  k_scanB<<<1, 256, 0, stream>>>(bsum, boff, NB);
  k_scanC<<<2 * NB, 256, 0, stream>>>(cnt, boff, row_src, row_dst, cur, N, NB);
  k_scatter<<<(E + 255) / 256, 256, 0, stream>>>(srcI, dstI, cur, eid_src, possD, srcb, N, E);

  // ---------------- layer 1 ----------------
  k_gemm1<<<(N + 127) / 128, 256, 0, stream>>>(x, W1, h1, N);
  k_emlp<0><<<(E + 127) / 128, 256, 0, stream>>>(kric, eid_src, WaT1g, WbT1g, bb1, ew, nullptr, E);
  k_emlp<1><<<(N + 127) / 128, 256, 0, stream>>>(epoi, nullptr, WcT1g, WdT1g, bd1, nullptr, pw1, N);
  k_norm<128><<<(N + 3) / 4, 256, 0, stream>>>(row_src, ew, h1, N);
  k_aggf<128, 1><<<(N + 3) / 4, 256, 0, stream>>>(row_dst, possD, srcb, ew, h1, pw1, b1, alpha, y1, N);

  // ---------------- layer 2 ----------------
  k_gemm2<<<(N + 5) / 6, 256, 0, stream>>>(y1, W2, h2, N);
  k_mlp40<0><<<(E + 255) / 256, 256, 0, stream>>>(kric, eid_src, Wa2, Wb2, bb2, ew, nullptr, E);
  k_mlp40<1><<<(N + 255) / 256, 256, 0, stream>>>(epoi, nullptr, Wc2, Wd2, bd2, nullptr, pw2, N);
  k_norm<40><<<(N + 3) / 4, 256, 0, stream>>>(row_src, ew, h2, N);
  k_aggf<40, 0><<<(N + 3) / 4, 256, 0, stream>>>(row_dst, possD, srcb, ew, h2, pw2, b2, alpha, (float*)d_out, N);
}

// Round 6
// 804.907 us; speedup vs baseline: 8.8024x; 1.0956x over previous
//
#include <hip/hip_runtime.h>
#include <math.h>

#define SM_EPS 1e-16f

typedef unsigned short u16;
typedef unsigned int u32;
typedef short s16x8 __attribute__((ext_vector_type(8)));
typedef float f32x4 __attribute__((ext_vector_type(4)));

__device__ __forceinline__ u16 f2bfh(float x) {
  __bf16 b = (__bf16)x;
  return __builtin_bit_cast(unsigned short, b);
}
__device__ __forceinline__ float bf2f(u16 u) {
  return __uint_as_float(((u32)u) << 16);
}

// -------- weight prep: transpose + bf16 convert (once per call) --------
// WaTg [128][16], WbTg [128][128], WcTg [128][16], WdTg [128][128], W1Tg [128][512]
__global__ __launch_bounds__(256) void k_prep(const float* __restrict__ Wa,
                                              const float* __restrict__ Wb,
                                              const float* __restrict__ Wc,
                                              const float* __restrict__ Wd,
                                              const float* __restrict__ W1,
                                              u16* __restrict__ WaTg, u16* __restrict__ WbTg,
                                              u16* __restrict__ WcTg, u16* __restrict__ WdTg,
                                              u16* __restrict__ W1Tg) {
  const int idx = blockIdx.x * 256 + threadIdx.x;
  if (idx < 2048) {
    const int n = idx >> 4, k = idx & 15;
    WaTg[idx] = f2bfh(Wa[k * 128 + n]);
  } else if (idx < 18432) {
    const int t = idx - 2048;
    const int n = t >> 7, k = t & 127;
    WbTg[t] = f2bfh(Wb[k * 128 + n]);
  } else if (idx < 20480) {
    const int t = idx - 18432;
    const int n = t >> 4, k = t & 15;
    WcTg[t] = f2bfh(Wc[k * 128 + n]);
  } else if (idx < 36864) {
    const int t = idx - 20480;
    const int n = t >> 7, k = t & 127;
    WdTg[t] = f2bfh(Wd[k * 128 + n]);
  } else if (idx < 102400) {
    const int t = idx - 36864;
    const int n = t >> 9, k = t & 511;
    W1Tg[t] = f2bfh(W1[k * 128 + n]);
  }
}

// ---------------- h1 = x @ W1 via MFMA: [M,512]@[512,128], bf16 ----------------
// BM=64 rows/block, 4 waves (2x2), each wave 32x64 (2x4 MFMA tiles), K chunks of 32.
__global__ __launch_bounds__(256) void k_gemm1m(const float* __restrict__ x,
                                                const u16* __restrict__ WT,  // [128][512]
                                                float* __restrict__ C, int M) {
  const int tid = threadIdx.x;
  const int lane = tid & 63;
  const int w = tid >> 6;
  const int wr = w >> 1, wc = w & 1;
  const int lg = lane >> 4;
  const int lm = lane & 15;
  const int r0 = blockIdx.x * 64;

  const f32x4 z4 = {0.f, 0.f, 0.f, 0.f};
  f32x4 acc[2][4];
#pragma unroll
  for (int i = 0; i < 2; ++i)
#pragma unroll
    for (int j = 0; j < 4; ++j) acc[i][j] = z4;

  auto load_chunk = [&](int ch, s16x8 af[2], s16x8 bf_[4]) {
#pragma unroll
    for (int i = 0; i < 2; ++i) {
      const int row = r0 + (wr * 2 + i) * 16 + lm;
      s16x8 a = (s16x8)0;
      if (row < M) {
        const float4 f0 = *reinterpret_cast<const float4*>(&x[(size_t)row * 512 + ch * 32 + lg * 8]);
        const float4 f1 = *reinterpret_cast<const float4*>(&x[(size_t)row * 512 + ch * 32 + lg * 8 + 4]);
        a[0] = (short)f2bfh(f0.x); a[1] = (short)f2bfh(f0.y);
        a[2] = (short)f2bfh(f0.z); a[3] = (short)f2bfh(f0.w);
        a[4] = (short)f2bfh(f1.x); a[5] = (short)f2bfh(f1.y);
        a[6] = (short)f2bfh(f1.z); a[7] = (short)f2bfh(f1.w);
      }
      af[i] = a;
    }
#pragma unroll
    for (int j = 0; j < 4; ++j) {
      const int n = (wc * 4 + j) * 16 + lm;
      bf_[j] = *reinterpret_cast<const s16x8*>(&WT[(size_t)n * 512 + ch * 32 + lg * 8]);
    }
  };

  s16x8 af[2], bf_[4];
  load_chunk(0, af, bf_);
  for (int ch = 0; ch < 16; ++ch) {
    s16x8 naf[2], nbf[4];
    if (ch < 15) load_chunk(ch + 1, naf, nbf);
#pragma unroll
    for (int i = 0; i < 2; ++i)
#pragma unroll
      for (int j = 0; j < 4; ++j)
        acc[i][j] = __builtin_amdgcn_mfma_f32_16x16x32_bf16(af[i], bf_[j], acc[i][j], 0, 0, 0);
    if (ch < 15) {
#pragma unroll
      for (int i = 0; i < 2; ++i) af[i] = naf[i];
#pragma unroll
      for (int j = 0; j < 4; ++j) bf_[j] = nbf[j];
    }
  }

#pragma unroll
  for (int i = 0; i < 2; ++i) {
#pragma unroll
    for (int rr = 0; rr < 4; ++rr) {
      const int row = r0 + (wr * 2 + i) * 16 + lg * 4 + rr;
      if (row < M) {
#pragma unroll
        for (int j = 0; j < 4; ++j)
          C[(size_t)row * 128 + (wc * 4 + j) * 16 + lm] = acc[i][j][rr];
      }
    }
  }
}

// ------- MFMA fused 16->128->128 MLP over rows -------
// eid != nullptr: row r computes input row eid[r] (src-CSR permuted), output at r.
// MODE 0: logit -> exp -> bf16 store.  MODE 1: logit -> lrelu(0.01) -> bf16 store.
// Output goes through LDS for coalesced uint4 stores.
template <int MODE>
__global__ __launch_bounds__(256) void k_emlp(
    const float* __restrict__ inp, const int* __restrict__ eid,
    const u16* __restrict__ WaTg, const u16* __restrict__ WbTg,
    const float* __restrict__ bbias,
    u16* __restrict__ outp, int R) {
  __shared__ __align__(16) unsigned char sU[32768];
  const int tid = threadIdx.x;
  const int lane = tid & 63;
  const int w = tid >> 6;
  const int wr = w >> 1, wc = w & 1;
  const int lg = lane >> 4;
  const int lm = lane & 15;
  const int r0 = blockIdx.x * 128;

  // ---- stage-1 A frags from global (K=16 zero-padded to 32) ----
  s16x8 afr[4];
#pragma unroll
  for (int i = 0; i < 4; ++i) {
    s16x8 a = (s16x8)0;
    if (lg < 2) {
      const int r = r0 + (wr * 4 + i) * 16 + lm;
      if (r < R) {
        const int e = eid ? eid[r] : r;
        const float4 f0 = *reinterpret_cast<const float4*>(&inp[(size_t)e * 16 + lg * 8]);
        const float4 f1 = *reinterpret_cast<const float4*>(&inp[(size_t)e * 16 + lg * 8 + 4]);
        a[0] = (short)f2bfh(f0.x); a[1] = (short)f2bfh(f0.y);
        a[2] = (short)f2bfh(f0.z); a[3] = (short)f2bfh(f0.w);
        a[4] = (short)f2bfh(f1.x); a[5] = (short)f2bfh(f1.y);
        a[6] = (short)f2bfh(f1.z); a[7] = (short)f2bfh(f1.w);
      }
    }
    afr[i] = a;
  }

  // ---- stage-1 B frags direct from global (Wa: [128][16] bf16) ----
  const f32x4 z4 = {0.f, 0.f, 0.f, 0.f};
  s16x8 bfr1[4];
#pragma unroll
  for (int j = 0; j < 4; ++j) {
    s16x8 b = (s16x8)0;
    if (lg < 2) {
      const int n = (wc * 4 + j) * 16 + lm;
      b = *reinterpret_cast<const s16x8*>(&WaTg[n * 16 + lg * 8]);
    }
    bfr1[j] = b;
  }

  // ---- stage 1: U = lrelu(K @ Wa) ----
  f32x4 acc1[4][4];
#pragma unroll
  for (int i = 0; i < 4; ++i)
#pragma unroll
    for (int j = 0; j < 4; ++j) acc1[i][j] = z4;
#pragma unroll
  for (int i = 0; i < 4; ++i)
#pragma unroll
    for (int j = 0; j < 4; ++j)
      acc1[i][j] = __builtin_amdgcn_mfma_f32_16x16x32_bf16(afr[i], bfr1[j], acc1[i][j], 0, 0, 0);

  // write U to LDS (bf16, XOR-16 swizzled); C layout: col=lane&15, row=(lane>>4)*4+reg
#pragma unroll
  for (int i = 0; i < 4; ++i) {
#pragma unroll
    for (int j = 0; j < 4; ++j) {
#pragma unroll
      for (int rr = 0; rr < 4; ++rr) {
        float v = acc1[i][j][rr];
        v = (v >= 0.f) ? v : 0.2f * v;
        const int grow = (wr * 4 + i) * 16 + lg * 4 + rr;
        const int gcol = (wc * 4 + j) * 16 + lm;
        const int byte = grow * 256 + ((((gcol >> 3) ^ (grow & 15))) << 4) + (gcol & 7) * 2;
        *reinterpret_cast<u16*>(&sU[byte]) = f2bfh(v);
      }
    }
  }
  __syncthreads();

  // ---- stage 2: logit = U @ Wb (A from LDS, B direct from global L2) ----
  f32x4 acc[4][4];
#pragma unroll
  for (int i = 0; i < 4; ++i)
#pragma unroll
    for (int j = 0; j < 4; ++j) acc[i][j] = z4;
#pragma unroll
  for (int kb = 0; kb < 4; ++kb) {
    s16x8 af[4], bf_[4];
    const int ch = kb * 4 + lg;
#pragma unroll
    for (int j = 0; j < 4; ++j) {
      const int n = (wc * 4 + j) * 16 + lm;
      bf_[j] = *reinterpret_cast<const s16x8*>(&WbTg[n * 128 + ch * 8]);
    }
#pragma unroll
    for (int i = 0; i < 4; ++i) {
      const int row = (wr * 4 + i) * 16 + lm;
      af[i] = *reinterpret_cast<const s16x8*>(&sU[row * 256 + ((ch ^ (row & 15)) << 4)]);
    }
#pragma unroll
    for (int i = 0; i < 4; ++i)
#pragma unroll
      for (int j = 0; j < 4; ++j)
        acc[i][j] = __builtin_amdgcn_mfma_f32_16x16x32_bf16(af[i], bf_[j], acc[i][j], 0, 0, 0);
  }
  __syncthreads();  // done reading sU; safe to overwrite

  // ---- epilogue: activation, write bf16 tile to LDS (swizzled) ----
  float bv[4];
#pragma unroll
  for (int j = 0; j < 4; ++j) bv[j] = bbias[(wc * 4 + j) * 16 + lm];
#pragma unroll
  for (int i = 0; i < 4; ++i) {
#pragma unroll
    for (int j = 0; j < 4; ++j) {
#pragma unroll
      for (int rr = 0; rr < 4; ++rr) {
        float v = acc[i][j][rr] + bv[j];
        if (MODE == 0) v = __expf(v);
        else v = (v >= 0.f) ? v : 0.01f * v;
        const int grow = (wr * 4 + i) * 16 + lg * 4 + rr;
        const int gcol = (wc * 4 + j) * 16 + lm;
        const int byte = grow * 256 + ((((gcol >> 3) ^ (grow & 15))) << 4) + (gcol & 7) * 2;
        *reinterpret_cast<u16*>(&sU[byte]) = f2bfh(v);
      }
    }
  }
  __syncthreads();

  // ---- coalesced copy-out: 2048 uint4, linearized ----
  const int rmax = R - r0;
#pragma unroll
  for (int q = 0; q < 8; ++q) {
    const int u = tid + q * 256;
    const int row = u >> 4, c8 = u & 15;
    if (row < rmax) {
      const uint4 v = *reinterpret_cast<const uint4*>(&sU[row * 256 + ((c8 ^ (row & 15)) << 4)]);
      *reinterpret_cast<uint4*>(&outp[(size_t)(r0 + row) * 128 + c8 * 8]) = v;
    }
  }
}

// ------------- fused 16->40->40 MLP, one row per thread ----------
// MODE 0: exp -> bf16 ew.  MODE 1: lrelu(0.01) -> bf16 pw.
template <int MODE>
__global__ __launch_bounds__(256) void k_mlp40(
    const float* __restrict__ inp, const int* __restrict__ eid,
    const float* __restrict__ Wa, const float* __restrict__ Wb,
    const float* __restrict__ bbias, u16* __restrict__ outp, int R) {
  __shared__ float Wa_s[16 * 40];
  __shared__ float Wb_s[40 * 40];
  __shared__ float bb_s[40];
  const int tid = threadIdx.x;
  for (int i = tid; i < 640; i += 256) Wa_s[i] = Wa[i];
  for (int i = tid; i < 1600; i += 256) Wb_s[i] = Wb[i];
  if (tid < 40) bb_s[tid] = bbias[tid];
  __syncthreads();
  const int r = blockIdx.x * 256 + tid;
  if (r >= R) return;
  const int e = eid ? eid[r] : r;

  float kreg[16];
#pragma unroll
  for (int t = 0; t < 4; ++t)
    *reinterpret_cast<float4*>(&kreg[t * 4]) =
        *reinterpret_cast<const float4*>(&inp[(size_t)e * 16 + t * 4]);

  float u[40];
#pragma unroll
  for (int c = 0; c < 40; ++c) u[c] = 0.f;
#pragma unroll
  for (int j = 0; j < 16; ++j) {
    const float kj = kreg[j];
#pragma unroll
    for (int c4 = 0; c4 < 10; ++c4) {
      const float4 w = *reinterpret_cast<const float4*>(&Wa_s[j * 40 + c4 * 4]);
      u[c4 * 4 + 0] = fmaf(kj, w.x, u[c4 * 4 + 0]);
      u[c4 * 4 + 1] = fmaf(kj, w.y, u[c4 * 4 + 1]);
      u[c4 * 4 + 2] = fmaf(kj, w.z, u[c4 * 4 + 2]);
      u[c4 * 4 + 3] = fmaf(kj, w.w, u[c4 * 4 + 3]);
    }
  }
#pragma unroll
  for (int c = 0; c < 40; ++c) u[c] = (u[c] >= 0.f) ? u[c] : 0.2f * u[c];

  float o[40];
#pragma unroll
  for (int c = 0; c < 40; ++c) o[c] = bb_s[c];
#pragma unroll
  for (int j = 0; j < 40; ++j) {
    const float uj = u[j];
#pragma unroll
    for (int c4 = 0; c4 < 10; ++c4) {
      const float4 w = *reinterpret_cast<const float4*>(&Wb_s[j * 40 + c4 * 4]);
      o[c4 * 4 + 0] = fmaf(uj, w.x, o[c4 * 4 + 0]);
      o[c4 * 4 + 1] = fmaf(uj, w.y, o[c4 * 4 + 1]);
      o[c4 * 4 + 2] = fmaf(uj, w.z, o[c4 * 4 + 2]);
      o[c4 * 4 + 3] = fmaf(uj, w.w, o[c4 * 4 + 3]);
    }
  }
#pragma unroll
  for (int c = 0; c < 40; ++c) {
    float v = o[c];
    if (MODE == 0) v = __expf(v);
    else v = (v >= 0.f) ? v : 0.01f * v;
    o[c] = v;
  }
#pragma unroll
  for (int c2 = 0; c2 < 20; ++c2) {
    u32 pk = (u32)f2bfh(o[2 * c2]) | ((u32)f2bfh(o[2 * c2 + 1]) << 16);
    *reinterpret_cast<u32*>(&outp[(size_t)r * 40 + c2 * 2]) = pk;
  }
}

// ------------- h2 = y1 @ W2  [M,128]@[128,40] ----------
__global__ __launch_bounds__(256) void k_gemm2(const float* __restrict__ A,
                                               const float* __restrict__ B,
                                               float* __restrict__ C, int M) {
  __shared__ float Bs[128 * 40];
  const int tid = threadIdx.x;
  for (int i = tid; i < 5120; i += 256) Bs[i] = B[i];
  __syncthreads();
  const int r = blockIdx.x * 6 + tid / 40;
  const int c = tid % 40;
  if (tid >= 240 || r >= M) return;
  const float* arow = &A[(size_t)r * 128];
  float acc = 0.f;
#pragma unroll
  for (int k4 = 0; k4 < 32; ++k4) {
    const float4 av = *reinterpret_cast<const float4*>(&arow[k4 * 4]);
    acc = fmaf(av.x, Bs[(k4 * 4 + 0) * 40 + c], acc);
    acc = fmaf(av.y, Bs[(k4 * 4 + 1) * 40 + c], acc);
    acc = fmaf(av.z, Bs[(k4 * 4 + 2) * 40 + c], acc);
    acc = fmaf(av.w, Bs[(k4 * 4 + 3) * 40 + c], acc);
  }
  C[(size_t)r * 40 + c] = acc;
}

// ================= CSR build =================
__global__ __launch_bounds__(256) void k_hist(const int* __restrict__ src,
                                              const int* __restrict__ dst,
                                              int* __restrict__ cnt, int N, int E) {
  const int e = blockIdx.x * 256 + threadIdx.x;
  if (e >= E) return;
  atomicAdd(&cnt[src[e]], 1);
  atomicAdd(&cnt[N + dst[e]], 1);
}

__global__ __launch_bounds__(256) void k_scanA(const int* __restrict__ cnt,
                                               int* __restrict__ bsum, int N, int NB) {
  const int arr = blockIdx.x / NB, bb = blockIdx.x % NB;
  const int g = bb * 256 + threadIdx.x;
  int v = (g < N) ? cnt[arr * N + g] : 0;
  __shared__ int sd[256];
  sd[threadIdx.x] = v;
  __syncthreads();
  for (int off = 128; off > 0; off >>= 1) {
    if (threadIdx.x < off) sd[threadIdx.x] += sd[threadIdx.x + off];
    __syncthreads();
  }
  if (threadIdx.x == 0) bsum[arr * 256 + bb] = sd[0];
}

__global__ __launch_bounds__(256) void k_scanB(const int* __restrict__ bsum,
                                               int* __restrict__ boff, int NB) {
  __shared__ int sd[256];
  for (int arr = 0; arr < 2; ++arr) {
    const int v = (threadIdx.x < NB) ? bsum[arr * 256 + threadIdx.x] : 0;
    sd[threadIdx.x] = v;
    __syncthreads();
    for (int off = 1; off < 256; off <<= 1) {
      const int t = (threadIdx.x >= off) ? sd[threadIdx.x - off] : 0;
      __syncthreads();
      sd[threadIdx.x] += t;
      __syncthreads();
    }
    if (threadIdx.x < NB) boff[arr * 256 + threadIdx.x] = sd[threadIdx.x] - v;
    __syncthreads();
  }
}

__global__ __launch_bounds__(256) void k_scanC(const int* __restrict__ cnt,
                                               const int* __restrict__ boff,
                                               int* __restrict__ row_src,
                                               int* __restrict__ row_dst,
                                               int* __restrict__ cur, int N, int NB) {
  const int arr = blockIdx.x / NB, bb = blockIdx.x % NB;
  const int g = bb * 256 + threadIdx.x;
  const int v = (g < N) ? cnt[arr * N + g] : 0;
  __shared__ int sd[256];
  sd[threadIdx.x] = v;
  __syncthreads();
  for (int off = 1; off < 256; off <<= 1) {
    const int t = (threadIdx.x >= off) ? sd[threadIdx.x - off] : 0;
    __syncthreads();
    sd[threadIdx.x] += t;
    __syncthreads();
  }
  const int incl = sd[threadIdx.x];
  const int base = boff[arr * 256 + bb];
  int* row = arr ? row_dst : row_src;
  if (g < N) {
    row[g] = base + incl - v;
    cur[arr * N + g] = base + incl - v;
    if (g == N - 1) row[N] = base + incl;
  }
}

// per-edge: ps = src-order position, pd = dst-order position
__global__ __launch_bounds__(256) void k_scatter(const int* __restrict__ src,
                                                 const int* __restrict__ dst,
                                                 int* __restrict__ cur,
                                                 int* __restrict__ eid_src,
                                                 int* __restrict__ possD,
                                                 int* __restrict__ srcb, int N, int E) {
  const int e = blockIdx.x * 256 + threadIdx.x;
  if (e >= E) return;
  const int s = src[e], d = dst[e];
  const int ps = atomicAdd(&cur[s], 1);
  eid_src[ps] = e;
  const int pd = atomicAdd(&cur[N + d], 1);
  possD[pd] = ps;
  srcb[pd] = s;
}

// ===== streaming: s = sum of ew rows [r0,r1) (src-CSR-ordered), g = h/(s+eps) =====
template <int C>
__global__ __launch_bounds__(256) void k_norm(const int* __restrict__ rowp,
                                              const u16* __restrict__ ew,
                                              float* __restrict__ h, int N) {
  const int lane = threadIdx.x & 63;
  const int wv = threadIdx.x >> 6;
  const int n = blockIdx.x * 4 + wv;
  if (n >= N) return;
  constexpr int CPL = (C == 128) ? 2 : 1;
  const int c0 = lane * CPL;
  if (c0 >= C) return;
  const int r0 = rowp[n], r1 = rowp[n + 1];
  float a0 = 0.f, a1 = 0.f;
  int p = r0;
  if (CPL == 2) {
    for (; p + 2 <= r1; p += 2) {
      const u32 w0 = *reinterpret_cast<const u32*>(&ew[(size_t)p * C + c0]);
      const u32 w1 = *reinterpret_cast<const u32*>(&ew[(size_t)(p + 1) * C + c0]);
      a0 += bf2f((u16)(w0 & 0xffffu)) + bf2f((u16)(w1 & 0xffffu));
      a1 += bf2f((u16)(w0 >> 16)) + bf2f((u16)(w1 >> 16));
    }
    for (; p < r1; ++p) {
      const u32 w0 = *reinterpret_cast<const u32*>(&ew[(size_t)p * C + c0]);
      a0 += bf2f((u16)(w0 & 0xffffu));
      a1 += bf2f((u16)(w0 >> 16));
    }
    float2 hv = *reinterpret_cast<const float2*>(&h[(size_t)n * C + c0]);
    hv.x /= (a0 + SM_EPS);
    hv.y /= (a1 + SM_EPS);
    *reinterpret_cast<float2*>(&h[(size_t)n * C + c0]) = hv;
  } else {
    for (; p + 2 <= r1; p += 2)
      a0 += bf2f(ew[(size_t)p * C + c0]) + bf2f(ew[(size_t)(p + 1) * C + c0]);
    for (; p < r1; ++p) a0 += bf2f(ew[(size_t)p * C + c0]);
    h[(size_t)n * C + c0] /= (a0 + SM_EPS);
  }
}

// ===== out[n] = sum_{in-edges} ew[poss[p]] * g[srcb[p]] + b + alpha*pw(bf16), opt ELU =====
template <int C, int DO_ELU>
__global__ __launch_bounds__(256) void k_aggf(const int* __restrict__ rowp,
                                              const int* __restrict__ poss,
                                              const int* __restrict__ srcb,
                                              const u16* __restrict__ ew,
                                              const float* __restrict__ g,
                                              const u16* __restrict__ pw,
                                              const float* __restrict__ bias,
                                              const float* __restrict__ alpha_p,
                                              float* __restrict__ out, int N) {
  const int lane = threadIdx.x & 63;
  const int wv = threadIdx.x >> 6;
  const int n = blockIdx.x * 4 + wv;
  if (n >= N) return;
  constexpr int CPL = (C == 128) ? 2 : 1;
  const int c0 = lane * CPL;
  if (c0 >= C) return;
  const int r0 = rowp[n], r1 = rowp[n + 1];
  float a0 = 0.f, a1 = 0.f;
  int p = r0;
  if (CPL == 2) {
    for (; p + 4 <= r1; p += 4) {
      const int s0 = srcb[p + 0], s1 = srcb[p + 1], s2 = srcb[p + 2], s3 = srcb[p + 3];
      const int q0 = poss[p + 0], q1 = poss[p + 1], q2 = poss[p + 2], q3 = poss[p + 3];
      const u32 w0 = *reinterpret_cast<const u32*>(&ew[(size_t)q0 * C + c0]);
      const u32 w1 = *reinterpret_cast<const u32*>(&ew[(size_t)q1 * C + c0]);
      const u32 w2 = *reinterpret_cast<const u32*>(&ew[(size_t)q2 * C + c0]);
      const u32 w3 = *reinterpret_cast<const u32*>(&ew[(size_t)q3 * C + c0]);
      const float2 g0 = *reinterpret_cast<const float2*>(&g[(size_t)s0 * C + c0]);
      const float2 g1 = *reinterpret_cast<const float2*>(&g[(size_t)s1 * C + c0]);
      const float2 g2 = *reinterpret_cast<const float2*>(&g[(size_t)s2 * C + c0]);
      const float2 g3 = *reinterpret_cast<const float2*>(&g[(size_t)s3 * C + c0]);
      a0 = fmaf(bf2f((u16)(w0 & 0xffffu)), g0.x, a0);
      a1 = fmaf(bf2f((u16)(w0 >> 16)), g0.y, a1);
      a0 = fmaf(bf2f((u16)(w1 & 0xffffu)), g1.x, a0);
      a1 = fmaf(bf2f((u16)(w1 >> 16)), g1.y, a1);
      a0 = fmaf(bf2f((u16)(w2 & 0xffffu)), g2.x, a0);
      a1 = fmaf(bf2f((u16)(w2 >> 16)), g2.y, a1);
      a0 = fmaf(bf2f((u16)(w3 & 0xffffu)), g3.x, a0);
      a1 = fmaf(bf2f((u16)(w3 >> 16)), g3.y, a1);
    }
    for (; p < r1; ++p) {
      const int s0 = srcb[p];
      const int q0 = poss[p];
      const u32 w0 = *reinterpret_cast<const u32*>(&ew[(size_t)q0 * C + c0]);
      const float2 g0 = *reinterpret_cast<const float2*>(&g[(size_t)s0 * C + c0]);
      a0 = fmaf(bf2f((u16)(w0 & 0xffffu)), g0.x, a0);
      a1 = fmaf(bf2f((u16)(w0 >> 16)), g0.y, a1);
    }
    const float al = alpha_p[0];
    const u32 pv2 = *reinterpret_cast<const u32*>(&pw[(size_t)n * C + c0]);
    float v0 = a0 + bias[c0] + al * bf2f((u16)(pv2 & 0xffffu));
    float v1 = a1 + bias[c0 + 1] + al * bf2f((u16)(pv2 >> 16));
    if (DO_ELU) {
      v0 = (v0 > 0.f) ? v0 : expm1f(v0);
      v1 = (v1 > 0.f) ? v1 : expm1f(v1);
    }
    *reinterpret_cast<float2*>(&out[(size_t)n * C + c0]) = make_float2(v0, v1);
  } else {
    for (; p + 4 <= r1; p += 4) {
      const int s0 = srcb[p + 0], s1 = srcb[p + 1], s2 = srcb[p + 2], s3 = srcb[p + 3];
      const int q0 = poss[p + 0], q1 = poss[p + 1], q2 = poss[p + 2], q3 = poss[p + 3];
      const float w0 = bf2f(ew[(size_t)q0 * C + c0]);
      const float w1 = bf2f(ew[(size_t)q1 * C + c0]);
      const float w2 = bf2f(ew[(size_t)q2 * C + c0]);
      const float w3 = bf2f(ew[(size_t)q3 * C + c0]);
      const float g0 = g[(size_t)s0 * C + c0];
      const float g1 = g[(size_t)s1 * C + c0];
      const float g2 = g[(size_t)s2 * C + c0];
      const float g3 = g[(size_t)s3 * C + c0];
      a0 = fmaf(w0, g0, a0);
      a0 = fmaf(w1, g1, a0);
      a0 = fmaf(w2, g2, a0);
      a0 = fmaf(w3, g3, a0);
    }
    for (; p < r1; ++p)
      a0 = fmaf(bf2f(ew[(size_t)poss[p] * C + c0]), g[(size_t)srcb[p] * C + c0], a0);
    float v = a0 + bias[c0] + alpha_p[0] * bf2f(pw[(size_t)n * C + c0]);
    if (DO_ELU) v = (v > 0.f) ? v : expm1f(v);
    out[(size_t)n * C + c0] = v;
  }
}

extern "C" void kernel_launch(void* const* d_in, const int* in_sizes, int n_in,
                              void* d_out, int out_size, void* d_ws, size_t ws_size,
                              hipStream_t stream) {
  const float* x    = (const float*)d_in[0];
  const int*   ei   = (const int*)d_in[1];
  const float* kric = (const float*)d_in[2];
  const float* epoi = (const float*)d_in[3];
  const float* alpha= (const float*)d_in[4];
  const float* W1   = (const float*)d_in[5];
  const float* Wa1  = (const float*)d_in[6];
  const float* Wb1  = (const float*)d_in[7];
  const float* bb1  = (const float*)d_in[8];
  const float* Wc1  = (const float*)d_in[9];
  const float* Wd1  = (const float*)d_in[10];
  const float* bd1  = (const float*)d_in[11];
  const float* b1   = (const float*)d_in[12];
  const float* W2   = (const float*)d_in[13];
  const float* Wa2  = (const float*)d_in[14];
  const float* Wb2  = (const float*)d_in[15];
  const float* bb2  = (const float*)d_in[16];
  const float* Wc2  = (const float*)d_in[17];
  const float* Wd2  = (const float*)d_in[18];
  const float* bd2  = (const float*)d_in[19];
  const float* b2   = (const float*)d_in[20];

  const int N = in_sizes[0] / 512;
  const int E = in_sizes[1] / 2;
  const int* srcI = ei;
  const int* dstI = ei + E;
  const int NB = (N + 255) / 256;

  // ---- workspace layout ----
  char* p = (char*)d_ws;
  int* cnt      = (int*)p; p += (size_t)2 * N * 4;
  int* cur      = (int*)p; p += (size_t)2 * N * 4;
  int* bsum     = (int*)p; p += 512 * 4;
  int* boff     = (int*)p; p += 512 * 4;
  int* row_src  = (int*)p; p += (size_t)(N + 1) * 4;
  int* row_dst  = (int*)p; p += (size_t)(N + 1) * 4;
  int* eid_src  = (int*)p; p += (size_t)E * 4;
  int* possD    = (int*)p; p += (size_t)E * 4;
  int* srcb     = (int*)p; p += (size_t)E * 4;
  p = (char*)(((uintptr_t)p + 255) & ~(uintptr_t)255);
  u16* WaT1g = (u16*)p; p += 2048 * 2;
  u16* WbT1g = (u16*)p; p += 16384 * 2;
  u16* WcT1g = (u16*)p; p += 2048 * 2;
  u16* WdT1g = (u16*)p; p += 16384 * 2;
  u16* W1Tg  = (u16*)p; p += 65536 * 2;
  p = (char*)(((uintptr_t)p + 255) & ~(uintptr_t)255);
  float* h1  = (float*)p; p += (size_t)N * 128 * 4;  // becomes g1 in place
  float* y1  = (float*)p; p += (size_t)N * 128 * 4;
  float* h2  = (float*)p; p += (size_t)N * 40 * 4;   // becomes g2 in place
  u16* pw1   = (u16*)p;  p += (size_t)N * 128 * 2;   // bf16
  u16* pw2   = (u16*)p;  p += (size_t)N * 40 * 2;    // bf16
  p = (char*)(((uintptr_t)p + 255) & ~(uintptr_t)255);
  u16* ew    = (u16*)p;  // E*128 bf16 (layer 1), reused E*40 (layer 2); src-CSR order

  // ---- CSR build (once, reused by both layers) + weight prep ----
  hipMemsetAsync(cnt, 0, (size_t)2 * N * 4, stream);
  k_prep<<<400, 256, 0, stream>>>(Wa1, Wb1, Wc1, Wd1, W1, WaT1g, WbT1g, WcT1g, WdT1g, W1Tg);
  k_hist<<<(E + 255) / 256, 256, 0, stream>>>(srcI, dstI, cnt, N, E);
  k_scanA<<<2 * NB, 256, 0, stream>>>(cnt, bsum, N, NB);
  k_scanB<<<1, 256, 0, stream>>>(bsum, boff, NB);
  k_scanC<<<2 * NB, 256, 0, stream>>>(cnt, boff, row_src, row_dst, cur, N, NB);
  k_scatter<<<(E + 255) / 256, 256, 0, stream>>>(srcI, dstI, cur, eid_src, possD, srcb, N, E);

  // ---------------- layer 1 ----------------
  k_gemm1m<<<(N + 63) / 64, 256, 0, stream>>>(x, W1Tg, h1, N);
  k_emlp<0><<<(E + 127) / 128, 256, 0, stream>>>(kric, eid_src, WaT1g, WbT1g, bb1, ew, E);
  k_emlp<1><<<(N + 127) / 128, 256, 0, stream>>>(epoi, nullptr, WcT1g, WdT1g, bd1, pw1, N);
  k_norm<128><<<(N + 3) / 4, 256, 0, stream>>>(row_src, ew, h1, N);
  k_aggf<128, 1><<<(N + 3) / 4, 256, 0, stream>>>(row_dst, possD, srcb, ew, h1, pw1, b1, alpha, y1, N);

  // ---------------- layer 2 ----------------
  k_gemm2<<<(N + 5) / 6, 256, 0, stream>>>(y1, W2, h2, N);
  k_mlp40<0><<<(E + 255) / 256, 256, 0, stream>>>(kric, eid_src, Wa2, Wb2, bb2, ew, E);
  k_mlp40<1><<<(N + 255) / 256, 256, 0, stream>>>(epoi, nullptr, Wc2, Wd2, bd2, pw2, N);
  k_norm<40><<<(N + 3) / 4, 256, 0, stream>>>(row_src, ew, h2, N);
  k_aggf<40, 0><<<(N + 3) / 4, 256, 0, stream>>>(row_dst, possD, srcb, ew, h2, pw2, b2, alpha, (float*)d_out, N);
}

// Round 8
// 770.746 us; speedup vs baseline: 9.1926x; 1.0443x over previous
//
#include <hip/hip_runtime.h>
#include <math.h>

#define SM_EPS 1e-16f

typedef unsigned short u16;
typedef unsigned int u32;
typedef short s16x8 __attribute__((ext_vector_type(8)));
typedef float f32x4 __attribute__((ext_vector_type(4)));

__device__ __forceinline__ u16 f2bfh(float x) {
  __bf16 b = (__bf16)x;
  return __builtin_bit_cast(unsigned short, b);
}
__device__ __forceinline__ float bf2f(u16 u) {
  return __uint_as_float(((u32)u) << 16);
}

// -------- weight prep: transpose + bf16 convert (once per call) --------
// WaTg [128][16], WbTg [128][128], WcTg [128][16], WdTg [128][128], W1Tg [128][512]
__global__ __launch_bounds__(256) void k_prep(const float* __restrict__ Wa,
                                              const float* __restrict__ Wb,
                                              const float* __restrict__ Wc,
                                              const float* __restrict__ Wd,
                                              const float* __restrict__ W1,
                                              u16* __restrict__ WaTg, u16* __restrict__ WbTg,
                                              u16* __restrict__ WcTg, u16* __restrict__ WdTg,
                                              u16* __restrict__ W1Tg) {
  const int idx = blockIdx.x * 256 + threadIdx.x;
  if (idx < 2048) {
    const int n = idx >> 4, k = idx & 15;
    WaTg[idx] = f2bfh(Wa[k * 128 + n]);
  } else if (idx < 18432) {
    const int t = idx - 2048;
    const int n = t >> 7, k = t & 127;
    WbTg[t] = f2bfh(Wb[k * 128 + n]);
  } else if (idx < 20480) {
    const int t = idx - 18432;
    const int n = t >> 4, k = t & 15;
    WcTg[t] = f2bfh(Wc[k * 128 + n]);
  } else if (idx < 36864) {
    const int t = idx - 20480;
    const int n = t >> 7, k = t & 127;
    WdTg[t] = f2bfh(Wd[k * 128 + n]);
  } else if (idx < 102400) {
    const int t = idx - 36864;
    const int n = t >> 9, k = t & 511;
    W1Tg[t] = f2bfh(W1[k * 128 + n]);
  }
}

// -------- input prep: kricP[p] = bf16(kric[eid_src[p]]), epoiP = bf16(epoi) --------
// 2 threads per row (16B halves) for coalesced writes.
__global__ __launch_bounds__(256) void k_prepIn(const float* __restrict__ kric,
                                                const int* __restrict__ eid,
                                                u16* __restrict__ kricP,
                                                const float* __restrict__ epoi,
                                                u16* __restrict__ epoiP,
                                                int E, int N) {
  const int idx = blockIdx.x * 256 + threadIdx.x;
  const float* srcp;
  u16* dstp;
  int r, half;
  if (idx < 2 * E) {
    r = idx >> 1; half = idx & 1;
    srcp = &kric[(size_t)eid[r] * 16 + half * 8];
    dstp = &kricP[(size_t)r * 16 + half * 8];
  } else if (idx < 2 * E + 2 * N) {
    const int t = idx - 2 * E;
    r = t >> 1; half = t & 1;
    srcp = &epoi[(size_t)r * 16 + half * 8];
    dstp = &epoiP[(size_t)r * 16 + half * 8];
  } else {
    return;
  }
  const float4 f0 = *reinterpret_cast<const float4*>(srcp);
  const float4 f1 = *reinterpret_cast<const float4*>(srcp + 4);
  u32 pk[4];
  pk[0] = (u32)f2bfh(f0.x) | ((u32)f2bfh(f0.y) << 16);
  pk[1] = (u32)f2bfh(f0.z) | ((u32)f2bfh(f0.w) << 16);
  pk[2] = (u32)f2bfh(f1.x) | ((u32)f2bfh(f1.y) << 16);
  pk[3] = (u32)f2bfh(f1.z) | ((u32)f2bfh(f1.w) << 16);
  *reinterpret_cast<uint4*>(dstp) = make_uint4(pk[0], pk[1], pk[2], pk[3]);
}

// ---------------- h1 = x @ W1 via MFMA: [M,512]@[512,128], bf16 ----------------
__global__ __launch_bounds__(256) void k_gemm1m(const float* __restrict__ x,
                                                const u16* __restrict__ WT,  // [128][512]
                                                float* __restrict__ C, int M) {
  const int tid = threadIdx.x;
  const int lane = tid & 63;
  const int w = tid >> 6;
  const int wr = w >> 1, wc = w & 1;
  const int lg = lane >> 4;
  const int lm = lane & 15;
  const int r0 = blockIdx.x * 64;

  const f32x4 z4 = {0.f, 0.f, 0.f, 0.f};
  f32x4 acc[2][4];
#pragma unroll
  for (int i = 0; i < 2; ++i)
#pragma unroll
    for (int j = 0; j < 4; ++j) acc[i][j] = z4;

  auto load_chunk = [&](int ch, s16x8 af[2], s16x8 bf_[4]) {
#pragma unroll
    for (int i = 0; i < 2; ++i) {
      const int row = r0 + (wr * 2 + i) * 16 + lm;
      s16x8 a = (s16x8)0;
      if (row < M) {
        const float4 f0 = *reinterpret_cast<const float4*>(&x[(size_t)row * 512 + ch * 32 + lg * 8]);
        const float4 f1 = *reinterpret_cast<const float4*>(&x[(size_t)row * 512 + ch * 32 + lg * 8 + 4]);
        a[0] = (short)f2bfh(f0.x); a[1] = (short)f2bfh(f0.y);
        a[2] = (short)f2bfh(f0.z); a[3] = (short)f2bfh(f0.w);
        a[4] = (short)f2bfh(f1.x); a[5] = (short)f2bfh(f1.y);
        a[6] = (short)f2bfh(f1.z); a[7] = (short)f2bfh(f1.w);
      }
      af[i] = a;
    }
#pragma unroll
    for (int j = 0; j < 4; ++j) {
      const int n = (wc * 4 + j) * 16 + lm;
      bf_[j] = *reinterpret_cast<const s16x8*>(&WT[(size_t)n * 512 + ch * 32 + lg * 8]);
    }
  };

  s16x8 af[2], bf_[4];
  load_chunk(0, af, bf_);
  for (int ch = 0; ch < 16; ++ch) {
    s16x8 naf[2], nbf[4];
    if (ch < 15) load_chunk(ch + 1, naf, nbf);
#pragma unroll
    for (int i = 0; i < 2; ++i)
#pragma unroll
      for (int j = 0; j < 4; ++j)
        acc[i][j] = __builtin_amdgcn_mfma_f32_16x16x32_bf16(af[i], bf_[j], acc[i][j], 0, 0, 0);
    if (ch < 15) {
#pragma unroll
      for (int i = 0; i < 2; ++i) af[i] = naf[i];
#pragma unroll
      for (int j = 0; j < 4; ++j) bf_[j] = nbf[j];
    }
  }

#pragma unroll
  for (int i = 0; i < 2; ++i) {
#pragma unroll
    for (int rr = 0; rr < 4; ++rr) {
      const int row = r0 + (wr * 2 + i) * 16 + lg * 4 + rr;
      if (row < M) {
#pragma unroll
        for (int j = 0; j < 4; ++j)
          C[(size_t)row * 128 + (wc * 4 + j) * 16 + lm] = acc[i][j][rr];
      }
    }
  }
}

// ------- MFMA fused 16->128->128 MLP over bf16 rows -------
// 64 rows/block, 4 waves = 4 col-quadrants (32 cols each). 16KB LDS.
// MODE 0: logit -> exp -> bf16 store.  MODE 1: logit -> lrelu(0.01) -> bf16 store.
template <int MODE>
__global__ __launch_bounds__(256) void k_emlp(
    const u16* __restrict__ inp,              // [R][16] bf16
    const u16* __restrict__ WaTg, const u16* __restrict__ WbTg,
    const float* __restrict__ bbias,
    u16* __restrict__ outp, int R) {
  __shared__ __align__(16) unsigned char sU[16384];
  const int tid = threadIdx.x;
  const int lane = tid & 63;
  const int wc = tid >> 6;   // 0..3 col quadrant
  const int lg = lane >> 4;
  const int lm = lane & 15;
  const int r0 = blockIdx.x * 64;

  // ---- stage-1 A frags (K=16 zero-padded to 32), direct bf16 loads ----
  s16x8 afr[4];
#pragma unroll
  for (int i = 0; i < 4; ++i) {
    s16x8 a = (s16x8)0;
    if (lg < 2) {
      const int r = r0 + i * 16 + lm;
      if (r < R) a = *reinterpret_cast<const s16x8*>(&inp[(size_t)r * 16 + lg * 8]);
    }
    afr[i] = a;
  }

  // ---- stage-1 B frags (Wa: [128][16] bf16) ----
  const f32x4 z4 = {0.f, 0.f, 0.f, 0.f};
  s16x8 bfr1[2];
#pragma unroll
  for (int j = 0; j < 2; ++j) {
    s16x8 b = (s16x8)0;
    if (lg < 2) {
      const int n = wc * 32 + j * 16 + lm;
      b = *reinterpret_cast<const s16x8*>(&WaTg[n * 16 + lg * 8]);
    }
    bfr1[j] = b;
  }

  // ---- stage 1: U = lrelu(K @ Wa) ----
  f32x4 acc1[4][2];
#pragma unroll
  for (int i = 0; i < 4; ++i)
#pragma unroll
    for (int j = 0; j < 2; ++j) acc1[i][j] = z4;
#pragma unroll
  for (int i = 0; i < 4; ++i)
#pragma unroll
    for (int j = 0; j < 2; ++j)
      acc1[i][j] = __builtin_amdgcn_mfma_f32_16x16x32_bf16(afr[i], bfr1[j], acc1[i][j], 0, 0, 0);

  // write U to LDS (bf16, XOR-16 swizzled); C layout: col=lane&15, row=(lane>>4)*4+reg
#pragma unroll
  for (int i = 0; i < 4; ++i) {
#pragma unroll
    for (int j = 0; j < 2; ++j) {
#pragma unroll
      for (int rr = 0; rr < 4; ++rr) {
        float v = acc1[i][j][rr];
        v = (v >= 0.f) ? v : 0.2f * v;
        const int grow = i * 16 + lg * 4 + rr;
        const int gcol = wc * 32 + j * 16 + lm;
        const int byte = grow * 256 + ((((gcol >> 3) ^ (grow & 15))) << 4) + (gcol & 7) * 2;
        *reinterpret_cast<u16*>(&sU[byte]) = f2bfh(v);
      }
    }
  }
  __syncthreads();

  // ---- stage 2: logit = U @ Wb (A from LDS, B direct from global L2) ----
  f32x4 acc[4][2];
#pragma unroll
  for (int i = 0; i < 4; ++i)
#pragma unroll
    for (int j = 0; j < 2; ++j) acc[i][j] = z4;
#pragma unroll
  for (int kb = 0; kb < 4; ++kb) {
    s16x8 af[4], bf_[2];
    const int ch = kb * 4 + lg;
#pragma unroll
    for (int j = 0; j < 2; ++j) {
      const int n = wc * 32 + j * 16 + lm;
      bf_[j] = *reinterpret_cast<const s16x8*>(&WbTg[n * 128 + ch * 8]);
    }
#pragma unroll
    for (int i = 0; i < 4; ++i) {
      const int row = i * 16 + lm;
      af[i] = *reinterpret_cast<const s16x8*>(&sU[row * 256 + ((ch ^ (row & 15)) << 4)]);
    }
#pragma unroll
    for (int i = 0; i < 4; ++i)
#pragma unroll
      for (int j = 0; j < 2; ++j)
        acc[i][j] = __builtin_amdgcn_mfma_f32_16x16x32_bf16(af[i], bf_[j], acc[i][j], 0, 0, 0);
  }
  __syncthreads();  // done reading sU; safe to overwrite

  // ---- epilogue: activation, write bf16 tile to LDS (swizzled) ----
  float bv[2];
#pragma unroll
  for (int j = 0; j < 2; ++j) bv[j] = bbias[wc * 32 + j * 16 + lm];
#pragma unroll
  for (int i = 0; i < 4; ++i) {
#pragma unroll
    for (int j = 0; j < 2; ++j) {
#pragma unroll
      for (int rr = 0; rr < 4; ++rr) {
        float v = acc[i][j][rr] + bv[j];
        if (MODE == 0) v = __expf(v);
        else v = (v >= 0.f) ? v : 0.01f * v;
        const int grow = i * 16 + lg * 4 + rr;
        const int gcol = wc * 32 + j * 16 + lm;
        const int byte = grow * 256 + ((((gcol >> 3) ^ (grow & 15))) << 4) + (gcol & 7) * 2;
        *reinterpret_cast<u16*>(&sU[byte]) = f2bfh(v);
      }
    }
  }
  __syncthreads();

  // ---- coalesced copy-out: 1024 uint4, linearized ----
  const int rmax = R - r0;
#pragma unroll
  for (int q = 0; q < 4; ++q) {
    const int u = tid + q * 256;
    const int row = u >> 4, c8 = u & 15;
    if (row < rmax) {
      const uint4 v = *reinterpret_cast<const uint4*>(&sU[row * 256 + ((c8 ^ (row & 15)) << 4)]);
      *reinterpret_cast<uint4*>(&outp[(size_t)(r0 + row) * 128 + c8 * 8]) = v;
    }
  }
}

// ------------- fused 16->40->40 MLP, one row per thread, bf16 input ----------
// MODE 0: exp -> bf16 ew.  MODE 1: lrelu(0.01) -> bf16 pw.
template <int MODE>
__global__ __launch_bounds__(256) void k_mlp40(
    const u16* __restrict__ inp,
    const float* __restrict__ Wa, const float* __restrict__ Wb,
    const float* __restrict__ bbias, u16* __restrict__ outp, int R) {
  __shared__ float Wa_s[16 * 40];
  __shared__ float Wb_s[40 * 40];
  __shared__ float bb_s[40];
  const int tid = threadIdx.x;
  for (int i = tid; i < 640; i += 256) Wa_s[i] = Wa[i];
  for (int i = tid; i < 1600; i += 256) Wb_s[i] = Wb[i];
  if (tid < 40) bb_s[tid] = bbias[tid];
  __syncthreads();
  const int r = blockIdx.x * 256 + tid;
  if (r >= R) return;

  float kreg[16];
  {
    const uint4 v0 = *reinterpret_cast<const uint4*>(&inp[(size_t)r * 16]);
    const uint4 v1 = *reinterpret_cast<const uint4*>(&inp[(size_t)r * 16 + 8]);
    const u32 ws[8] = {v0.x, v0.y, v0.z, v0.w, v1.x, v1.y, v1.z, v1.w};
#pragma unroll
    for (int t = 0; t < 8; ++t) {
      kreg[2 * t] = bf2f((u16)(ws[t] & 0xffffu));
      kreg[2 * t + 1] = bf2f((u16)(ws[t] >> 16));
    }
  }

  float u[40];
#pragma unroll
  for (int c = 0; c < 40; ++c) u[c] = 0.f;
#pragma unroll
  for (int j = 0; j < 16; ++j) {
    const float kj = kreg[j];
#pragma unroll
    for (int c4 = 0; c4 < 10; ++c4) {
      const float4 w = *reinterpret_cast<const float4*>(&Wa_s[j * 40 + c4 * 4]);
      u[c4 * 4 + 0] = fmaf(kj, w.x, u[c4 * 4 + 0]);
      u[c4 * 4 + 1] = fmaf(kj, w.y, u[c4 * 4 + 1]);
      u[c4 * 4 + 2] = fmaf(kj, w.z, u[c4 * 4 + 2]);
      u[c4 * 4 + 3] = fmaf(kj, w.w, u[c4 * 4 + 3]);
    }
  }
#pragma unroll
  for (int c = 0; c < 40; ++c) u[c] = (u[c] >= 0.f) ? u[c] : 0.2f * u[c];

  float o[40];
#pragma unroll
  for (int c = 0; c < 40; ++c) o[c] = bb_s[c];
#pragma unroll
  for (int j = 0; j < 40; ++j) {
    const float uj = u[j];
#pragma unroll
    for (int c4 = 0; c4 < 10; ++c4) {
      const float4 w = *reinterpret_cast<const float4*>(&Wb_s[j * 40 + c4 * 4]);
      o[c4 * 4 + 0] = fmaf(uj, w.x, o[c4 * 4 + 0]);
      o[c4 * 4 + 1] = fmaf(uj, w.y, o[c4 * 4 + 1]);
      o[c4 * 4 + 2] = fmaf(uj, w.z, o[c4 * 4 + 2]);
      o[c4 * 4 + 3] = fmaf(uj, w.w, o[c4 * 4 + 3]);
    }
  }
#pragma unroll
  for (int c = 0; c < 40; ++c) {
    float v = o[c];
    if (MODE == 0) v = __expf(v);
    else v = (v >= 0.f) ? v : 0.01f * v;
    o[c] = v;
  }
#pragma unroll
  for (int c2 = 0; c2 < 20; ++c2) {
    u32 pk = (u32)f2bfh(o[2 * c2]) | ((u32)f2bfh(o[2 * c2 + 1]) << 16);
    *reinterpret_cast<u32*>(&outp[(size_t)r * 40 + c2 * 2]) = pk;
  }
}

// ------------- h2 = y1 @ W2  [M,128]@[128,40] ----------
__global__ __launch_bounds__(256) void k_gemm2(const float* __restrict__ A,
                                               const float* __restrict__ B,
                                               float* __restrict__ C, int M) {
  __shared__ float Bs[128 * 40];
  const int tid = threadIdx.x;
  for (int i = tid; i < 5120; i += 256) Bs[i] = B[i];
  __syncthreads();
  const int r = blockIdx.x * 6 + tid / 40;
  const int c = tid % 40;
  if (tid >= 240 || r >= M) return;
  const float* arow = &A[(size_t)r * 128];
  float acc = 0.f;
#pragma unroll
  for (int k4 = 0; k4 < 32; ++k4) {
    const float4 av = *reinterpret_cast<const float4*>(&arow[k4 * 4]);
    acc = fmaf(av.x, Bs[(k4 * 4 + 0) * 40 + c], acc);
    acc = fmaf(av.y, Bs[(k4 * 4 + 1) * 40 + c], acc);
    acc = fmaf(av.z, Bs[(k4 * 4 + 2) * 40 + c], acc);
    acc = fmaf(av.w, Bs[(k4 * 4 + 3) * 40 + c], acc);
  }
  C[(size_t)r * 40 + c] = acc;
}

// ================= CSR build =================
__global__ __launch_bounds__(256) void k_hist(const int* __restrict__ src,
                                              const int* __restrict__ dst,
                                              int* __restrict__ cnt, int N, int E) {
  const int e = blockIdx.x * 256 + threadIdx.x;
  if (e >= E) return;
  atomicAdd(&cnt[src[e]], 1);
  atomicAdd(&cnt[N + dst[e]], 1);
}

__global__ __launch_bounds__(256) void k_scanA(const int* __restrict__ cnt,
                                               int* __restrict__ bsum, int N, int NB) {
  const int arr = blockIdx.x / NB, bb = blockIdx.x % NB;
  const int g = bb * 256 + threadIdx.x;
  int v = (g < N) ? cnt[arr * N + g] : 0;
  __shared__ int sd[256];
  sd[threadIdx.x] = v;
  __syncthreads();
  for (int off = 128; off > 0; off >>= 1) {
    if (threadIdx.x < off) sd[threadIdx.x] += sd[threadIdx.x + off];
    __syncthreads();
  }
  if (threadIdx.x == 0) bsum[arr * 256 + bb] = sd[0];
}

__global__ __launch_bounds__(256) void k_scanB(const int* __restrict__ bsum,
                                               int* __restrict__ boff, int NB) {
  __shared__ int sd[256];
  for (int arr = 0; arr < 2; ++arr) {
    const int v = (threadIdx.x < NB) ? bsum[arr * 256 + threadIdx.x] : 0;
    sd[threadIdx.x] = v;
    __syncthreads();
    for (int off = 1; off < 256; off <<= 1) {
      const int t = (threadIdx.x >= off) ? sd[threadIdx.x - off] : 0;
      __syncthreads();
      sd[threadIdx.x] += t;
      __syncthreads();
    }
    if (threadIdx.x < NB) boff[arr * 256 + threadIdx.x] = sd[threadIdx.x] - v;
    __syncthreads();
  }
}

__global__ __launch_bounds__(256) void k_scanC(const int* __restrict__ cnt,
                                               const int* __restrict__ boff,
                                               int* __restrict__ row_src,
                                               int* __restrict__ row_dst,
                                               int* __restrict__ cur, int N, int NB) {
  const int arr = blockIdx.x / NB, bb = blockIdx.x % NB;
  const int g = bb * 256 + threadIdx.x;
  const int v = (g < N) ? cnt[arr * N + g] : 0;
  __shared__ int sd[256];
  sd[threadIdx.x] = v;
  __syncthreads();
  for (int off = 1; off < 256; off <<= 1) {
    const int t = (threadIdx.x >= off) ? sd[threadIdx.x - off] : 0;
    __syncthreads();
    sd[threadIdx.x] += t;
    __syncthreads();
  }
  const int incl = sd[threadIdx.x];
  const int base = boff[arr * 256 + bb];
  int* row = arr ? row_dst : row_src;
  if (g < N) {
    row[g] = base + incl - v;
    cur[arr * N + g] = base + incl - v;
    if (g == N - 1) row[N] = base + incl;
  }
}

// per-edge: ps = src-order position, pd = dst-order position
__global__ __launch_bounds__(256) void k_scatter(const int* __restrict__ src,
                                                 const int* __restrict__ dst,
                                                 int* __restrict__ cur,
                                                 int* __restrict__ eid_src,
                                                 int* __restrict__ possD,
                                                 int* __restrict__ srcb, int N, int E) {
  const int e = blockIdx.x * 256 + threadIdx.x;
  if (e >= E) return;
  const int s = src[e], d = dst[e];
  const int ps = atomicAdd(&cur[s], 1);
  eid_src[ps] = e;
  const int pd = atomicAdd(&cur[N + d], 1);
  possD[pd] = ps;
  srcb[pd] = s;
}

// ===== streaming: s = sum of ew rows [r0,r1) (src-CSR-ordered), g = h/(s+eps) =====
template <int C>
__global__ __launch_bounds__(256) void k_norm(const int* __restrict__ rowp,
                                              const u16* __restrict__ ew,
                                              float* __restrict__ h, int N) {
  const int lane = threadIdx.x & 63;
  const int wv = threadIdx.x >> 6;
  const int n = blockIdx.x * 4 + wv;
  if (n >= N) return;
  constexpr int CPL = (C == 128) ? 2 : 1;
  const int c0 = lane * CPL;
  if (c0 >= C) return;
  const int r0 = rowp[n], r1 = rowp[n + 1];
  float a0 = 0.f, a1 = 0.f;
  int p = r0;
  if (CPL == 2) {
    for (; p + 2 <= r1; p += 2) {
      const u32 w0 = *reinterpret_cast<const u32*>(&ew[(size_t)p * C + c0]);
      const u32 w1 = *reinterpret_cast<const u32*>(&ew[(size_t)(p + 1) * C + c0]);
      a0 += bf2f((u16)(w0 & 0xffffu)) + bf2f((u16)(w1 & 0xffffu));
      a1 += bf2f((u16)(w0 >> 16)) + bf2f((u16)(w1 >> 16));
    }
    for (; p < r1; ++p) {
      const u32 w0 = *reinterpret_cast<const u32*>(&ew[(size_t)p * C + c0]);
      a0 += bf2f((u16)(w0 & 0xffffu));
      a1 += bf2f((u16)(w0 >> 16));
    }
    float2 hv = *reinterpret_cast<const float2*>(&h[(size_t)n * C + c0]);
    hv.x /= (a0 + SM_EPS);
    hv.y /= (a1 + SM_EPS);
    *reinterpret_cast<float2*>(&h[(size_t)n * C + c0]) = hv;
  } else {
    for (; p + 2 <= r1; p += 2)
      a0 += bf2f(ew[(size_t)p * C + c0]) + bf2f(ew[(size_t)(p + 1) * C + c0]);
    for (; p < r1; ++p) a0 += bf2f(ew[(size_t)p * C + c0]);
    h[(size_t)n * C + c0] /= (a0 + SM_EPS);
  }
}

// ===== out[n] = sum_{in-edges} ew[poss[p]] * g[srcb[p]] + b + alpha*pw(bf16), opt ELU =====
template <int C, int DO_ELU>
__global__ __launch_bounds__(256) void k_aggf(const int* __restrict__ rowp,
                                              const int* __restrict__ poss,
                                              const int* __restrict__ srcb,
                                              const u16* __restrict__ ew,
                                              const float* __restrict__ g,
                                              const u16* __restrict__ pw,
                                              const float* __restrict__ bias,
                                              const float* __restrict__ alpha_p,
                                              float* __restrict__ out, int N) {
  const int lane = threadIdx.x & 63;
  const int wv = threadIdx.x >> 6;
  const int n = blockIdx.x * 4 + wv;
  if (n >= N) return;
  constexpr int CPL = (C == 128) ? 2 : 1;
  const int c0 = lane * CPL;
  if (c0 >= C) return;
  const int r0 = rowp[n], r1 = rowp[n + 1];
  float a0 = 0.f, a1 = 0.f;
  int p = r0;
  if (CPL == 2) {
    for (; p + 4 <= r1; p += 4) {
      const int s0 = srcb[p + 0], s1 = srcb[p + 1], s2 = srcb[p + 2], s3 = srcb[p + 3];
      const int q0 = poss[p + 0], q1 = poss[p + 1], q2 = poss[p + 2], q3 = poss[p + 3];
      const u32 w0 = *reinterpret_cast<const u32*>(&ew[(size_t)q0 * C + c0]);
      const u32 w1 = *reinterpret_cast<const u32*>(&ew[(size_t)q1 * C + c0]);
      const u32 w2 = *reinterpret_cast<const u32*>(&ew[(size_t)q2 * C + c0]);
      const u32 w3 = *reinterpret_cast<const u32*>(&ew[(size_t)q3 * C + c0]);
      const float2 g0 = *reinterpret_cast<const float2*>(&g[(size_t)s0 * C + c0]);
      const float2 g1 = *reinterpret_cast<const float2*>(&g[(size_t)s1 * C + c0]);
      const float2 g2 = *reinterpret_cast<const float2*>(&g[(size_t)s2 * C + c0]);
      const float2 g3 = *reinterpret_cast<const float2*>(&g[(size_t)s3 * C + c0]);
      a0 = fmaf(bf2f((u16)(w0 & 0xffffu)), g0.x, a0);
      a1 = fmaf(bf2f((u16)(w0 >> 16)), g0.y, a1);
      a0 = fmaf(bf2f((u16)(w1 & 0xffffu)), g1.x, a0);
      a1 = fmaf(bf2f((u16)(w1 >> 16)), g1.y, a1);
      a0 = fmaf(bf2f((u16)(w2 & 0xffffu)), g2.x, a0);
      a1 = fmaf(bf2f((u16)(w2 >> 16)), g2.y, a1);
      a0 = fmaf(bf2f((u16)(w3 & 0xffffu)), g3.x, a0);
      a1 = fmaf(bf2f((u16)(w3 >> 16)), g3.y, a1);
    }
    for (; p < r1; ++p) {
      const int s0 = srcb[p];
      const int q0 = poss[p];
      const u32 w0 = *reinterpret_cast<const u32*>(&ew[(size_t)q0 * C + c0]);
      const float2 g0 = *reinterpret_cast<const float2*>(&g[(size_t)s0 * C + c0]);
      a0 = fmaf(bf2f((u16)(w0 & 0xffffu)), g0.x, a0);
      a1 = fmaf(bf2f((u16)(w0 >> 16)), g0.y, a1);
    }
    const float al = alpha_p[0];
    const u32 pv2 = *reinterpret_cast<const u32*>(&pw[(size_t)n * C + c0]);
    float v0 = a0 + bias[c0] + al * bf2f((u16)(pv2 & 0xffffu));
    float v1 = a1 + bias[c0 + 1] + al * bf2f((u16)(pv2 >> 16));
    if (DO_ELU) {
      v0 = (v0 > 0.f) ? v0 : expm1f(v0);
      v1 = (v1 > 0.f) ? v1 : expm1f(v1);
    }
    *reinterpret_cast<float2*>(&out[(size_t)n * C + c0]) = make_float2(v0, v1);
  } else {
    for (; p + 4 <= r1; p += 4) {
      const int s0 = srcb[p + 0], s1 = srcb[p + 1], s2 = srcb[p + 2], s3 = srcb[p + 3];
      const int q0 = poss[p + 0], q1 = poss[p + 1], q2 = poss[p + 2], q3 = poss[p + 3];
      const float w0 = bf2f(ew[(size_t)q0 * C + c0]);
      const float w1 = bf2f(ew[(size_t)q1 * C + c0]);
      const float w2 = bf2f(ew[(size_t)q2 * C + c0]);
      const float w3 = bf2f(ew[(size_t)q3 * C + c0]);
      const float g0 = g[(size_t)s0 * C + c0];
      const float g1 = g[(size_t)s1 * C + c0];
      const float g2 = g[(size_t)s2 * C + c0];
      const float g3 = g[(size_t)s3 * C + c0];
      a0 = fmaf(w0, g0, a0);
      a0 = fmaf(w1, g1, a0);
      a0 = fmaf(w2, g2, a0);
      a0 = fmaf(w3, g3, a0);
    }
    for (; p < r1; ++p)
      a0 = fmaf(bf2f(ew[(size_t)poss[p] * C + c0]), g[(size_t)srcb[p] * C + c0], a0);
    float v = a0 + bias[c0] + alpha_p[0] * bf2f(pw[(size_t)n * C + c0]);
    if (DO_ELU) v = (v > 0.f) ? v : expm1f(v);
    out[(size_t)n * C + c0] = v;
  }
}

extern "C" void kernel_launch(void* const* d_in, const int* in_sizes, int n_in,
                              void* d_out, int out_size, void* d_ws, size_t ws_size,
                              hipStream_t stream) {
  const float* x    = (const float*)d_in[0];
  const int*   ei   = (const int*)d_in[1];
  const float* kric = (const float*)d_in[2];
  const float* epoi = (const float*)d_in[3];
  const float* alpha= (const float*)d_in[4];
  const float* W1   = (const float*)d_in[5];
  const float* Wa1  = (const float*)d_in[6];
  const float* Wb1  = (const float*)d_in[7];
  const float* bb1  = (const float*)d_in[8];
  const float* Wc1  = (const float*)d_in[9];
  const float* Wd1  = (const float*)d_in[10];
  const float* bd1  = (const float*)d_in[11];
  const float* b1   = (const float*)d_in[12];
  const float* W2   = (const float*)d_in[13];
  const float* Wa2  = (const float*)d_in[14];
  const float* Wb2  = (const float*)d_in[15];
  const float* bb2  = (const float*)d_in[16];
  const float* Wc2  = (const float*)d_in[17];
  const float* Wd2  = (const float*)d_in[18];
  const float* bd2  = (const float*)d_in[19];
  const float* b2   = (const float*)d_in[20];

  const int N = in_sizes[0] / 512;
  const int E = in_sizes[1] / 2;
  const int* srcI = ei;
  const int* dstI = ei + E;
  const int NB = (N + 255) / 256;

  // ---- workspace layout ----
  char* p = (char*)d_ws;
  int* cnt      = (int*)p; p += (size_t)2 * N * 4;
  int* cur      = (int*)p; p += (size_t)2 * N * 4;
  int* bsum     = (int*)p; p += 512 * 4;
  int* boff     = (int*)p; p += 512 * 4;
  int* row_src  = (int*)p; p += (size_t)(N + 1) * 4;
  int* row_dst  = (int*)p; p += (size_t)(N + 1) * 4;
  int* eid_src  = (int*)p; p += (size_t)E * 4;
  int* possD    = (int*)p; p += (size_t)E * 4;
  int* srcb     = (int*)p; p += (size_t)E * 4;
  p = (char*)(((uintptr_t)p + 255) & ~(uintptr_t)255);
  u16* WaT1g = (u16*)p; p += 2048 * 2;
  u16* WbT1g = (u16*)p; p += 16384 * 2;
  u16* WcT1g = (u16*)p; p += 2048 * 2;
  u16* WdT1g = (u16*)p; p += 16384 * 2;
  u16* W1Tg  = (u16*)p; p += 65536 * 2;
  p = (char*)(((uintptr_t)p + 255) & ~(uintptr_t)255);
  u16* kricP = (u16*)p; p += (size_t)E * 16 * 2;   // bf16, src-CSR order
  u16* epoiP = (u16*)p; p += (size_t)N * 16 * 2;   // bf16
  p = (char*)(((uintptr_t)p + 255) & ~(uintptr_t)255);
  float* h1  = (float*)p; p += (size_t)N * 128 * 4;  // becomes g1 in place
  float* y1  = (float*)p; p += (size_t)N * 128 * 4;
  float* h2  = (float*)p; p += (size_t)N * 40 * 4;   // becomes g2 in place
  u16* pw1   = (u16*)p;  p += (size_t)N * 128 * 2;   // bf16
  u16* pw2   = (u16*)p;  p += (size_t)N * 40 * 2;    // bf16
  p = (char*)(((uintptr_t)p + 255) & ~(uintptr_t)255);
  u16* ew    = (u16*)p;  // E*128 bf16 (layer 1), reused E*40 (layer 2); src-CSR order

  // ---- CSR build (once, reused by both layers) + weight/input prep ----
  hipMemsetAsync(cnt, 0, (size_t)2 * N * 4, stream);
  k_prep<<<400, 256, 0, stream>>>(Wa1, Wb1, Wc1, Wd1, W1, WaT1g, WbT1g, WcT1g, WdT1g, W1Tg);
  k_hist<<<(E + 255) / 256, 256, 0, stream>>>(srcI, dstI, cnt, N, E);
  k_scanA<<<2 * NB, 256, 0, stream>>>(cnt, bsum, N, NB);
  k_scanB<<<1, 256, 0, stream>>>(bsum, boff, NB);
  k_scanC<<<2 * NB, 256, 0, stream>>>(cnt, boff, row_src, row_dst, cur, N, NB);
  k_scatter<<<(E + 255) / 256, 256, 0, stream>>>(srcI, dstI, cur, eid_src, possD, srcb, N, E);
  k_prepIn<<<(2 * (E + N) + 255) / 256, 256, 0, stream>>>(kric, eid_src, kricP, epoi, epoiP, E, N);

  // ---------------- layer 1 ----------------
  k_gemm1m<<<(N + 63) / 64, 256, 0, stream>>>(x, W1Tg, h1, N);
  k_emlp<0><<<(E + 63) / 64, 256, 0, stream>>>(kricP, WaT1g, WbT1g, bb1, ew, E);
  k_emlp<1><<<(N + 63) / 64, 256, 0, stream>>>(epoiP, WcT1g, WdT1g, bd1, pw1, N);
  k_norm<128><<<(N + 3) / 4, 256, 0, stream>>>(row_src, ew, h1, N);
  k_aggf<128, 1><<<(N + 3) / 4, 256, 0, stream>>>(row_dst, possD, srcb, ew, h1, pw1, b1, alpha, y1, N);

  // ---------------- layer 2 ----------------
  k_gemm2<<<(N + 5) / 6, 256, 0, stream>>>(y1, W2, h2, N);
  k_mlp40<0><<<(E + 255) / 256, 256, 0, stream>>>(kricP, Wa2, Wb2, bb2, ew, E);
  k_mlp40<1><<<(N + 255) / 256, 256, 0, stream>>>(epoiP, Wc2, Wd2, bd2, pw2, N);
  k_norm<40><<<(N + 3) / 4, 256, 0, stream>>>(row_src, ew, h2, N);
  k_aggf<40, 0><<<(N + 3) / 4, 256, 0, stream>>>(row_dst, possD, srcb, ew, h2, pw2, b2, alpha, (float*)d_out, N);
}

// Round 11
// 710.808 us; speedup vs baseline: 9.9677x; 1.0843x over previous
//
#include <hip/hip_runtime.h>
#include <math.h>

#define SM_EPS 1e-16f

typedef unsigned short u16;
typedef unsigned int u32;
typedef short s16x8 __attribute__((ext_vector_type(8)));
typedef float f32x4 __attribute__((ext_vector_type(4)));

__device__ __forceinline__ u16 f2bfh(float x) {
  __bf16 b = (__bf16)x;
  return __builtin_bit_cast(unsigned short, b);
}
__device__ __forceinline__ float bf2f(u16 u) {
  return __uint_as_float(((u32)u) << 16);
}

// -------- weight + epoi prep: transpose + bf16 convert (once per call) --------
// WaTg [128][16], WbTg [128][128], WcTg [128][16], WdTg [128][128], W1Tg [128][512],
// epoiP [N][16] bf16 (2 threads/row).
__global__ __launch_bounds__(256) void k_prep(const float* __restrict__ Wa,
                                              const float* __restrict__ Wb,
                                              const float* __restrict__ Wc,
                                              const float* __restrict__ Wd,
                                              const float* __restrict__ W1,
                                              const float* __restrict__ epoi,
                                              u16* __restrict__ WaTg, u16* __restrict__ WbTg,
                                              u16* __restrict__ WcTg, u16* __restrict__ WdTg,
                                              u16* __restrict__ W1Tg, u16* __restrict__ epoiP,
                                              int N) {
  const int idx = blockIdx.x * 256 + threadIdx.x;
  if (idx < 2048) {
    const int n = idx >> 4, k = idx & 15;
    WaTg[idx] = f2bfh(Wa[k * 128 + n]);
  } else if (idx < 18432) {
    const int t = idx - 2048;
    const int n = t >> 7, k = t & 127;
    WbTg[t] = f2bfh(Wb[k * 128 + n]);
  } else if (idx < 20480) {
    const int t = idx - 18432;
    const int n = t >> 4, k = t & 15;
    WcTg[t] = f2bfh(Wc[k * 128 + n]);
  } else if (idx < 36864) {
    const int t = idx - 20480;
    const int n = t >> 7, k = t & 127;
    WdTg[t] = f2bfh(Wd[k * 128 + n]);
  } else if (idx < 102400) {
    const int t = idx - 36864;
    const int n = t >> 9, k = t & 511;
    W1Tg[t] = f2bfh(W1[k * 128 + n]);
  } else if (idx < 102400 + 2 * N) {
    const int t = idx - 102400;
    const int r = t >> 1, half = t & 1;
    const float4 f0 = *reinterpret_cast<const float4*>(&epoi[(size_t)r * 16 + half * 8]);
    const float4 f1 = *reinterpret_cast<const float4*>(&epoi[(size_t)r * 16 + half * 8 + 4]);
    u32 pk[4];
    pk[0] = (u32)f2bfh(f0.x) | ((u32)f2bfh(f0.y) << 16);
    pk[1] = (u32)f2bfh(f0.z) | ((u32)f2bfh(f0.w) << 16);
    pk[2] = (u32)f2bfh(f1.x) | ((u32)f2bfh(f1.y) << 16);
    pk[3] = (u32)f2bfh(f1.z) | ((u32)f2bfh(f1.w) << 16);
    *reinterpret_cast<uint4*>(&epoiP[(size_t)r * 16 + half * 8]) = make_uint4(pk[0], pk[1], pk[2], pk[3]);
  }
}

// ---------------- h1 = x @ W1 via MFMA: [M,512]@[512,128], bf16 ----------------
__global__ __launch_bounds__(256) void k_gemm1m(const float* __restrict__ x,
                                                const u16* __restrict__ WT,  // [128][512]
                                                float* __restrict__ C, int M) {
  const int tid = threadIdx.x;
  const int lane = tid & 63;
  const int w = tid >> 6;
  const int wr = w >> 1, wc = w & 1;
  const int lg = lane >> 4;
  const int lm = lane & 15;
  const int r0 = blockIdx.x * 64;

  const f32x4 z4 = {0.f, 0.f, 0.f, 0.f};
  f32x4 acc[2][4];
#pragma unroll
  for (int i = 0; i < 2; ++i)
#pragma unroll
    for (int j = 0; j < 4; ++j) acc[i][j] = z4;

  auto load_chunk = [&](int ch, s16x8 af[2], s16x8 bf_[4]) {
#pragma unroll
    for (int i = 0; i < 2; ++i) {
      const int row = r0 + (wr * 2 + i) * 16 + lm;
      s16x8 a = (s16x8)0;
      if (row < M) {
        const float4 f0 = *reinterpret_cast<const float4*>(&x[(size_t)row * 512 + ch * 32 + lg * 8]);
        const float4 f1 = *reinterpret_cast<const float4*>(&x[(size_t)row * 512 + ch * 32 + lg * 8 + 4]);
        a[0] = (short)f2bfh(f0.x); a[1] = (short)f2bfh(f0.y);
        a[2] = (short)f2bfh(f0.z); a[3] = (short)f2bfh(f0.w);
        a[4] = (short)f2bfh(f1.x); a[5] = (short)f2bfh(f1.y);
        a[6] = (short)f2bfh(f1.z); a[7] = (short)f2bfh(f1.w);
      }
      af[i] = a;
    }
#pragma unroll
    for (int j = 0; j < 4; ++j) {
      const int n = (wc * 4 + j) * 16 + lm;
      bf_[j] = *reinterpret_cast<const s16x8*>(&WT[(size_t)n * 512 + ch * 32 + lg * 8]);
    }
  };

  s16x8 af[2], bf_[4];
  load_chunk(0, af, bf_);
  for (int ch = 0; ch < 16; ++ch) {
    s16x8 naf[2], nbf[4];
    if (ch < 15) load_chunk(ch + 1, naf, nbf);
#pragma unroll
    for (int i = 0; i < 2; ++i)
#pragma unroll
      for (int j = 0; j < 4; ++j)
        acc[i][j] = __builtin_amdgcn_mfma_f32_16x16x32_bf16(af[i], bf_[j], acc[i][j], 0, 0, 0);
    if (ch < 15) {
#pragma unroll
      for (int i = 0; i < 2; ++i) af[i] = naf[i];
#pragma unroll
      for (int j = 0; j < 4; ++j) bf_[j] = nbf[j];
    }
  }

#pragma unroll
  for (int i = 0; i < 2; ++i) {
#pragma unroll
    for (int rr = 0; rr < 4; ++rr) {
      const int row = r0 + (wr * 2 + i) * 16 + lg * 4 + rr;
      if (row < M) {
#pragma unroll
        for (int j = 0; j < 4; ++j)
          C[(size_t)row * 128 + (wc * 4 + j) * 16 + lm] = acc[i][j][rr];
      }
    }
  }
}

// ------- MFMA fused 16->128->128 MLP over bf16 rows -------
// 64 rows/block, 4 waves = 4 col-quadrants (32 cols each). 16KB LDS.
// MODE 0: logit -> exp -> bf16 store.  MODE 1: logit -> lrelu(0.01) -> bf16 store.
template <int MODE>
__global__ __launch_bounds__(256) void k_emlp(
    const u16* __restrict__ inp,              // [R][16] bf16
    const u16* __restrict__ WaTg, const u16* __restrict__ WbTg,
    const float* __restrict__ bbias,
    u16* __restrict__ outp, int R) {
  __shared__ __align__(16) unsigned char sU[16384];
  const int tid = threadIdx.x;
  const int lane = tid & 63;
  const int wc = tid >> 6;   // 0..3 col quadrant
  const int lg = lane >> 4;
  const int lm = lane & 15;
  const int r0 = blockIdx.x * 64;

  // ---- stage-1 A frags (K=16 zero-padded to 32), direct bf16 loads ----
  s16x8 afr[4];
#pragma unroll
  for (int i = 0; i < 4; ++i) {
    s16x8 a = (s16x8)0;
    if (lg < 2) {
      const int r = r0 + i * 16 + lm;
      if (r < R) a = *reinterpret_cast<const s16x8*>(&inp[(size_t)r * 16 + lg * 8]);
    }
    afr[i] = a;
  }

  // ---- stage-1 B frags (Wa: [128][16] bf16) ----
  const f32x4 z4 = {0.f, 0.f, 0.f, 0.f};
  s16x8 bfr1[2];
#pragma unroll
  for (int j = 0; j < 2; ++j) {
    s16x8 b = (s16x8)0;
    if (lg < 2) {
      const int n = wc * 32 + j * 16 + lm;
      b = *reinterpret_cast<const s16x8*>(&WaTg[n * 16 + lg * 8]);
    }
    bfr1[j] = b;
  }

  // ---- stage 1: U = lrelu(K @ Wa) ----
  f32x4 acc1[4][2];
#pragma unroll
  for (int i = 0; i < 4; ++i)
#pragma unroll
    for (int j = 0; j < 2; ++j) acc1[i][j] = z4;
#pragma unroll
  for (int i = 0; i < 4; ++i)
#pragma unroll
    for (int j = 0; j < 2; ++j)
      acc1[i][j] = __builtin_amdgcn_mfma_f32_16x16x32_bf16(afr[i], bfr1[j], acc1[i][j], 0, 0, 0);

  // write U to LDS (bf16, XOR-16 swizzled); C layout: col=lane&15, row=(lane>>4)*4+reg
#pragma unroll
  for (int i = 0; i < 4; ++i) {
#pragma unroll
    for (int j = 0; j < 2; ++j) {
#pragma unroll
      for (int rr = 0; rr < 4; ++rr) {
        float v = acc1[i][j][rr];
        v = (v >= 0.f) ? v : 0.2f * v;
        const int grow = i * 16 + lg * 4 + rr;
        const int gcol = wc * 32 + j * 16 + lm;
        const int byte = grow * 256 + ((((gcol >> 3) ^ (grow & 15))) << 4) + (gcol & 7) * 2;
        *reinterpret_cast<u16*>(&sU[byte]) = f2bfh(v);
      }
    }
  }
  __syncthreads();

  // ---- stage 2: logit = U @ Wb (A from LDS, B direct from global L2) ----
  f32x4 acc[4][2];
#pragma unroll
  for (int i = 0; i < 4; ++i)
#pragma unroll
    for (int j = 0; j < 2; ++j) acc[i][j] = z4;
#pragma unroll
  for (int kb = 0; kb < 4; ++kb) {
    s16x8 af[4], bf_[2];
    const int ch = kb * 4 + lg;
#pragma unroll
    for (int j = 0; j < 2; ++j) {
      const int n = wc * 32 + j * 16 + lm;
      bf_[j] = *reinterpret_cast<const s16x8*>(&WbTg[n * 128 + ch * 8]);
    }
#pragma unroll
    for (int i = 0; i < 4; ++i) {
      const int row = i * 16 + lm;
      af[i] = *reinterpret_cast<const s16x8*>(&sU[row * 256 + ((ch ^ (row & 15)) << 4)]);
    }
#pragma unroll
    for (int i = 0; i < 4; ++i)
#pragma unroll
      for (int j = 0; j < 2; ++j)
        acc[i][j] = __builtin_amdgcn_mfma_f32_16x16x32_bf16(af[i], bf_[j], acc[i][j], 0, 0, 0);
  }
  __syncthreads();  // done reading sU; safe to overwrite

  // ---- epilogue: activation, write bf16 tile to LDS (swizzled) ----
  float bv[2];
#pragma unroll
  for (int j = 0; j < 2; ++j) bv[j] = bbias[wc * 32 + j * 16 + lm];
#pragma unroll
  for (int i = 0; i < 4; ++i) {
#pragma unroll
    for (int j = 0; j < 2; ++j) {
#pragma unroll
      for (int rr = 0; rr < 4; ++rr) {
        float v = acc[i][j][rr] + bv[j];
        if (MODE == 0) v = __expf(v);
        else v = (v >= 0.f) ? v : 0.01f * v;
        const int grow = i * 16 + lg * 4 + rr;
        const int gcol = wc * 32 + j * 16 + lm;
        const int byte = grow * 256 + ((((gcol >> 3) ^ (grow & 15))) << 4) + (gcol & 7) * 2;
        *reinterpret_cast<u16*>(&sU[byte]) = f2bfh(v);
      }
    }
  }
  __syncthreads();

  // ---- coalesced copy-out: 1024 uint4, linearized ----
  const int rmax = R - r0;
#pragma unroll
  for (int q = 0; q < 4; ++q) {
    const int u = tid + q * 256;
    const int row = u >> 4, c8 = u & 15;
    if (row < rmax) {
      const uint4 v = *reinterpret_cast<const uint4*>(&sU[row * 256 + ((c8 ^ (row & 15)) << 4)]);
      *reinterpret_cast<uint4*>(&outp[(size_t)(r0 + row) * 128 + c8 * 8]) = v;
    }
  }
}

// ------------- fused 16->40->40 MLP, one row per thread, bf16 input ----------
// MODE 0: exp -> bf16 ew.  MODE 1: lrelu(0.01) -> bf16 pw.
template <int MODE>
__global__ __launch_bounds__(256) void k_mlp40(
    const u16* __restrict__ inp,
    const float* __restrict__ Wa, const float* __restrict__ Wb,
    const float* __restrict__ bbias, u16* __restrict__ outp, int R) {
  __shared__ float Wa_s[16 * 40];
  __shared__ float Wb_s[40 * 40];
  __shared__ float bb_s[40];
  const int tid = threadIdx.x;
  for (int i = tid; i < 640; i += 256) Wa_s[i] = Wa[i];
  for (int i = tid; i < 1600; i += 256) Wb_s[i] = Wb[i];
  if (tid < 40) bb_s[tid] = bbias[tid];
  __syncthreads();
  const int r = blockIdx.x * 256 + tid;
  if (r >= R) return;

  float kreg[16];
  {
    const uint4 v0 = *reinterpret_cast<const uint4*>(&inp[(size_t)r * 16]);
    const uint4 v1 = *reinterpret_cast<const uint4*>(&inp[(size_t)r * 16 + 8]);
    const u32 ws[8] = {v0.x, v0.y, v0.z, v0.w, v1.x, v1.y, v1.z, v1.w};
#pragma unroll
    for (int t = 0; t < 8; ++t) {
      kreg[2 * t] = bf2f((u16)(ws[t] & 0xffffu));
      kreg[2 * t + 1] = bf2f((u16)(ws[t] >> 16));
    }
  }

  float u[40];
#pragma unroll
  for (int c = 0; c < 40; ++c) u[c] = 0.f;
#pragma unroll
  for (int j = 0; j < 16; ++j) {
    const float kj = kreg[j];
#pragma unroll
    for (int c4 = 0; c4 < 10; ++c4) {
      const float4 w = *reinterpret_cast<const float4*>(&Wa_s[j * 40 + c4 * 4]);
      u[c4 * 4 + 0] = fmaf(kj, w.x, u[c4 * 4 + 0]);
      u[c4 * 4 + 1] = fmaf(kj, w.y, u[c4 * 4 + 1]);
      u[c4 * 4 + 2] = fmaf(kj, w.z, u[c4 * 4 + 2]);
      u[c4 * 4 + 3] = fmaf(kj, w.w, u[c4 * 4 + 3]);
    }
  }
#pragma unroll
  for (int c = 0; c < 40; ++c) u[c] = (u[c] >= 0.f) ? u[c] : 0.2f * u[c];

  float o[40];
#pragma unroll
  for (int c = 0; c < 40; ++c) o[c] = bb_s[c];
#pragma unroll
  for (int j = 0; j < 40; ++j) {
    const float uj = u[j];
#pragma unroll
    for (int c4 = 0; c4 < 10; ++c4) {
      const float4 w = *reinterpret_cast<const float4*>(&Wb_s[j * 40 + c4 * 4]);
      o[c4 * 4 + 0] = fmaf(uj, w.x, o[c4 * 4 + 0]);
      o[c4 * 4 + 1] = fmaf(uj, w.y, o[c4 * 4 + 1]);
      o[c4 * 4 + 2] = fmaf(uj, w.z, o[c4 * 4 + 2]);
      o[c4 * 4 + 3] = fmaf(uj, w.w, o[c4 * 4 + 3]);
    }
  }
#pragma unroll
  for (int c = 0; c < 40; ++c) {
    float v = o[c];
    if (MODE == 0) v = __expf(v);
    else v = (v >= 0.f) ? v : 0.01f * v;
    o[c] = v;
  }
#pragma unroll
  for (int c2 = 0; c2 < 20; ++c2) {
    u32 pk = (u32)f2bfh(o[2 * c2]) | ((u32)f2bfh(o[2 * c2 + 1]) << 16);
    *reinterpret_cast<u32*>(&outp[(size_t)r * 40 + c2 * 2]) = pk;
  }
}

// ------------- h2 = y1 @ W2  [M,128]@[128,40] ----------
__global__ __launch_bounds__(256) void k_gemm2(const float* __restrict__ A,
                                               const float* __restrict__ B,
                                               float* __restrict__ C, int M) {
  __shared__ float Bs[128 * 40];
  const int tid = threadIdx.x;
  for (int i = tid; i < 5120; i += 256) Bs[i] = B[i];
  __syncthreads();
  const int r = blockIdx.x * 6 + tid / 40;
  const int c = tid % 40;
  if (tid >= 240 || r >= M) return;
  const float* arow = &A[(size_t)r * 128];
  float acc = 0.f;
#pragma unroll
  for (int k4 = 0; k4 < 32; ++k4) {
    const float4 av = *reinterpret_cast<const float4*>(&arow[k4 * 4]);
    acc = fmaf(av.x, Bs[(k4 * 4 + 0) * 40 + c], acc);
    acc = fmaf(av.y, Bs[(k4 * 4 + 1) * 40 + c], acc);
    acc = fmaf(av.z, Bs[(k4 * 4 + 2) * 40 + c], acc);
    acc = fmaf(av.w, Bs[(k4 * 4 + 3) * 40 + c], acc);
  }
  C[(size_t)r * 40 + c] = acc;
}

// ================= CSR build =================
__global__ __launch_bounds__(256) void k_hist(const int* __restrict__ src,
                                              const int* __restrict__ dst,
                                              int* __restrict__ cnt, int N, int E) {
  const int e = blockIdx.x * 256 + threadIdx.x;
  if (e >= E) return;
  atomicAdd(&cnt[src[e]], 1);
  atomicAdd(&cnt[N + dst[e]], 1);
}

__global__ __launch_bounds__(256) void k_scanA(const int* __restrict__ cnt,
                                               int* __restrict__ bsum, int N, int NB) {
  const int arr = blockIdx.x / NB, bb = blockIdx.x % NB;
  const int g = bb * 256 + threadIdx.x;
  int v = (g < N) ? cnt[arr * N + g] : 0;
  __shared__ int sd[256];
  sd[threadIdx.x] = v;
  __syncthreads();
  for (int off = 128; off > 0; off >>= 1) {
    if (threadIdx.x < off) sd[threadIdx.x] += sd[threadIdx.x + off];
    __syncthreads();
  }
  if (threadIdx.x == 0) bsum[arr * 256 + bb] = sd[0];
}

__global__ __launch_bounds__(256) void k_scanB(const int* __restrict__ bsum,
                                               int* __restrict__ boff, int NB) {
  __shared__ int sd[256];
  for (int arr = 0; arr < 2; ++arr) {
    const int v = (threadIdx.x < NB) ? bsum[arr * 256 + threadIdx.x] : 0;
    sd[threadIdx.x] = v;
    __syncthreads();
    for (int off = 1; off < 256; off <<= 1) {
      const int t = (threadIdx.x >= off) ? sd[threadIdx.x - off] : 0;
      __syncthreads();
      sd[threadIdx.x] += t;
      __syncthreads();
    }
    if (threadIdx.x < NB) boff[arr * 256 + threadIdx.x] = sd[threadIdx.x] - v;
    __syncthreads();
  }
}

__global__ __launch_bounds__(256) void k_scanC(const int* __restrict__ cnt,
                                               const int* __restrict__ boff,
                                               int* __restrict__ row_src,
                                               int* __restrict__ row_dst,
                                               int* __restrict__ cur, int N, int NB) {
  const int arr = blockIdx.x / NB, bb = blockIdx.x % NB;
  const int g = bb * 256 + threadIdx.x;
  const int v = (g < N) ? cnt[arr * N + g] : 0;
  __shared__ int sd[256];
  sd[threadIdx.x] = v;
  __syncthreads();
  for (int off = 1; off < 256; off <<= 1) {
    const int t = (threadIdx.x >= off) ? sd[threadIdx.x - off] : 0;
    __syncthreads();
    sd[threadIdx.x] += t;
    __syncthreads();
  }
  const int incl = sd[threadIdx.x];
  const int base = boff[arr * 256 + bb];
  int* row = arr ? row_dst : row_src;
  if (g < N) {
    row[g] = base + incl - v;
    cur[arr * N + g] = base + incl - v;
    if (g == N - 1) row[N] = base + incl;
  }
}

// per-edge: ps = src-order position, pd = dst-order position.
// Writes kricP[ps] (bf16 row, 32B) and pdInfo[pd] = (ps, src) directly.
__global__ __launch_bounds__(256) void k_scatter(const int* __restrict__ src,
                                                 const int* __restrict__ dst,
                                                 int* __restrict__ cur,
                                                 const float* __restrict__ kric,
                                                 u16* __restrict__ kricP,
                                                 uint2* __restrict__ pdInfo, int N, int E) {
  const int e = blockIdx.x * 256 + threadIdx.x;
  if (e >= E) return;
  const int s = src[e], d = dst[e];
  // coalesced 64B read of kric row e
  const float4 f0 = *reinterpret_cast<const float4*>(&kric[(size_t)e * 16]);
  const float4 f1 = *reinterpret_cast<const float4*>(&kric[(size_t)e * 16 + 4]);
  const float4 f2 = *reinterpret_cast<const float4*>(&kric[(size_t)e * 16 + 8]);
  const float4 f3 = *reinterpret_cast<const float4*>(&kric[(size_t)e * 16 + 12]);
  const int ps = atomicAdd(&cur[s], 1);
  const int pd = atomicAdd(&cur[N + d], 1);
  pdInfo[pd] = make_uint2((u32)ps, (u32)s);
  u32 pk[8];
  pk[0] = (u32)f2bfh(f0.x) | ((u32)f2bfh(f0.y) << 16);
  pk[1] = (u32)f2bfh(f0.z) | ((u32)f2bfh(f0.w) << 16);
  pk[2] = (u32)f2bfh(f1.x) | ((u32)f2bfh(f1.y) << 16);
  pk[3] = (u32)f2bfh(f1.z) | ((u32)f2bfh(f1.w) << 16);
  pk[4] = (u32)f2bfh(f2.x) | ((u32)f2bfh(f2.y) << 16);
  pk[5] = (u32)f2bfh(f2.z) | ((u32)f2bfh(f2.w) << 16);
  pk[6] = (u32)f2bfh(f3.x) | ((u32)f2bfh(f3.y) << 16);
  pk[7] = (u32)f2bfh(f3.z) | ((u32)f2bfh(f3.w) << 16);
  u16* outr = &kricP[(size_t)ps * 16];
  *reinterpret_cast<uint4*>(outr) = make_uint4(pk[0], pk[1], pk[2], pk[3]);
  *reinterpret_cast<uint4*>(outr + 8) = make_uint4(pk[4], pk[5], pk[6], pk[7]);
}

// ===== streaming: s = sum of ew rows [r0,r1) (src-CSR-ordered), g = h/(s+eps) =====
template <int C>
__global__ __launch_bounds__(256) void k_norm(const int* __restrict__ rowp,
                                              const u16* __restrict__ ew,
                                              float* __restrict__ h, int N) {
  const int lane = threadIdx.x & 63;
  const int wv = threadIdx.x >> 6;
  const int n = blockIdx.x * 4 + wv;
  if (n >= N) return;
  constexpr int CPL = (C == 128) ? 2 : 1;
  const int c0 = lane * CPL;
  if (c0 >= C) return;
  const int r0 = rowp[n], r1 = rowp[n + 1];
  float a0 = 0.f, a1 = 0.f;
  int p = r0;
  if (CPL == 2) {
    for (; p + 2 <= r1; p += 2) {
      const u32 w0 = *reinterpret_cast<const u32*>(&ew[(size_t)p * C + c0]);
      const u32 w1 = *reinterpret_cast<const u32*>(&ew[(size_t)(p + 1) * C + c0]);
      a0 += bf2f((u16)(w0 & 0xffffu)) + bf2f((u16)(w1 & 0xffffu));
      a1 += bf2f((u16)(w0 >> 16)) + bf2f((u16)(w1 >> 16));
    }
    for (; p < r1; ++p) {
      const u32 w0 = *reinterpret_cast<const u32*>(&ew[(size_t)p * C + c0]);
      a0 += bf2f((u16)(w0 & 0xffffu));
      a1 += bf2f((u16)(w0 >> 16));
    }
    float2 hv = *reinterpret_cast<const float2*>(&h[(size_t)n * C + c0]);
    hv.x /= (a0 + SM_EPS);
    hv.y /= (a1 + SM_EPS);
    *reinterpret_cast<float2*>(&h[(size_t)n * C + c0]) = hv;
  } else {
    for (; p + 2 <= r1; p += 2)
      a0 += bf2f(ew[(size_t)p * C + c0]) + bf2f(ew[(size_t)(p + 1) * C + c0]);
    for (; p < r1; ++p) a0 += bf2f(ew[(size_t)p * C + c0]);
    h[(size_t)n * C + c0] /= (a0 + SM_EPS);
  }
}

// ===== out[n] = sum_{in-edges} ew[pd.x] * g[pd.y] + b + alpha*pw(bf16), opt ELU =====
template <int C, int DO_ELU>
__global__ __launch_bounds__(256) void k_aggf(const int* __restrict__ rowp,
                                              const uint2* __restrict__ pdInfo,
                                              const u16* __restrict__ ew,
                                              const float* __restrict__ g,
                                              const u16* __restrict__ pw,
                                              const float* __restrict__ bias,
                                              const float* __restrict__ alpha_p,
                                              float* __restrict__ out, int N) {
  const int lane = threadIdx.x & 63;
  const int wv = threadIdx.x >> 6;
  const int n = blockIdx.x * 4 + wv;
  if (n >= N) return;
  constexpr int CPL = (C == 128) ? 2 : 1;
  const int c0 = lane * CPL;
  if (c0 >= C) return;
  const int r0 = rowp[n], r1 = rowp[n + 1];
  float a0 = 0.f, a1 = 0.f;
  int p = r0;
  if (CPL == 2) {
    for (; p + 4 <= r1; p += 4) {
      const uint2 i0 = pdInfo[p + 0], i1 = pdInfo[p + 1], i2 = pdInfo[p + 2], i3 = pdInfo[p + 3];
      const u32 w0 = *reinterpret_cast<const u32*>(&ew[(size_t)i0.x * C + c0]);
      const u32 w1 = *reinterpret_cast<const u32*>(&ew[(size_t)i1.x * C + c0]);
      const u32 w2 = *reinterpret_cast<const u32*>(&ew[(size_t)i2.x * C + c0]);
      const u32 w3 = *reinterpret_cast<const u32*>(&ew[(size_t)i3.x * C + c0]);
      const float2 g0 = *reinterpret_cast<const float2*>(&g[(size_t)i0.y * C + c0]);
      const float2 g1 = *reinterpret_cast<const float2*>(&g[(size_t)i1.y * C + c0]);
      const float2 g2 = *reinterpret_cast<const float2*>(&g[(size_t)i2.y * C + c0]);
      const float2 g3 = *reinterpret_cast<const float2*>(&g[(size_t)i3.y * C + c0]);
      a0 = fmaf(bf2f((u16)(w0 & 0xffffu)), g0.x, a0);
      a1 = fmaf(bf2f((u16)(w0 >> 16)), g0.y, a1);
      a0 = fmaf(bf2f((u16)(w1 & 0xffffu)), g1.x, a0);
      a1 = fmaf(bf2f((u16)(w1 >> 16)), g1.y, a1);
      a0 = fmaf(bf2f((u16)(w2 & 0xffffu)), g2.x, a0);
      a1 = fmaf(bf2f((u16)(w2 >> 16)), g2.y, a1);
      a0 = fmaf(bf2f((u16)(w3 & 0xffffu)), g3.x, a0);
      a1 = fmaf(bf2f((u16)(w3 >> 16)), g3.y, a1);
    }
    for (; p < r1; ++p) {
      const uint2 i0 = pdInfo[p];
      const u32 w0 = *reinterpret_cast<const u32*>(&ew[(size_t)i0.x * C + c0]);
      const float2 g0 = *reinterpret_cast<const float2*>(&g[(size_t)i0.y * C + c0]);
      a0 = fmaf(bf2f((u16)(w0 & 0xffffu)), g0.x, a0);
      a1 = fmaf(bf2f((u16)(w0 >> 16)), g0.y, a1);
    }
    const float al = alpha_p[0];
    const u32 pv2 = *reinterpret_cast<const u32*>(&pw[(size_t)n * C + c0]);
    float v0 = a0 + bias[c0] + al * bf2f((u16)(pv2 & 0xffffu));
    float v1 = a1 + bias[c0 + 1] + al * bf2f((u16)(pv2 >> 16));
    if (DO_ELU) {
      v0 = (v0 > 0.f) ? v0 : expm1f(v0);
      v1 = (v1 > 0.f) ? v1 : expm1f(v1);
    }
    *reinterpret_cast<float2*>(&out[(size_t)n * C + c0]) = make_float2(v0, v1);
  } else {
    for (; p + 4 <= r1; p += 4) {
      const uint2 i0 = pdInfo[p + 0], i1 = pdInfo[p + 1], i2 = pdInfo[p + 2], i3 = pdInfo[p + 3];
      const float w0 = bf2f(ew[(size_t)i0.x * C + c0]);
      const float w1 = bf2f(ew[(size_t)i1.x * C + c0]);
      const float w2 = bf2f(ew[(size_t)i2.x * C + c0]);
      const float w3 = bf2f(ew[(size_t)i3.x * C + c0]);
      const float g0 = g[(size_t)i0.y * C + c0];
      const float g1 = g[(size_t)i1.y * C + c0];
      const float g2 = g[(size_t)i2.y * C + c0];
      const float g3 = g[(size_t)i3.y * C + c0];
      a0 = fmaf(w0, g0, a0);
      a0 = fmaf(w1, g1, a0);
      a0 = fmaf(w2, g2, a0);
      a0 = fmaf(w3, g3, a0);
    }
    for (; p < r1; ++p) {
      const uint2 i0 = pdInfo[p];
      a0 = fmaf(bf2f(ew[(size_t)i0.x * C + c0]), g[(size_t)i0.y * C + c0], a0);
    }
    float v = a0 + bias[c0] + alpha_p[0] * bf2f(pw[(size_t)n * C + c0]);
    if (DO_ELU) v = (v > 0.f) ? v : expm1f(v);
    out[(size_t)n * C + c0] = v;
  }
}

extern "C" void kernel_launch(void* const* d_in, const int* in_sizes, int n_in,
                              void* d_out, int out_size, void* d_ws, size_t ws_size,
                              hipStream_t stream) {
  const float* x    = (const float*)d_in[0];
  const int*   ei   = (const int*)d_in[1];
  const float* kric = (const float*)d_in[2];
  const float* epoi = (const float*)d_in[3];
  const float* alpha= (const float*)d_in[4];
  const float* W1   = (const float*)d_in[5];
  const float* Wa1  = (const float*)d_in[6];
  const float* Wb1  = (const float*)d_in[7];
  const float* bb1  = (const float*)d_in[8];
  const float* Wc1  = (const float*)d_in[9];
  const float* Wd1  = (const float*)d_in[10];
  const float* bd1  = (const float*)d_in[11];
  const float* b1   = (const float*)d_in[12];
  const float* W2   = (const float*)d_in[13];
  const float* Wa2  = (const float*)d_in[14];
  const float* Wb2  = (const float*)d_in[15];
  const float* bb2  = (const float*)d_in[16];
  const float* Wc2  = (const float*)d_in[17];
  const float* Wd2  = (const float*)d_in[18];
  const float* bd2  = (const float*)d_in[19];
  const float* b2   = (const float*)d_in[20];

  const int N = in_sizes[0] / 512;
  const int E = in_sizes[1] / 2;
  const int* srcI = ei;
  const int* dstI = ei + E;
  const int NB = (N + 255) / 256;

  // ---- workspace layout ----
  char* p = (char*)d_ws;
  int* cnt      = (int*)p; p += (size_t)2 * N * 4;
  int* cur      = (int*)p; p += (size_t)2 * N * 4;
  int* bsum     = (int*)p; p += 512 * 4;
  int* boff     = (int*)p; p += 512 * 4;
  int* row_src  = (int*)p; p += (size_t)(N + 1) * 4;
  int* row_dst  = (int*)p; p += (size_t)(N + 1) * 4;
  p = (char*)(((uintptr_t)p + 255) & ~(uintptr_t)255);
  uint2* pdInfo = (uint2*)p; p += (size_t)E * 8;
  p = (char*)(((uintptr_t)p + 255) & ~(uintptr_t)255);
  u16* WaT1g = (u16*)p; p += 2048 * 2;
  u16* WbT1g = (u16*)p; p += 16384 * 2;
  u16* WcT1g = (u16*)p; p += 2048 * 2;
  u16* WdT1g = (u16*)p; p += 16384 * 2;
  u16* W1Tg  = (u16*)p; p += 65536 * 2;
  p = (char*)(((uintptr_t)p + 255) & ~(uintptr_t)255);
  u16* kricP = (u16*)p; p += (size_t)E * 16 * 2;   // bf16, src-CSR order
  u16* epoiP = (u16*)p; p += (size_t)N * 16 * 2;   // bf16
  p = (char*)(((uintptr_t)p + 255) & ~(uintptr_t)255);
  float* h1  = (float*)p; p += (size_t)N * 128 * 4;  // becomes g1 in place
  float* y1  = (float*)p; p += (size_t)N * 128 * 4;
  float* h2  = (float*)p; p += (size_t)N * 40 * 4;   // becomes g2 in place
  u16* pw1   = (u16*)p;  p += (size_t)N * 128 * 2;   // bf16
  u16* pw2   = (u16*)p;  p += (size_t)N * 40 * 2;    // bf16
  p = (char*)(((uintptr_t)p + 255) & ~(uintptr_t)255);
  u16* ew    = (u16*)p;  // E*128 bf16 (layer 1), reused E*40 (layer 2); src-CSR order

  // ---- CSR build (once, reused by both layers) + weight/input prep ----
  hipMemsetAsync(cnt, 0, (size_t)2 * N * 4, stream);
  k_prep<<<(102400 + 2 * N + 255) / 256, 256, 0, stream>>>(
      Wa1, Wb1, Wc1, Wd1, W1, epoi, WaT1g, WbT1g, WcT1g, WdT1g, W1Tg, epoiP, N);
  k_hist<<<(E + 255) / 256, 256, 0, stream>>>(srcI, dstI, cnt, N, E);
  k_scanA<<<2 * NB, 256, 0, stream>>>(cnt, bsum, N, NB);
  k_scanB<<<1, 256, 0, stream>>>(bsum, boff, NB);
  k_scanC<<<2 * NB, 256, 0, stream>>>(cnt, boff, row_src, row_dst, cur, N, NB);
  k_scatter<<<(E + 255) / 256, 256, 0, stream>>>(srcI, dstI, cur, kric, kricP, pdInfo, N, E);

  // ---------------- layer 1 ----------------
  k_gemm1m<<<(N + 63) / 64, 256, 0, stream>>>(x, W1Tg, h1, N);
  k_emlp<0><<<(E + 63) / 64, 256, 0, stream>>>(kricP, WaT1g, WbT1g, bb1, ew, E);
  k_emlp<1><<<(N + 63) / 64, 256, 0, stream>>>(epoiP, WcT1g, WdT1g, bd1, pw1, N);
  k_norm<128><<<(N + 3) / 4, 256, 0, stream>>>(row_src, ew, h1, N);
  k_aggf<128, 1><<<(N + 3) / 4, 256, 0, stream>>>(row_dst, pdInfo, ew, h1, pw1, b1, alpha, y1, N);

  // ---------------- layer 2 ----------------
  k_gemm2<<<(N + 5) / 6, 256, 0, stream>>>(y1, W2, h2, N);
  k_mlp40<0><<<(E + 255) / 256, 256, 0, stream>>>(kricP, Wa2, Wb2, bb2, ew, E);
  k_mlp40<1><<<(N + 255) / 256, 256, 0, stream>>>(epoiP, Wc2, Wd2, bd2, pw2, N);
  k_norm<40><<<(N + 3) / 4, 256, 0, stream>>>(row_src, ew, h2, N);
  k_aggf<40, 0><<<(N + 3) / 4, 256, 0, stream>>>(row_dst, pdInfo, ew, h2, pw2, b2, alpha, (float*)d_out, N);
}

// Round 13
// 648.641 us; speedup vs baseline: 10.9231x; 1.0958x over previous
//
#include <hip/hip_runtime.h>
#include <math.h>

#define SM_EPS 1e-16f

typedef unsigned short u16;
typedef unsigned int u32;
typedef short s16x8 __attribute__((ext_vector_type(8)));
typedef float f32x4 __attribute__((ext_vector_type(4)));

__device__ __forceinline__ u16 f2bfh(float x) {
  __bf16 b = (__bf16)x;
  return __builtin_bit_cast(unsigned short, b);
}
__device__ __forceinline__ float bf2f(u16 u) {
  return __uint_as_float(((u32)u) << 16);
}

// -------- weight + epoi prep (once per call) --------
__global__ __launch_bounds__(256) void k_prep(const float* __restrict__ Wa,
                                              const float* __restrict__ Wb,
                                              const float* __restrict__ Wc,
                                              const float* __restrict__ Wd,
                                              const float* __restrict__ W1,
                                              const float* __restrict__ Wa2,
                                              const float* __restrict__ Wb2,
                                              const float* __restrict__ Wc2,
                                              const float* __restrict__ Wd2,
                                              const float* __restrict__ bb2,
                                              const float* __restrict__ bd2,
                                              const float* __restrict__ epoi,
                                              u16* __restrict__ WaTg, u16* __restrict__ WbTg,
                                              u16* __restrict__ WcTg, u16* __restrict__ WdTg,
                                              u16* __restrict__ W1Tg,
                                              u16* __restrict__ WaT2g, u16* __restrict__ WbT2g,
                                              u16* __restrict__ WcT2g, u16* __restrict__ WdT2g,
                                              float* __restrict__ bb48, float* __restrict__ bd48,
                                              u16* __restrict__ epoiP,
                                              int N) {
  const int idx = blockIdx.x * 256 + threadIdx.x;
  if (idx < 2048) {
    const int n = idx >> 4, k = idx & 15;
    WaTg[idx] = f2bfh(Wa[k * 128 + n]);
  } else if (idx < 18432) {
    const int t = idx - 2048;
    const int n = t >> 7, k = t & 127;
    WbTg[t] = f2bfh(Wb[k * 128 + n]);
  } else if (idx < 20480) {
    const int t = idx - 18432;
    const int n = t >> 4, k = t & 15;
    WcTg[t] = f2bfh(Wc[k * 128 + n]);
  } else if (idx < 36864) {
    const int t = idx - 20480;
    const int n = t >> 7, k = t & 127;
    WdTg[t] = f2bfh(Wd[k * 128 + n]);
  } else if (idx < 102400) {
    const int t = idx - 36864;
    const int n = t >> 9, k = t & 511;
    W1Tg[t] = f2bfh(W1[k * 128 + n]);
  } else {
    const int t = idx - 102400;
    if (t < 768) {
      const int n = t >> 4, k = t & 15;
      WaT2g[t] = (n < 40) ? f2bfh(Wa2[k * 40 + n]) : (u16)0;
    } else if (t < 3840) {
      const int t2 = t - 768;
      const int n = t2 >> 6, k = t2 & 63;
      WbT2g[t2] = (n < 40 && k < 40) ? f2bfh(Wb2[k * 40 + n]) : (u16)0;
    } else if (t < 4608) {
      const int t2 = t - 3840;
      const int n = t2 >> 4, k = t2 & 15;
      WcT2g[t2] = (n < 40) ? f2bfh(Wc2[k * 40 + n]) : (u16)0;
    } else if (t < 7680) {
      const int t2 = t - 4608;
      const int n = t2 >> 6, k = t2 & 63;
      WdT2g[t2] = (n < 40 && k < 40) ? f2bfh(Wd2[k * 40 + n]) : (u16)0;
    } else if (t < 7728) {
      const int t2 = t - 7680;
      bb48[t2] = (t2 < 40) ? bb2[t2] : 0.f;
    } else if (t < 7776) {
      const int t2 = t - 7728;
      bd48[t2] = (t2 < 40) ? bd2[t2] : 0.f;
    } else {
      const int t3 = t - 7776;
      if (t3 < 2 * N) {
        const int r = t3 >> 1, half = t3 & 1;
        const float4 f0 = *reinterpret_cast<const float4*>(&epoi[(size_t)r * 16 + half * 8]);
        const float4 f1 = *reinterpret_cast<const float4*>(&epoi[(size_t)r * 16 + half * 8 + 4]);
        u32 pk[4];
        pk[0] = (u32)f2bfh(f0.x) | ((u32)f2bfh(f0.y) << 16);
        pk[1] = (u32)f2bfh(f0.z) | ((u32)f2bfh(f0.w) << 16);
        pk[2] = (u32)f2bfh(f1.x) | ((u32)f2bfh(f1.y) << 16);
        pk[3] = (u32)f2bfh(f1.z) | ((u32)f2bfh(f1.w) << 16);
        *reinterpret_cast<uint4*>(&epoiP[(size_t)r * 16 + half * 8]) = make_uint4(pk[0], pk[1], pk[2], pk[3]);
      }
    }
  }
}

// ---------------- h1 = x @ W1 via MFMA: [M,512]@[512,128], bf16 ----------------
__global__ __launch_bounds__(256) void k_gemm1m(const float* __restrict__ x,
                                                const u16* __restrict__ WT,  // [128][512]
                                                float* __restrict__ C, int M) {
  const int tid = threadIdx.x;
  const int lane = tid & 63;
  const int w = tid >> 6;
  const int wr = w >> 1, wc = w & 1;
  const int lg = lane >> 4;
  const int lm = lane & 15;
  const int r0 = blockIdx.x * 64;

  const f32x4 z4 = {0.f, 0.f, 0.f, 0.f};
  f32x4 acc[2][4];
#pragma unroll
  for (int i = 0; i < 2; ++i)
#pragma unroll
    for (int j = 0; j < 4; ++j) acc[i][j] = z4;

  auto load_chunk = [&](int ch, s16x8 af[2], s16x8 bf_[4]) {
#pragma unroll
    for (int i = 0; i < 2; ++i) {
      const int row = r0 + (wr * 2 + i) * 16 + lm;
      s16x8 a = (s16x8)0;
      if (row < M) {
        const float4 f0 = *reinterpret_cast<const float4*>(&x[(size_t)row * 512 + ch * 32 + lg * 8]);
        const float4 f1 = *reinterpret_cast<const float4*>(&x[(size_t)row * 512 + ch * 32 + lg * 8 + 4]);
        a[0] = (short)f2bfh(f0.x); a[1] = (short)f2bfh(f0.y);
        a[2] = (short)f2bfh(f0.z); a[3] = (short)f2bfh(f0.w);
        a[4] = (short)f2bfh(f1.x); a[5] = (short)f2bfh(f1.y);
        a[6] = (short)f2bfh(f1.z); a[7] = (short)f2bfh(f1.w);
      }
      af[i] = a;
    }
#pragma unroll
    for (int j = 0; j < 4; ++j) {
      const int n = (wc * 4 + j) * 16 + lm;
      bf_[j] = *reinterpret_cast<const s16x8*>(&WT[(size_t)n * 512 + ch * 32 + lg * 8]);
    }
  };

  s16x8 af[2], bf_[4];
  load_chunk(0, af, bf_);
  for (int ch = 0; ch < 16; ++ch) {
    s16x8 naf[2], nbf[4];
    if (ch < 15) load_chunk(ch + 1, naf, nbf);
#pragma unroll
    for (int i = 0; i < 2; ++i)
#pragma unroll
      for (int j = 0; j < 4; ++j)
        acc[i][j] = __builtin_amdgcn_mfma_f32_16x16x32_bf16(af[i], bf_[j], acc[i][j], 0, 0, 0);
    if (ch < 15) {
#pragma unroll
      for (int i = 0; i < 2; ++i) af[i] = naf[i];
#pragma unroll
      for (int j = 0; j < 4; ++j) bf_[j] = nbf[j];
    }
  }

#pragma unroll
  for (int i = 0; i < 2; ++i) {
#pragma unroll
    for (int rr = 0; rr < 4; ++rr) {
      const int row = r0 + (wr * 2 + i) * 16 + lg * 4 + rr;
      if (row < M) {
#pragma unroll
        for (int j = 0; j < 4; ++j)
          C[(size_t)row * 128 + (wc * 4 + j) * 16 + lm] = acc[i][j][rr];
      }
    }
  }
}

// ------- MFMA fused 16->128->128 MLP over bf16 rows -------
// 64 rows/block, 4 waves = 4 col-quadrants (32 cols each). 16KB LDS.
template <int MODE>
__global__ __launch_bounds__(256) void k_emlp(
    const u16* __restrict__ inp,              // [R][16] bf16
    const u16* __restrict__ WaTg, const u16* __restrict__ WbTg,
    const float* __restrict__ bbias,
    u16* __restrict__ outp, int R) {
  __shared__ __align__(16) unsigned char sU[16384];
  const int tid = threadIdx.x;
  const int lane = tid & 63;
  const int wc = tid >> 6;   // 0..3 col quadrant
  const int lg = lane >> 4;
  const int lm = lane & 15;
  const int r0 = blockIdx.x * 64;

  s16x8 afr[4];
#pragma unroll
  for (int i = 0; i < 4; ++i) {
    s16x8 a = (s16x8)0;
    if (lg < 2) {
      const int r = r0 + i * 16 + lm;
      if (r < R) a = *reinterpret_cast<const s16x8*>(&inp[(size_t)r * 16 + lg * 8]);
    }
    afr[i] = a;
  }

  const f32x4 z4 = {0.f, 0.f, 0.f, 0.f};
  s16x8 bfr1[2];
#pragma unroll
  for (int j = 0; j < 2; ++j) {
    s16x8 b = (s16x8)0;
    if (lg < 2) {
      const int n = wc * 32 + j * 16 + lm;
      b = *reinterpret_cast<const s16x8*>(&WaTg[n * 16 + lg * 8]);
    }
    bfr1[j] = b;
  }

  f32x4 acc1[4][2];
#pragma unroll
  for (int i = 0; i < 4; ++i)
#pragma unroll
    for (int j = 0; j < 2; ++j) acc1[i][j] = z4;
#pragma unroll
  for (int i = 0; i < 4; ++i)
#pragma unroll
    for (int j = 0; j < 2; ++j)
      acc1[i][j] = __builtin_amdgcn_mfma_f32_16x16x32_bf16(afr[i], bfr1[j], acc1[i][j], 0, 0, 0);

#pragma unroll
  for (int i = 0; i < 4; ++i) {
#pragma unroll
    for (int j = 0; j < 2; ++j) {
#pragma unroll
      for (int rr = 0; rr < 4; ++rr) {
        float v = acc1[i][j][rr];
        v = (v >= 0.f) ? v : 0.2f * v;
        const int grow = i * 16 + lg * 4 + rr;
        const int gcol = wc * 32 + j * 16 + lm;
        const int byte = grow * 256 + ((((gcol >> 3) ^ (grow & 15))) << 4) + (gcol & 7) * 2;
        *reinterpret_cast<u16*>(&sU[byte]) = f2bfh(v);
      }
    }
  }
  __syncthreads();

  f32x4 acc[4][2];
#pragma unroll
  for (int i = 0; i < 4; ++i)
#pragma unroll
    for (int j = 0; j < 2; ++j) acc[i][j] = z4;
#pragma unroll
  for (int kb = 0; kb < 4; ++kb) {
    s16x8 af[4], bf_[2];
    const int ch = kb * 4 + lg;
#pragma unroll
    for (int j = 0; j < 2; ++j) {
      const int n = wc * 32 + j * 16 + lm;
      bf_[j] = *reinterpret_cast<const s16x8*>(&WbTg[n * 128 + ch * 8]);
    }
#pragma unroll
    for (int i = 0; i < 4; ++i) {
      const int row = i * 16 + lm;
      af[i] = *reinterpret_cast<const s16x8*>(&sU[row * 256 + ((ch ^ (row & 15)) << 4)]);
    }
#pragma unroll
    for (int i = 0; i < 4; ++i)
#pragma unroll
      for (int j = 0; j < 2; ++j)
        acc[i][j] = __builtin_amdgcn_mfma_f32_16x16x32_bf16(af[i], bf_[j], acc[i][j], 0, 0, 0);
  }
  __syncthreads();

  float bv[2];
#pragma unroll
  for (int j = 0; j < 2; ++j) bv[j] = bbias[wc * 32 + j * 16 + lm];
#pragma unroll
  for (int i = 0; i < 4; ++i) {
#pragma unroll
    for (int j = 0; j < 2; ++j) {
#pragma unroll
      for (int rr = 0; rr < 4; ++rr) {
        float v = acc[i][j][rr] + bv[j];
        if (MODE == 0) v = __expf(v);
        else v = (v >= 0.f) ? v : 0.01f * v;
        const int grow = i * 16 + lg * 4 + rr;
        const int gcol = wc * 32 + j * 16 + lm;
        const int byte = grow * 256 + ((((gcol >> 3) ^ (grow & 15))) << 4) + (gcol & 7) * 2;
        *reinterpret_cast<u16*>(&sU[byte]) = f2bfh(v);
      }
    }
  }
  __syncthreads();

  const int rmax = R - r0;
#pragma unroll
  for (int q = 0; q < 4; ++q) {
    const int u = tid + q * 256;
    const int row = u >> 4, c8 = u & 15;
    if (row < rmax) {
      const uint4 v = *reinterpret_cast<const uint4*>(&sU[row * 256 + ((c8 ^ (row & 15)) << 4)]);
      *reinterpret_cast<uint4*>(&outp[(size_t)(r0 + row) * 128 + c8 * 8]) = v;
    }
  }
}

// ------- MFMA fused 16->40->40 MLP (48-padded) over bf16 rows -------
// 128 rows/block, 4 waves x 32 rows x 48 cols. LDS U [128][64] bf16 = 16KB.
// U cols 48..63 are never written by stage 1 -> must be zeroed (NaN x 0 = NaN!).
template <int MODE>
__global__ __launch_bounds__(256) void k_emlp48(
    const u16* __restrict__ inp,              // [R][16] bf16
    const u16* __restrict__ WaT,              // [48][16] bf16 (zero-padded n>=40)
    const u16* __restrict__ WbT,              // [48][64] bf16 (zero-padded)
    const float* __restrict__ bias48,         // [48]
    u16* __restrict__ outp, int R) {          // [R][40] bf16
  __shared__ __align__(16) unsigned char sU[16384];
  const int tid = threadIdx.x;
  const int lane = tid & 63;
  const int wv = tid >> 6;   // 0..3 row group (32 rows each)
  const int lg = lane >> 4;
  const int lm = lane & 15;
  const int r0 = blockIdx.x * 128;

  // zero U pad columns 48..63 (disjoint from data cols, no race with stage-1 writes)
#pragma unroll
  for (int q = 0; q < 4; ++q) {
    const int u = tid + q * 256;      // 0..1023
    const int row = u >> 3;           // 0..127
    const int col = 48 + (u & 7) * 2; // 48,50,..,62
    const int byte = row * 128 + ((((col >> 3) ^ (row & 7))) << 4) + (col & 7) * 2;
    *reinterpret_cast<u32*>(&sU[byte]) = 0;
  }

  // stage-1 A frags (K=16 zero-padded to 32)
  s16x8 afr[2];
#pragma unroll
  for (int i = 0; i < 2; ++i) {
    s16x8 a = (s16x8)0;
    if (lg < 2) {
      const int r = r0 + wv * 32 + i * 16 + lm;
      if (r < R) a = *reinterpret_cast<const s16x8*>(&inp[(size_t)r * 16 + lg * 8]);
    }
    afr[i] = a;
  }
  // stage-1 B frags (WaT [48][16])
  const f32x4 z4 = {0.f, 0.f, 0.f, 0.f};
  s16x8 bfr1[3];
#pragma unroll
  for (int j = 0; j < 3; ++j) {
    s16x8 b = (s16x8)0;
    if (lg < 2) {
      const int n = j * 16 + lm;
      b = *reinterpret_cast<const s16x8*>(&WaT[n * 16 + lg * 8]);
    }
    bfr1[j] = b;
  }
  // stage 1: U = lrelu(K @ Wa)
  f32x4 acc1[2][3];
#pragma unroll
  for (int i = 0; i < 2; ++i)
#pragma unroll
    for (int j = 0; j < 3; ++j) acc1[i][j] = z4;
#pragma unroll
  for (int i = 0; i < 2; ++i)
#pragma unroll
    for (int j = 0; j < 3; ++j)
      acc1[i][j] = __builtin_amdgcn_mfma_f32_16x16x32_bf16(afr[i], bfr1[j], acc1[i][j], 0, 0, 0);

  // write U (cols 0..47; cols 40..47 exact zeros from Wa padding)
#pragma unroll
  for (int i = 0; i < 2; ++i) {
#pragma unroll
    for (int j = 0; j < 3; ++j) {
#pragma unroll
      for (int rr = 0; rr < 4; ++rr) {
        float v = acc1[i][j][rr];
        v = (v >= 0.f) ? v : 0.2f * v;
        const int grow = wv * 32 + i * 16 + lg * 4 + rr;
        const int gcol = j * 16 + lm;
        const int byte = grow * 128 + ((((gcol >> 3) ^ (grow & 7))) << 4) + (gcol & 7) * 2;
        *reinterpret_cast<u16*>(&sU[byte]) = f2bfh(v);
      }
    }
  }
  __syncthreads();

  // stage 2: logit = U @ Wb, K=64 (U cols 48..63 zeroed above)
  f32x4 acc[2][3];
#pragma unroll
  for (int i = 0; i < 2; ++i)
#pragma unroll
    for (int j = 0; j < 3; ++j) acc[i][j] = z4;
#pragma unroll
  for (int kb = 0; kb < 2; ++kb) {
    s16x8 af[2], bf_[3];
    const int ch = kb * 4 + lg;
#pragma unroll
    for (int j = 0; j < 3; ++j) {
      const int n = j * 16 + lm;
      bf_[j] = *reinterpret_cast<const s16x8*>(&WbT[n * 64 + ch * 8]);
    }
#pragma unroll
    for (int i = 0; i < 2; ++i) {
      const int row = wv * 32 + i * 16 + lm;
      af[i] = *reinterpret_cast<const s16x8*>(&sU[row * 128 + ((ch ^ (row & 7)) << 4)]);
    }
#pragma unroll
    for (int i = 0; i < 2; ++i)
#pragma unroll
      for (int j = 0; j < 3; ++j)
        acc[i][j] = __builtin_amdgcn_mfma_f32_16x16x32_bf16(af[i], bf_[j], acc[i][j], 0, 0, 0);
  }
  __syncthreads();  // done reading sU

  // epilogue -> sU (cols 0..47)
  float bv[3];
#pragma unroll
  for (int j = 0; j < 3; ++j) bv[j] = bias48[j * 16 + lm];
#pragma unroll
  for (int i = 0; i < 2; ++i) {
#pragma unroll
    for (int j = 0; j < 3; ++j) {
#pragma unroll
      for (int rr = 0; rr < 4; ++rr) {
        float v = acc[i][j][rr] + bv[j];
        if (MODE == 0) v = __expf(v);
        else v = (v >= 0.f) ? v : 0.01f * v;
        const int grow = wv * 32 + i * 16 + lg * 4 + rr;
        const int gcol = j * 16 + lm;
        const int byte = grow * 128 + ((((gcol >> 3) ^ (grow & 7))) << 4) + (gcol & 7) * 2;
        *reinterpret_cast<u16*>(&sU[byte]) = f2bfh(v);
      }
    }
  }
  __syncthreads();

  // copy-out: 128 rows x 40 cols; 2 threads/row, 10 u32 each
  const int rmax = R - r0;
  const int row = tid >> 1, half = tid & 1;
  if (row < rmax) {
    const size_t obase = (size_t)(r0 + row) * 40;
#pragma unroll
    for (int q = 0; q < 10; ++q) {
      const int col = (half * 10 + q) * 2;
      const int byte = row * 128 + ((((col >> 3) ^ (row & 7))) << 4) + (col & 7) * 2;
      *reinterpret_cast<u32*>(&outp[obase + col]) = *reinterpret_cast<const u32*>(&sU[byte]);
    }
  }
}

// ------------- h2 = y1 @ W2  [M,128]@[128,40] ----------
__global__ __launch_bounds__(256) void k_gemm2(const float* __restrict__ A,
                                               const float* __restrict__ B,
                                               float* __restrict__ C, int M) {
  __shared__ float Bs[128 * 40];
  const int tid = threadIdx.x;
  for (int i = tid; i < 5120; i += 256) Bs[i] = B[i];
  __syncthreads();
  const int r = blockIdx.x * 6 + tid / 40;
  const int c = tid % 40;
  if (tid >= 240 || r >= M) return;
  const float* arow = &A[(size_t)r * 128];
  float acc = 0.f;
#pragma unroll
  for (int k4 = 0; k4 < 32; ++k4) {
    const float4 av = *reinterpret_cast<const float4*>(&arow[k4 * 4]);
    acc = fmaf(av.x, Bs[(k4 * 4 + 0) * 40 + c], acc);
    acc = fmaf(av.y, Bs[(k4 * 4 + 1) * 40 + c], acc);
    acc = fmaf(av.z, Bs[(k4 * 4 + 2) * 40 + c], acc);
    acc = fmaf(av.w, Bs[(k4 * 4 + 3) * 40 + c], acc);
  }
  C[(size_t)r * 40 + c] = acc;
}

// ================= CSR build =================
__global__ __launch_bounds__(256) void k_hist(const int* __restrict__ src,
                                              const int* __restrict__ dst,
                                              int* __restrict__ cnt, int N, int E) {
  const int e = blockIdx.x * 256 + threadIdx.x;
  if (e >= E) return;
  atomicAdd(&cnt[src[e]], 1);
  atomicAdd(&cnt[N + dst[e]], 1);
}

__global__ __launch_bounds__(256) void k_scanA(const int* __restrict__ cnt,
                                               int* __restrict__ bsum, int N, int NB) {
  const int arr = blockIdx.x / NB, bb = blockIdx.x % NB;
  const int g = bb * 256 + threadIdx.x;
  int v = (g < N) ? cnt[arr * N + g] : 0;
  __shared__ int sd[256];
  sd[threadIdx.x] = v;
  __syncthreads();
  for (int off = 128; off > 0; off >>= 1) {
    if (threadIdx.x < off) sd[threadIdx.x] += sd[threadIdx.x + off];
    __syncthreads();
  }
  if (threadIdx.x == 0) bsum[arr * 256 + bb] = sd[0];
}

__global__ __launch_bounds__(256) void k_scanB(const int* __restrict__ bsum,
                                               int* __restrict__ boff, int NB) {
  __shared__ int sd[256];
  for (int arr = 0; arr < 2; ++arr) {
    const int v = (threadIdx.x < NB) ? bsum[arr * 256 + threadIdx.x] : 0;
    sd[threadIdx.x] = v;
    __syncthreads();
    for (int off = 1; off < 256; off <<= 1) {
      const int t = (threadIdx.x >= off) ? sd[threadIdx.x - off] : 0;
      __syncthreads();
      sd[threadIdx.x] += t;
      __syncthreads();
    }
    if (threadIdx.x < NB) boff[arr * 256 + threadIdx.x] = sd[threadIdx.x] - v;
    __syncthreads();
  }
}

__global__ __launch_bounds__(256) void k_scanC(const int* __restrict__ cnt,
                                               const int* __restrict__ boff,
                                               int* __restrict__ row_src,
                                               int* __restrict__ row_dst,
                                               int* __restrict__ cur, int N, int NB) {
  const int arr = blockIdx.x / NB, bb = blockIdx.x % NB;
  const int g = bb * 256 + threadIdx.x;
  const int v = (g < N) ? cnt[arr * N + g] : 0;
  __shared__ int sd[256];
  sd[threadIdx.x] = v;
  __syncthreads();
  for (int off = 1; off < 256; off <<= 1) {
    const int t = (threadIdx.x >= off) ? sd[threadIdx.x - off] : 0;
    __syncthreads();
    sd[threadIdx.x] += t;
    __syncthreads();
  }
  const int incl = sd[threadIdx.x];
  const int base = boff[arr * 256 + bb];
  int* row = arr ? row_dst : row_src;
  if (g < N) {
    row[g] = base + incl - v;
    cur[arr * N + g] = base + incl - v;
    if (g == N - 1) row[N] = base + incl;
  }
}

// per-edge: ps = src-order position, pd = dst-order position.
__global__ __launch_bounds__(256) void k_scatter(const int* __restrict__ src,
                                                 const int* __restrict__ dst,
                                                 int* __restrict__ cur,
                                                 const float* __restrict__ kric,
                                                 u16* __restrict__ kricP,
                                                 uint2* __restrict__ pdInfo, int N, int E) {
  const int e = blockIdx.x * 256 + threadIdx.x;
  if (e >= E) return;
  const int s = src[e], d = dst[e];
  const float4 f0 = *reinterpret_cast<const float4*>(&kric[(size_t)e * 16]);
  const float4 f1 = *reinterpret_cast<const float4*>(&kric[(size_t)e * 16 + 4]);
  const float4 f2 = *reinterpret_cast<const float4*>(&kric[(size_t)e * 16 + 8]);
  const float4 f3 = *reinterpret_cast<const float4*>(&kric[(size_t)e * 16 + 12]);
  const int ps = atomicAdd(&cur[s], 1);
  const int pd = atomicAdd(&cur[N + d], 1);
  pdInfo[pd] = make_uint2((u32)ps, (u32)s);
  u32 pk[8];
  pk[0] = (u32)f2bfh(f0.x) | ((u32)f2bfh(f0.y) << 16);
  pk[1] = (u32)f2bfh(f0.z) | ((u32)f2bfh(f0.w) << 16);
  pk[2] = (u32)f2bfh(f1.x) | ((u32)f2bfh(f1.y) << 16);
  pk[3] = (u32)f2bfh(f1.z) | ((u32)f2bfh(f1.w) << 16);
  pk[4] = (u32)f2bfh(f2.x) | ((u32)f2bfh(f2.y) << 16);
  pk[5] = (u32)f2bfh(f2.z) | ((u32)f2bfh(f2.w) << 16);
  pk[6] = (u32)f2bfh(f3.x) | ((u32)f2bfh(f3.y) << 16);
  pk[7] = (u32)f2bfh(f3.z) | ((u32)f2bfh(f3.w) << 16);
  u16* outr = &kricP[(size_t)ps * 16];
  *reinterpret_cast<uint4*>(outr) = make_uint4(pk[0], pk[1], pk[2], pk[3]);
  *reinterpret_cast<uint4*>(outr + 8) = make_uint4(pk[4], pk[5], pk[6], pk[7]);
}

// ===== streaming: s = sum of ew rows [r0,r1), g = h/(s+eps) =====
template <int C>
__global__ __launch_bounds__(256) void k_norm(const int* __restrict__ rowp,
                                              const u16* __restrict__ ew,
                                              float* __restrict__ h, int N) {
  const int lane = threadIdx.x & 63;
  const int wv = threadIdx.x >> 6;
  const int n = blockIdx.x * 4 + wv;
  if (n >= N) return;
  constexpr int CPL = (C == 128) ? 2 : 1;
  const int c0 = lane * CPL;
  if (c0 >= C) return;
  const int r0 = rowp[n], r1 = rowp[n + 1];
  float a0 = 0.f, a1 = 0.f;
  int p = r0;
  if (CPL == 2) {
    for (; p + 2 <= r1; p += 2) {
      const u32 w0 = *reinterpret_cast<const u32*>(&ew[(size_t)p * C + c0]);
      const u32 w1 = *reinterpret_cast<const u32*>(&ew[(size_t)(p + 1) * C + c0]);
      a0 += bf2f((u16)(w0 & 0xffffu)) + bf2f((u16)(w1 & 0xffffu));
      a1 += bf2f((u16)(w0 >> 16)) + bf2f((u16)(w1 >> 16));
    }
    for (; p < r1; ++p) {
      const u32 w0 = *reinterpret_cast<const u32*>(&ew[(size_t)p * C + c0]);
      a0 += bf2f((u16)(w0 & 0xffffu));
      a1 += bf2f((u16)(w0 >> 16));
    }
    float2 hv = *reinterpret_cast<const float2*>(&h[(size_t)n * C + c0]);
    hv.x /= (a0 + SM_EPS);
    hv.y /= (a1 + SM_EPS);
    *reinterpret_cast<float2*>(&h[(size_t)n * C + c0]) = hv;
  } else {
    for (; p + 2 <= r1; p += 2)
      a0 += bf2f(ew[(size_t)p * C + c0]) + bf2f(ew[(size_t)(p + 1) * C + c0]);
    for (; p < r1; ++p) a0 += bf2f(ew[(size_t)p * C + c0]);
    h[(size_t)n * C + c0] /= (a0 + SM_EPS);
  }
}

// ===== out[n] = sum_{in-edges} ew[pd.x] * g[pd.y] + b + alpha*pw(bf16), opt ELU =====
template <int C, int DO_ELU>
__global__ __launch_bounds__(256) void k_aggf(const int* __restrict__ rowp,
                                              const uint2* __restrict__ pdInfo,
                                              const u16* __restrict__ ew,
                                              const float* __restrict__ g,
                                              const u16* __restrict__ pw,
                                              const float* __restrict__ bias,
                                              const float* __restrict__ alpha_p,
                                              float* __restrict__ out, int N) {
  const int lane = threadIdx.x & 63;
  const int wv = threadIdx.x >> 6;
  const int n = blockIdx.x * 4 + wv;
  if (n >= N) return;
  constexpr int CPL = (C == 128) ? 2 : 1;
  const int c0 = lane * CPL;
  if (c0 >= C) return;
  const int r0 = rowp[n], r1 = rowp[n + 1];
  float a0 = 0.f, a1 = 0.f;
  int p = r0;
  if (CPL == 2) {
    for (; p + 8 <= r1; p += 8) {
      uint2 ii[8];
      u32 ww[8];
      float2 gg[8];
#pragma unroll
      for (int t = 0; t < 8; ++t) ii[t] = pdInfo[p + t];
#pragma unroll
      for (int t = 0; t < 8; ++t) ww[t] = *reinterpret_cast<const u32*>(&ew[(size_t)ii[t].x * C + c0]);
#pragma unroll
      for (int t = 0; t < 8; ++t) gg[t] = *reinterpret_cast<const float2*>(&g[(size_t)ii[t].y * C + c0]);
#pragma unroll
      for (int t = 0; t < 8; ++t) {
        a0 = fmaf(bf2f((u16)(ww[t] & 0xffffu)), gg[t].x, a0);
        a1 = fmaf(bf2f((u16)(ww[t] >> 16)), gg[t].y, a1);
      }
    }
    for (; p + 4 <= r1; p += 4) {
      const uint2 i0 = pdInfo[p + 0], i1 = pdInfo[p + 1], i2 = pdInfo[p + 2], i3 = pdInfo[p + 3];
      const u32 w0 = *reinterpret_cast<const u32*>(&ew[(size_t)i0.x * C + c0]);
      const u32 w1 = *reinterpret_cast<const u32*>(&ew[(size_t)i1.x * C + c0]);
      const u32 w2 = *reinterpret_cast<const u32*>(&ew[(size_t)i2.x * C + c0]);
      const u32 w3 = *reinterpret_cast<const u32*>(&ew[(size_t)i3.x * C + c0]);
      const float2 g0 = *reinterpret_cast<const float2*>(&g[(size_t)i0.y * C + c0]);
      const float2 g1 = *reinterpret_cast<const float2*>(&g[(size_t)i1.y * C + c0]);
      const float2 g2 = *reinterpret_cast<const float2*>(&g[(size_t)i2.y * C + c0]);
      const float2 g3 = *reinterpret_cast<const float2*>(&g[(size_t)i3.y * C + c0]);
      a0 = fmaf(bf2f((u16)(w0 & 0xffffu)), g0.x, a0);
      a1 = fmaf(bf2f((u16)(w0 >> 16)), g0.y, a1);
      a0 = fmaf(bf2f((u16)(w1 & 0xffffu)), g1.x, a0);
      a1 = fmaf(bf2f((u16)(w1 >> 16)), g1.y, a1);
      a0 = fmaf(bf2f((u16)(w2 & 0xffffu)), g2.x, a0);
      a1 = fmaf(bf2f((u16)(w2 >> 16)), g2.y, a1);
      a0 = fmaf(bf2f((u16)(w3 & 0xffffu)), g3.x, a0);
      a1 = fmaf(bf2f((u16)(w3 >> 16)), g3.y, a1);
    }
    for (; p < r1; ++p) {
      const uint2 i0 = pdInfo[p];
      const u32 w0 = *reinterpret_cast<const u32*>(&ew[(size_t)i0.x * C + c0]);
      const float2 g0 = *reinterpret_cast<const float2*>(&g[(size_t)i0.y * C + c0]);
      a0 = fmaf(bf2f((u16)(w0 & 0xffffu)), g0.x, a0);
      a1 = fmaf(bf2f((u16)(w0 >> 16)), g0.y, a1);
    }
    const float al = alpha_p[0];
    const u32 pv2 = *reinterpret_cast<const u32*>(&pw[(size_t)n * C + c0]);
    float v0 = a0 + bias[c0] + al * bf2f((u16)(pv2 & 0xffffu));
    float v1 = a1 + bias[c0 + 1] + al * bf2f((u16)(pv2 >> 16));
    if (DO_ELU) {
      v0 = (v0 > 0.f) ? v0 : expm1f(v0);
      v1 = (v1 > 0.f) ? v1 : expm1f(v1);
    }
    *reinterpret_cast<float2*>(&out[(size_t)n * C + c0]) = make_float2(v0, v1);
  } else {
    for (; p + 4 <= r1; p += 4) {
      const uint2 i0 = pdInfo[p + 0], i1 = pdInfo[p + 1], i2 = pdInfo[p + 2], i3 = pdInfo[p + 3];
      const float w0 = bf2f(ew[(size_t)i0.x * C + c0]);
      const float w1 = bf2f(ew[(size_t)i1.x * C + c0]);
      const float w2 = bf2f(ew[(size_t)i2.x * C + c0]);
      const float w3 = bf2f(ew[(size_t)i3.x * C + c0]);
      const float g0 = g[(size_t)i0.y * C + c0];
      const float g1 = g[(size_t)i1.y * C + c0];
      const float g2 = g[(size_t)i2.y * C + c0];
      const float g3 = g[(size_t)i3.y * C + c0];
      a0 = fmaf(w0, g0, a0);
      a0 = fmaf(w1, g1, a0);
      a0 = fmaf(w2, g2, a0);
      a0 = fmaf(w3, g3, a0);
    }
    for (; p < r1; ++p) {
      const uint2 i0 = pdInfo[p];
      a0 = fmaf(bf2f(ew[(size_t)i0.x * C + c0]), g[(size_t)i0.y * C + c0], a0);
    }
    float v = a0 + bias[c0] + alpha_p[0] * bf2f(pw[(size_t)n * C + c0]);
    if (DO_ELU) v = (v > 0.f) ? v : expm1f(v);
    out[(size_t)n * C + c0] = v;
  }
}

extern "C" void kernel_launch(void* const* d_in, const int* in_sizes, int n_in,
                              void* d_out, int out_size, void* d_ws, size_t ws_size,
                              hipStream_t stream) {
  const float* x    = (const float*)d_in[0];
  const int*   ei   = (const int*)d_in[1];
  const float* kric = (const float*)d_in[2];
  const float* epoi = (const float*)d_in[3];
  const float* alpha= (const float*)d_in[4];
  const float* W1   = (const float*)d_in[5];
  const float* Wa1  = (const float*)d_in[6];
  const float* Wb1  = (const float*)d_in[7];
  const float* bb1  = (const float*)d_in[8];
  const float* Wc1  = (const float*)d_in[9];
  const float* Wd1  = (const float*)d_in[10];
  const float* bd1  = (const float*)d_in[11];
  const float* b1   = (const float*)d_in[12];
  const float* W2   = (const float*)d_in[13];
  const float* Wa2  = (const float*)d_in[14];
  const float* Wb2  = (const float*)d_in[15];
  const float* bb2  = (const float*)d_in[16];
  const float* Wc2  = (const float*)d_in[17];
  const float* Wd2  = (const float*)d_in[18];
  const float* bd2  = (const float*)d_in[19];
  const float* b2   = (const float*)d_in[20];

  const int N = in_sizes[0] / 512;
  const int E = in_sizes[1] / 2;
  const int* srcI = ei;
  const int* dstI = ei + E;
  const int NB = (N + 255) / 256;

  // ---- workspace layout ----
  char* p = (char*)d_ws;
  int* cnt      = (int*)p; p += (size_t)2 * N * 4;
  int* cur      = (int*)p; p += (size_t)2 * N * 4;
  int* bsum     = (int*)p; p += 512 * 4;
  int* boff     = (int*)p; p += 512 * 4;
  int* row_src  = (int*)p; p += (size_t)(N + 1) * 4;
  int* row_dst  = (int*)p; p += (size_t)(N + 1) * 4;
  p = (char*)(((uintptr_t)p + 255) & ~(uintptr_t)255);
  uint2* pdInfo = (uint2*)p; p += (size_t)E * 8;
  p = (char*)(((uintptr_t)p + 255) & ~(uintptr_t)255);
  u16* WaT1g = (u16*)p; p += 2048 * 2;
  u16* WbT1g = (u16*)p; p += 16384 * 2;
  u16* WcT1g = (u16*)p; p += 2048 * 2;
  u16* WdT1g = (u16*)p; p += 16384 * 2;
  u16* W1Tg  = (u16*)p; p += 65536 * 2;
  u16* WaT2g = (u16*)p; p += 768 * 2;
  u16* WbT2g = (u16*)p; p += 3072 * 2;
  u16* WcT2g = (u16*)p; p += 768 * 2;
  u16* WdT2g = (u16*)p; p += 3072 * 2;
  p = (char*)(((uintptr_t)p + 255) & ~(uintptr_t)255);
  float* bb48 = (float*)p; p += 48 * 4;
  float* bd48 = (float*)p; p += 48 * 4;
  p = (char*)(((uintptr_t)p + 255) & ~(uintptr_t)255);
  u16* kricP = (u16*)p; p += (size_t)E * 16 * 2;   // bf16, src-CSR order
  u16* epoiP = (u16*)p; p += (size_t)N * 16 * 2;   // bf16
  p = (char*)(((uintptr_t)p + 255) & ~(uintptr_t)255);
  float* h1  = (float*)p; p += (size_t)N * 128 * 4;  // becomes g1 in place
  float* y1  = (float*)p; p += (size_t)N * 128 * 4;
  float* h2  = (float*)p; p += (size_t)N * 40 * 4;   // becomes g2 in place
  u16* pw1   = (u16*)p;  p += (size_t)N * 128 * 2;   // bf16
  u16* pw2   = (u16*)p;  p += (size_t)N * 40 * 2;    // bf16
  p = (char*)(((uintptr_t)p + 255) & ~(uintptr_t)255);
  u16* ew    = (u16*)p;  // E*128 bf16 (layer 1), reused E*40 (layer 2); src-CSR order

  // ---- CSR build + weight/input prep ----
  hipMemsetAsync(cnt, 0, (size_t)2 * N * 4, stream);
  k_prep<<<(110176 + 2 * N + 255) / 256, 256, 0, stream>>>(
      Wa1, Wb1, Wc1, Wd1, W1, Wa2, Wb2, Wc2, Wd2, bb2, bd2, epoi,
      WaT1g, WbT1g, WcT1g, WdT1g, W1Tg, WaT2g, WbT2g, WcT2g, WdT2g, bb48, bd48, epoiP, N);
  k_hist<<<(E + 255) / 256, 256, 0, stream>>>(srcI, dstI, cnt, N, E);
  k_scanA<<<2 * NB, 256, 0, stream>>>(cnt, bsum, N, NB);
  k_scanB<<<1, 256, 0, stream>>>(bsum, boff, NB);
  k_scanC<<<2 * NB, 256, 0, stream>>>(cnt, boff, row_src, row_dst, cur, N, NB);
  k_scatter<<<(E + 255) / 256, 256, 0, stream>>>(srcI, dstI, cur, kric, kricP, pdInfo, N, E);

  // ---------------- layer 1 ----------------
  k_gemm1m<<<(N + 63) / 64, 256, 0, stream>>>(x, W1Tg, h1, N);
  k_emlp<0><<<(E + 63) / 64, 256, 0, stream>>>(kricP, WaT1g, WbT1g, bb1, ew, E);
  k_emlp<1><<<(N + 63) / 64, 256, 0, stream>>>(epoiP, WcT1g, WdT1g, bd1, pw1, N);
  k_norm<128><<<(N + 3) / 4, 256, 0, stream>>>(row_src, ew, h1, N);
  k_aggf<128, 1><<<(N + 3) / 4, 256, 0, stream>>>(row_dst, pdInfo, ew, h1, pw1, b1, alpha, y1, N);

  // ---------------- layer 2 ----------------
  k_gemm2<<<(N + 5) / 6, 256, 0, stream>>>(y1, W2, h2, N);
  k_emlp48<0><<<(E + 127) / 128, 256, 0, stream>>>(kricP, WaT2g, WbT2g, bb48, ew, E);
  k_emlp48<1><<<(N + 127) / 128, 256, 0, stream>>>(epoiP, WcT2g, WdT2g, bd48, pw2, N);
  k_norm<40><<<(N + 3) / 4, 256, 0, stream>>>(row_src, ew, h2, N);
  k_aggf<40, 0><<<(N + 3) / 4, 256, 0, stream>>>(row_dst, pdInfo, ew, h2, pw2, b2, alpha, (float*)d_out, N);
}

// Round 14
// 613.941 us; speedup vs baseline: 11.5404x; 1.0565x over previous
//
#include <hip/hip_runtime.h>
#include <math.h>

#define SM_EPS 1e-16f

typedef unsigned short u16;
typedef unsigned int u32;
typedef short s16x8 __attribute__((ext_vector_type(8)));
typedef float f32x4 __attribute__((ext_vector_type(4)));

__device__ __forceinline__ u16 f2bfh(float x) {
  __bf16 b = (__bf16)x;
  return __builtin_bit_cast(unsigned short, b);
}
__device__ __forceinline__ float bf2f(u16 u) {
  return __uint_as_float(((u32)u) << 16);
}

// -------- weight + epoi prep (once per call) --------
__global__ __launch_bounds__(256) void k_prep(const float* __restrict__ Wa,
                                              const float* __restrict__ Wb,
                                              const float* __restrict__ Wc,
                                              const float* __restrict__ Wd,
                                              const float* __restrict__ W1,
                                              const float* __restrict__ Wa2,
                                              const float* __restrict__ Wb2,
                                              const float* __restrict__ Wc2,
                                              const float* __restrict__ Wd2,
                                              const float* __restrict__ bb2,
                                              const float* __restrict__ bd2,
                                              const float* __restrict__ epoi,
                                              u16* __restrict__ WaTg, u16* __restrict__ WbTg,
                                              u16* __restrict__ WcTg, u16* __restrict__ WdTg,
                                              u16* __restrict__ W1Tg,
                                              u16* __restrict__ WaT2g, u16* __restrict__ WbT2g,
                                              u16* __restrict__ WcT2g, u16* __restrict__ WdT2g,
                                              float* __restrict__ bb48, float* __restrict__ bd48,
                                              u16* __restrict__ epoiP,
                                              int N) {
  const int idx = blockIdx.x * 256 + threadIdx.x;
  if (idx < 2048) {
    const int n = idx >> 4, k = idx & 15;
    WaTg[idx] = f2bfh(Wa[k * 128 + n]);
  } else if (idx < 18432) {
    const int t = idx - 2048;
    const int n = t >> 7, k = t & 127;
    WbTg[t] = f2bfh(Wb[k * 128 + n]);
  } else if (idx < 20480) {
    const int t = idx - 18432;
    const int n = t >> 4, k = t & 15;
    WcTg[t] = f2bfh(Wc[k * 128 + n]);
  } else if (idx < 36864) {
    const int t = idx - 20480;
    const int n = t >> 7, k = t & 127;
    WdTg[t] = f2bfh(Wd[k * 128 + n]);
  } else if (idx < 102400) {
    const int t = idx - 36864;
    const int n = t >> 9, k = t & 511;
    W1Tg[t] = f2bfh(W1[k * 128 + n]);
  } else {
    const int t = idx - 102400;
    if (t < 768) {
      const int n = t >> 4, k = t & 15;
      WaT2g[t] = (n < 40) ? f2bfh(Wa2[k * 40 + n]) : (u16)0;
    } else if (t < 3840) {
      const int t2 = t - 768;
      const int n = t2 >> 6, k = t2 & 63;
      WbT2g[t2] = (n < 40 && k < 40) ? f2bfh(Wb2[k * 40 + n]) : (u16)0;
    } else if (t < 4608) {
      const int t2 = t - 3840;
      const int n = t2 >> 4, k = t2 & 15;
      WcT2g[t2] = (n < 40) ? f2bfh(Wc2[k * 40 + n]) : (u16)0;
    } else if (t < 7680) {
      const int t2 = t - 4608;
      const int n = t2 >> 6, k = t2 & 63;
      WdT2g[t2] = (n < 40 && k < 40) ? f2bfh(Wd2[k * 40 + n]) : (u16)0;
    } else if (t < 7728) {
      const int t2 = t - 7680;
      bb48[t2] = (t2 < 40) ? bb2[t2] : 0.f;
    } else if (t < 7776) {
      const int t2 = t - 7728;
      bd48[t2] = (t2 < 40) ? bd2[t2] : 0.f;
    } else {
      const int t3 = t - 7776;
      if (t3 < 2 * N) {
        const int r = t3 >> 1, half = t3 & 1;
        const float4 f0 = *reinterpret_cast<const float4*>(&epoi[(size_t)r * 16 + half * 8]);
        const float4 f1 = *reinterpret_cast<const float4*>(&epoi[(size_t)r * 16 + half * 8 + 4]);
        u32 pk[4];
        pk[0] = (u32)f2bfh(f0.x) | ((u32)f2bfh(f0.y) << 16);
        pk[1] = (u32)f2bfh(f0.z) | ((u32)f2bfh(f0.w) << 16);
        pk[2] = (u32)f2bfh(f1.x) | ((u32)f2bfh(f1.y) << 16);
        pk[3] = (u32)f2bfh(f1.z) | ((u32)f2bfh(f1.w) << 16);
        *reinterpret_cast<uint4*>(&epoiP[(size_t)r * 16 + half * 8]) = make_uint4(pk[0], pk[1], pk[2], pk[3]);
      }
    }
  }
}

// ---------------- h1 = x @ W1 via MFMA: [M,512]@[512,128], bf16 ----------------
__global__ __launch_bounds__(256) void k_gemm1m(const float* __restrict__ x,
                                                const u16* __restrict__ WT,  // [128][512]
                                                float* __restrict__ C, int M) {
  const int tid = threadIdx.x;
  const int lane = tid & 63;
  const int w = tid >> 6;
  const int wr = w >> 1, wc = w & 1;
  const int lg = lane >> 4;
  const int lm = lane & 15;
  const int r0 = blockIdx.x * 64;

  const f32x4 z4 = {0.f, 0.f, 0.f, 0.f};
  f32x4 acc[2][4];
#pragma unroll
  for (int i = 0; i < 2; ++i)
#pragma unroll
    for (int j = 0; j < 4; ++j) acc[i][j] = z4;

  auto load_chunk = [&](int ch, s16x8 af[2], s16x8 bf_[4]) {
#pragma unroll
    for (int i = 0; i < 2; ++i) {
      const int row = r0 + (wr * 2 + i) * 16 + lm;
      s16x8 a = (s16x8)0;
      if (row < M) {
        const float4 f0 = *reinterpret_cast<const float4*>(&x[(size_t)row * 512 + ch * 32 + lg * 8]);
        const float4 f1 = *reinterpret_cast<const float4*>(&x[(size_t)row * 512 + ch * 32 + lg * 8 + 4]);
        a[0] = (short)f2bfh(f0.x); a[1] = (short)f2bfh(f0.y);
        a[2] = (short)f2bfh(f0.z); a[3] = (short)f2bfh(f0.w);
        a[4] = (short)f2bfh(f1.x); a[5] = (short)f2bfh(f1.y);
        a[6] = (short)f2bfh(f1.z); a[7] = (short)f2bfh(f1.w);
      }
      af[i] = a;
    }
#pragma unroll
    for (int j = 0; j < 4; ++j) {
      const int n = (wc * 4 + j) * 16 + lm;
      bf_[j] = *reinterpret_cast<const s16x8*>(&WT[(size_t)n * 512 + ch * 32 + lg * 8]);
    }
  };

  s16x8 af[2], bf_[4];
  load_chunk(0, af, bf_);
  for (int ch = 0; ch < 16; ++ch) {
    s16x8 naf[2], nbf[4];
    if (ch < 15) load_chunk(ch + 1, naf, nbf);
#pragma unroll
    for (int i = 0; i < 2; ++i)
#pragma unroll
      for (int j = 0; j < 4; ++j)
        acc[i][j] = __builtin_amdgcn_mfma_f32_16x16x32_bf16(af[i], bf_[j], acc[i][j], 0, 0, 0);
    if (ch < 15) {
#pragma unroll
      for (int i = 0; i < 2; ++i) af[i] = naf[i];
#pragma unroll
      for (int j = 0; j < 4; ++j) bf_[j] = nbf[j];
    }
  }

#pragma unroll
  for (int i = 0; i < 2; ++i) {
#pragma unroll
    for (int rr = 0; rr < 4; ++rr) {
      const int row = r0 + (wr * 2 + i) * 16 + lg * 4 + rr;
      if (row < M) {
#pragma unroll
        for (int j = 0; j < 4; ++j)
          C[(size_t)row * 128 + (wc * 4 + j) * 16 + lm] = acc[i][j][rr];
      }
    }
  }
}

// ------- MFMA fused 16->128->128 MLP over bf16 rows -------
template <int MODE>
__global__ __launch_bounds__(256) void k_emlp(
    const u16* __restrict__ inp,              // [R][16] bf16
    const u16* __restrict__ WaTg, const u16* __restrict__ WbTg,
    const float* __restrict__ bbias,
    u16* __restrict__ outp, int R) {
  __shared__ __align__(16) unsigned char sU[16384];
  const int tid = threadIdx.x;
  const int lane = tid & 63;
  const int wc = tid >> 6;   // 0..3 col quadrant
  const int lg = lane >> 4;
  const int lm = lane & 15;
  const int r0 = blockIdx.x * 64;

  s16x8 afr[4];
#pragma unroll
  for (int i = 0; i < 4; ++i) {
    s16x8 a = (s16x8)0;
    if (lg < 2) {
      const int r = r0 + i * 16 + lm;
      if (r < R) a = *reinterpret_cast<const s16x8*>(&inp[(size_t)r * 16 + lg * 8]);
    }
    afr[i] = a;
  }

  const f32x4 z4 = {0.f, 0.f, 0.f, 0.f};
  s16x8 bfr1[2];
#pragma unroll
  for (int j = 0; j < 2; ++j) {
    s16x8 b = (s16x8)0;
    if (lg < 2) {
      const int n = wc * 32 + j * 16 + lm;
      b = *reinterpret_cast<const s16x8*>(&WaTg[n * 16 + lg * 8]);
    }
    bfr1[j] = b;
  }

  f32x4 acc1[4][2];
#pragma unroll
  for (int i = 0; i < 4; ++i)
#pragma unroll
    for (int j = 0; j < 2; ++j) acc1[i][j] = z4;
#pragma unroll
  for (int i = 0; i < 4; ++i)
#pragma unroll
    for (int j = 0; j < 2; ++j)
      acc1[i][j] = __builtin_amdgcn_mfma_f32_16x16x32_bf16(afr[i], bfr1[j], acc1[i][j], 0, 0, 0);

#pragma unroll
  for (int i = 0; i < 4; ++i) {
#pragma unroll
    for (int j = 0; j < 2; ++j) {
#pragma unroll
      for (int rr = 0; rr < 4; ++rr) {
        float v = acc1[i][j][rr];
        v = (v >= 0.f) ? v : 0.2f * v;
        const int grow = i * 16 + lg * 4 + rr;
        const int gcol = wc * 32 + j * 16 + lm;
        const int byte = grow * 256 + ((((gcol >> 3) ^ (grow & 15))) << 4) + (gcol & 7) * 2;
        *reinterpret_cast<u16*>(&sU[byte]) = f2bfh(v);
      }
    }
  }
  __syncthreads();

  f32x4 acc[4][2];
#pragma unroll
  for (int i = 0; i < 4; ++i)
#pragma unroll
    for (int j = 0; j < 2; ++j) acc[i][j] = z4;
#pragma unroll
  for (int kb = 0; kb < 4; ++kb) {
    s16x8 af[4], bf_[2];
    const int ch = kb * 4 + lg;
#pragma unroll
    for (int j = 0; j < 2; ++j) {
      const int n = wc * 32 + j * 16 + lm;
      bf_[j] = *reinterpret_cast<const s16x8*>(&WbTg[n * 128 + ch * 8]);
    }
#pragma unroll
    for (int i = 0; i < 4; ++i) {
      const int row = i * 16 + lm;
      af[i] = *reinterpret_cast<const s16x8*>(&sU[row * 256 + ((ch ^ (row & 15)) << 4)]);
    }
#pragma unroll
    for (int i = 0; i < 4; ++i)
#pragma unroll
      for (int j = 0; j < 2; ++j)
        acc[i][j] = __builtin_amdgcn_mfma_f32_16x16x32_bf16(af[i], bf_[j], acc[i][j], 0, 0, 0);
  }
  __syncthreads();

  float bv[2];
#pragma unroll
  for (int j = 0; j < 2; ++j) bv[j] = bbias[wc * 32 + j * 16 + lm];
#pragma unroll
  for (int i = 0; i < 4; ++i) {
#pragma unroll
    for (int j = 0; j < 2; ++j) {
#pragma unroll
      for (int rr = 0; rr < 4; ++rr) {
        float v = acc[i][j][rr] + bv[j];
        if (MODE == 0) v = __expf(v);
        else v = (v >= 0.f) ? v : 0.01f * v;
        const int grow = i * 16 + lg * 4 + rr;
        const int gcol = wc * 32 + j * 16 + lm;
        const int byte = grow * 256 + ((((gcol >> 3) ^ (grow & 15))) << 4) + (gcol & 7) * 2;
        *reinterpret_cast<u16*>(&sU[byte]) = f2bfh(v);
      }
    }
  }
  __syncthreads();

  const int rmax = R - r0;
#pragma unroll
  for (int q = 0; q < 4; ++q) {
    const int u = tid + q * 256;
    const int row = u >> 4, c8 = u & 15;
    if (row < rmax) {
      const uint4 v = *reinterpret_cast<const uint4*>(&sU[row * 256 + ((c8 ^ (row & 15)) << 4)]);
      *reinterpret_cast<uint4*>(&outp[(size_t)(r0 + row) * 128 + c8 * 8]) = v;
    }
  }
}

// ------- MFMA fused 16->40->40 MLP (48-padded) over bf16 rows -------
template <int MODE>
__global__ __launch_bounds__(256) void k_emlp48(
    const u16* __restrict__ inp,              // [R][16] bf16
    const u16* __restrict__ WaT,              // [48][16] bf16 (zero-padded n>=40)
    const u16* __restrict__ WbT,              // [48][64] bf16 (zero-padded)
    const float* __restrict__ bias48,         // [48]
    u16* __restrict__ outp, int R) {          // [R][40] bf16
  __shared__ __align__(16) unsigned char sU[16384];
  const int tid = threadIdx.x;
  const int lane = tid & 63;
  const int wv = tid >> 6;   // 0..3 row group (32 rows each)
  const int lg = lane >> 4;
  const int lm = lane & 15;
  const int r0 = blockIdx.x * 128;

  // zero U pad columns 48..63 (disjoint from data cols, no race)
#pragma unroll
  for (int q = 0; q < 4; ++q) {
    const int u = tid + q * 256;
    const int row = u >> 3;
    const int col = 48 + (u & 7) * 2;
    const int byte = row * 128 + ((((col >> 3) ^ (row & 7))) << 4) + (col & 7) * 2;
    *reinterpret_cast<u32*>(&sU[byte]) = 0;
  }

  s16x8 afr[2];
#pragma unroll
  for (int i = 0; i < 2; ++i) {
    s16x8 a = (s16x8)0;
    if (lg < 2) {
      const int r = r0 + wv * 32 + i * 16 + lm;
      if (r < R) a = *reinterpret_cast<const s16x8*>(&inp[(size_t)r * 16 + lg * 8]);
    }
    afr[i] = a;
  }
  const f32x4 z4 = {0.f, 0.f, 0.f, 0.f};
  s16x8 bfr1[3];
#pragma unroll
  for (int j = 0; j < 3; ++j) {
    s16x8 b = (s16x8)0;
    if (lg < 2) {
      const int n = j * 16 + lm;
      b = *reinterpret_cast<const s16x8*>(&WaT[n * 16 + lg * 8]);
    }
    bfr1[j] = b;
  }
  f32x4 acc1[2][3];
#pragma unroll
  for (int i = 0; i < 2; ++i)
#pragma unroll
    for (int j = 0; j < 3; ++j) acc1[i][j] = z4;
#pragma unroll
  for (int i = 0; i < 2; ++i)
#pragma unroll
    for (int j = 0; j < 3; ++j)
      acc1[i][j] = __builtin_amdgcn_mfma_f32_16x16x32_bf16(afr[i], bfr1[j], acc1[i][j], 0, 0, 0);

#pragma unroll
  for (int i = 0; i < 2; ++i) {
#pragma unroll
    for (int j = 0; j < 3; ++j) {
#pragma unroll
      for (int rr = 0; rr < 4; ++rr) {
        float v = acc1[i][j][rr];
        v = (v >= 0.f) ? v : 0.2f * v;
        const int grow = wv * 32 + i * 16 + lg * 4 + rr;
        const int gcol = j * 16 + lm;
        const int byte = grow * 128 + ((((gcol >> 3) ^ (grow & 7))) << 4) + (gcol & 7) * 2;
        *reinterpret_cast<u16*>(&sU[byte]) = f2bfh(v);
      }
    }
  }
  __syncthreads();

  f32x4 acc[2][3];
#pragma unroll
  for (int i = 0; i < 2; ++i)
#pragma unroll
    for (int j = 0; j < 3; ++j) acc[i][j] = z4;
#pragma unroll
  for (int kb = 0; kb < 2; ++kb) {
    s16x8 af[2], bf_[3];
    const int ch = kb * 4 + lg;
#pragma unroll
    for (int j = 0; j < 3; ++j) {
      const int n = j * 16 + lm;
      bf_[j] = *reinterpret_cast<const s16x8*>(&WbT[n * 64 + ch * 8]);
    }
#pragma unroll
    for (int i = 0; i < 2; ++i) {
      const int row = wv * 32 + i * 16 + lm;
      af[i] = *reinterpret_cast<const s16x8*>(&sU[row * 128 + ((ch ^ (row & 7)) << 4)]);
    }
#pragma unroll
    for (int i = 0; i < 2; ++i)
#pragma unroll
      for (int j = 0; j < 3; ++j)
        acc[i][j] = __builtin_amdgcn_mfma_f32_16x16x32_bf16(af[i], bf_[j], acc[i][j], 0, 0, 0);
  }
  __syncthreads();

  float bv[3];
#pragma unroll
  for (int j = 0; j < 3; ++j) bv[j] = bias48[j * 16 + lm];
#pragma unroll
  for (int i = 0; i < 2; ++i) {
#pragma unroll
    for (int j = 0; j < 3; ++j) {
#pragma unroll
      for (int rr = 0; rr < 4; ++rr) {
        float v = acc[i][j][rr] + bv[j];
        if (MODE == 0) v = __expf(v);
        else v = (v >= 0.f) ? v : 0.01f * v;
        const int grow = wv * 32 + i * 16 + lg * 4 + rr;
        const int gcol = j * 16 + lm;
        const int byte = grow * 128 + ((((gcol >> 3) ^ (grow & 7))) << 4) + (gcol & 7) * 2;
        *reinterpret_cast<u16*>(&sU[byte]) = f2bfh(v);
      }
    }
  }
  __syncthreads();

  const int rmax = R - r0;
  const int row = tid >> 1, half = tid & 1;
  if (row < rmax) {
    const size_t obase = (size_t)(r0 + row) * 40;
#pragma unroll
    for (int q = 0; q < 10; ++q) {
      const int col = (half * 10 + q) * 2;
      const int byte = row * 128 + ((((col >> 3) ^ (row & 7))) << 4) + (col & 7) * 2;
      *reinterpret_cast<u32*>(&outp[obase + col]) = *reinterpret_cast<const u32*>(&sU[byte]);
    }
  }
}

// ------------- h2 = y1 @ W2  [M,128]@[128,40] ----------
__global__ __launch_bounds__(256) void k_gemm2(const float* __restrict__ A,
                                               const float* __restrict__ B,
                                               float* __restrict__ C, int M) {
  __shared__ float Bs[128 * 40];
  const int tid = threadIdx.x;
  for (int i = tid; i < 5120; i += 256) Bs[i] = B[i];
  __syncthreads();
  const int r = blockIdx.x * 6 + tid / 40;
  const int c = tid % 40;
  if (tid >= 240 || r >= M) return;
  const float* arow = &A[(size_t)r * 128];
  float acc = 0.f;
#pragma unroll
  for (int k4 = 0; k4 < 32; ++k4) {
    const float4 av = *reinterpret_cast<const float4*>(&arow[k4 * 4]);
    acc = fmaf(av.x, Bs[(k4 * 4 + 0) * 40 + c], acc);
    acc = fmaf(av.y, Bs[(k4 * 4 + 1) * 40 + c], acc);
    acc = fmaf(av.z, Bs[(k4 * 4 + 2) * 40 + c], acc);
    acc = fmaf(av.w, Bs[(k4 * 4 + 3) * 40 + c], acc);
  }
  C[(size_t)r * 40 + c] = acc;
}

// ================= CSR build =================
__global__ __launch_bounds__(256) void k_hist(const int* __restrict__ src,
                                              const int* __restrict__ dst,
                                              int* __restrict__ cnt, int N, int E) {
  const int e = blockIdx.x * 256 + threadIdx.x;
  if (e >= E) return;
  atomicAdd(&cnt[src[e]], 1);
  atomicAdd(&cnt[N + dst[e]], 1);
}

__global__ __launch_bounds__(256) void k_scanA(const int* __restrict__ cnt,
                                               int* __restrict__ bsum, int N, int NB) {
  const int arr = blockIdx.x / NB, bb = blockIdx.x % NB;
  const int g = bb * 256 + threadIdx.x;
  int v = (g < N) ? cnt[arr * N + g] : 0;
  __shared__ int sd[256];
  sd[threadIdx.x] = v;
  __syncthreads();
  for (int off = 128; off > 0; off >>= 1) {
    if (threadIdx.x < off) sd[threadIdx.x] += sd[threadIdx.x + off];
    __syncthreads();
  }
  if (threadIdx.x == 0) bsum[arr * 256 + bb] = sd[0];
}

__global__ __launch_bounds__(256) void k_scanB(const int* __restrict__ bsum,
                                               int* __restrict__ boff, int NB) {
  __shared__ int sd[256];
  for (int arr = 0; arr < 2; ++arr) {
    const int v = (threadIdx.x < NB) ? bsum[arr * 256 + threadIdx.x] : 0;
    sd[threadIdx.x] = v;
    __syncthreads();
    for (int off = 1; off < 256; off <<= 1) {
      const int t = (threadIdx.x >= off) ? sd[threadIdx.x - off] : 0;
      __syncthreads();
      sd[threadIdx.x] += t;
      __syncthreads();
    }
    if (threadIdx.x < NB) boff[arr * 256 + threadIdx.x] = sd[threadIdx.x] - v;
    __syncthreads();
  }
}

__global__ __launch_bounds__(256) void k_scanC(const int* __restrict__ cnt,
                                               const int* __restrict__ boff,
                                               int* __restrict__ row_src,
                                               int* __restrict__ row_dst,
                                               int* __restrict__ cur, int N, int NB) {
  const int arr = blockIdx.x / NB, bb = blockIdx.x % NB;
  const int g = bb * 256 + threadIdx.x;
  const int v = (g < N) ? cnt[arr * N + g] : 0;
  __shared__ int sd[256];
  sd[threadIdx.x] = v;
  __syncthreads();
  for (int off = 1; off < 256; off <<= 1) {
    const int t = (threadIdx.x >= off) ? sd[threadIdx.x - off] : 0;
    __syncthreads();
    sd[threadIdx.x] += t;
    __syncthreads();
  }
  const int incl = sd[threadIdx.x];
  const int base = boff[arr * 256 + bb];
  int* row = arr ? row_dst : row_src;
  if (g < N) {
    row[g] = base + incl - v;
    cur[arr * N + g] = base + incl - v;
    if (g == N - 1) row[N] = base + incl;
  }
}

// per-edge: ps = src-order position, pd = dst-order position.
__global__ __launch_bounds__(256) void k_scatter(const int* __restrict__ src,
                                                 const int* __restrict__ dst,
                                                 int* __restrict__ cur,
                                                 const float* __restrict__ kric,
                                                 u16* __restrict__ kricP,
                                                 uint2* __restrict__ pdInfo, int N, int E) {
  const int e = blockIdx.x * 256 + threadIdx.x;
  if (e >= E) return;
  const int s = src[e], d = dst[e];
  const float4 f0 = *reinterpret_cast<const float4*>(&kric[(size_t)e * 16]);
  const float4 f1 = *reinterpret_cast<const float4*>(&kric[(size_t)e * 16 + 4]);
  const float4 f2 = *reinterpret_cast<const float4*>(&kric[(size_t)e * 16 + 8]);
  const float4 f3 = *reinterpret_cast<const float4*>(&kric[(size_t)e * 16 + 12]);
  const int ps = atomicAdd(&cur[s], 1);
  const int pd = atomicAdd(&cur[N + d], 1);
  pdInfo[pd] = make_uint2((u32)ps, (u32)s);
  u32 pk[8];
  pk[0] = (u32)f2bfh(f0.x) | ((u32)f2bfh(f0.y) << 16);
  pk[1] = (u32)f2bfh(f0.z) | ((u32)f2bfh(f0.w) << 16);
  pk[2] = (u32)f2bfh(f1.x) | ((u32)f2bfh(f1.y) << 16);
  pk[3] = (u32)f2bfh(f1.z) | ((u32)f2bfh(f1.w) << 16);
  pk[4] = (u32)f2bfh(f2.x) | ((u32)f2bfh(f2.y) << 16);
  pk[5] = (u32)f2bfh(f2.z) | ((u32)f2bfh(f2.w) << 16);
  pk[6] = (u32)f2bfh(f3.x) | ((u32)f2bfh(f3.y) << 16);
  pk[7] = (u32)f2bfh(f3.z) | ((u32)f2bfh(f3.w) << 16);
  u16* outr = &kricP[(size_t)ps * 16];
  *reinterpret_cast<uint4*>(outr) = make_uint4(pk[0], pk[1], pk[2], pk[3]);
  *reinterpret_cast<uint4*>(outr + 8) = make_uint4(pk[4], pk[5], pk[6], pk[7]);
}

// ===== s = segsum(ew rows [r0,r1)), gB = bf16(h/(s+eps)) =====
template <int C>
__global__ __launch_bounds__(256) void k_norm(const int* __restrict__ rowp,
                                              const u16* __restrict__ ew,
                                              const float* __restrict__ h,
                                              u16* __restrict__ gB, int N) {
  const int lane = threadIdx.x & 63;
  const int wv = threadIdx.x >> 6;
  const int n = blockIdx.x * 4 + wv;
  if (n >= N) return;
  constexpr int CPL = (C == 128) ? 2 : 1;
  const int c0 = lane * CPL;
  if (c0 >= C) return;
  const int r0 = rowp[n], r1 = rowp[n + 1];
  float a0 = 0.f, a1 = 0.f;
  int p = r0;
  if (CPL == 2) {
    for (; p + 2 <= r1; p += 2) {
      const u32 w0 = *reinterpret_cast<const u32*>(&ew[(size_t)p * C + c0]);
      const u32 w1 = *reinterpret_cast<const u32*>(&ew[(size_t)(p + 1) * C + c0]);
      a0 += bf2f((u16)(w0 & 0xffffu)) + bf2f((u16)(w1 & 0xffffu));
      a1 += bf2f((u16)(w0 >> 16)) + bf2f((u16)(w1 >> 16));
    }
    for (; p < r1; ++p) {
      const u32 w0 = *reinterpret_cast<const u32*>(&ew[(size_t)p * C + c0]);
      a0 += bf2f((u16)(w0 & 0xffffu));
      a1 += bf2f((u16)(w0 >> 16));
    }
    const float2 hv = *reinterpret_cast<const float2*>(&h[(size_t)n * C + c0]);
    const float gx = hv.x / (a0 + SM_EPS);
    const float gy = hv.y / (a1 + SM_EPS);
    *reinterpret_cast<u32*>(&gB[(size_t)n * C + c0]) = (u32)f2bfh(gx) | ((u32)f2bfh(gy) << 16);
  } else {
    for (; p + 2 <= r1; p += 2)
      a0 += bf2f(ew[(size_t)p * C + c0]) + bf2f(ew[(size_t)(p + 1) * C + c0]);
    for (; p < r1; ++p) a0 += bf2f(ew[(size_t)p * C + c0]);
    gB[(size_t)n * C + c0] = f2bfh(h[(size_t)n * C + c0] / (a0 + SM_EPS));
  }
}

// ===== out[n] = sum_{in-edges} ew[pd.x] * gB[pd.y] + b + alpha*pw(bf16), opt ELU =====
template <int C, int DO_ELU>
__global__ __launch_bounds__(256) void k_aggf(const int* __restrict__ rowp,
                                              const uint2* __restrict__ pdInfo,
                                              const u16* __restrict__ ew,
                                              const u16* __restrict__ gB,
                                              const u16* __restrict__ pw,
                                              const float* __restrict__ bias,
                                              const float* __restrict__ alpha_p,
                                              float* __restrict__ out, int N) {
  const int lane = threadIdx.x & 63;
  const int wv = threadIdx.x >> 6;
  const int n = blockIdx.x * 4 + wv;
  if (n >= N) return;
  constexpr int CPL = (C == 128) ? 2 : 1;
  const int c0 = lane * CPL;
  if (c0 >= C) return;
  const int r0 = rowp[n], r1 = rowp[n + 1];
  float a0 = 0.f, a1 = 0.f;
  int p = r0;
  if (CPL == 2) {
    for (; p + 8 <= r1; p += 8) {
      uint2 ii[8];
      u32 ww[8];
      u32 gg[8];
#pragma unroll
      for (int t = 0; t < 8; ++t) ii[t] = pdInfo[p + t];
#pragma unroll
      for (int t = 0; t < 8; ++t) ww[t] = *reinterpret_cast<const u32*>(&ew[(size_t)ii[t].x * C + c0]);
#pragma unroll
      for (int t = 0; t < 8; ++t) gg[t] = *reinterpret_cast<const u32*>(&gB[(size_t)ii[t].y * C + c0]);
#pragma unroll
      for (int t = 0; t < 8; ++t) {
        a0 = fmaf(bf2f((u16)(ww[t] & 0xffffu)), bf2f((u16)(gg[t] & 0xffffu)), a0);
        a1 = fmaf(bf2f((u16)(ww[t] >> 16)), bf2f((u16)(gg[t] >> 16)), a1);
      }
    }
    for (; p + 4 <= r1; p += 4) {
      const uint2 i0 = pdInfo[p + 0], i1 = pdInfo[p + 1], i2 = pdInfo[p + 2], i3 = pdInfo[p + 3];
      const u32 w0 = *reinterpret_cast<const u32*>(&ew[(size_t)i0.x * C + c0]);
      const u32 w1 = *reinterpret_cast<const u32*>(&ew[(size_t)i1.x * C + c0]);
      const u32 w2 = *reinterpret_cast<const u32*>(&ew[(size_t)i2.x * C + c0]);
      const u32 w3 = *reinterpret_cast<const u32*>(&ew[(size_t)i3.x * C + c0]);
      const u32 g0 = *reinterpret_cast<const u32*>(&gB[(size_t)i0.y * C + c0]);
      const u32 g1 = *reinterpret_cast<const u32*>(&gB[(size_t)i1.y * C + c0]);
      const u32 g2 = *reinterpret_cast<const u32*>(&gB[(size_t)i2.y * C + c0]);
      const u32 g3 = *reinterpret_cast<const u32*>(&gB[(size_t)i3.y * C + c0]);
      a0 = fmaf(bf2f((u16)(w0 & 0xffffu)), bf2f((u16)(g0 & 0xffffu)), a0);
      a1 = fmaf(bf2f((u16)(w0 >> 16)), bf2f((u16)(g0 >> 16)), a1);
      a0 = fmaf(bf2f((u16)(w1 & 0xffffu)), bf2f((u16)(g1 & 0xffffu)), a0);
      a1 = fmaf(bf2f((u16)(w1 >> 16)), bf2f((u16)(g1 >> 16)), a1);
      a0 = fmaf(bf2f((u16)(w2 & 0xffffu)), bf2f((u16)(g2 & 0xffffu)), a0);
      a1 = fmaf(bf2f((u16)(w2 >> 16)), bf2f((u16)(g2 >> 16)), a1);
      a0 = fmaf(bf2f((u16)(w3 & 0xffffu)), bf2f((u16)(g3 & 0xffffu)), a0);
      a1 = fmaf(bf2f((u16)(w3 >> 16)), bf2f((u16)(g3 >> 16)), a1);
    }
    for (; p < r1; ++p) {
      const uint2 i0 = pdInfo[p];
      const u32 w0 = *reinterpret_cast<const u32*>(&ew[(size_t)i0.x * C + c0]);
      const u32 g0 = *reinterpret_cast<const u32*>(&gB[(size_t)i0.y * C + c0]);
      a0 = fmaf(bf2f((u16)(w0 & 0xffffu)), bf2f((u16)(g0 & 0xffffu)), a0);
      a1 = fmaf(bf2f((u16)(w0 >> 16)), bf2f((u16)(g0 >> 16)), a1);
    }
    const float al = alpha_p[0];
    const u32 pv2 = *reinterpret_cast<const u32*>(&pw[(size_t)n * C + c0]);
    float v0 = a0 + bias[c0] + al * bf2f((u16)(pv2 & 0xffffu));
    float v1 = a1 + bias[c0 + 1] + al * bf2f((u16)(pv2 >> 16));
    if (DO_ELU) {
      v0 = (v0 > 0.f) ? v0 : expm1f(v0);
      v1 = (v1 > 0.f) ? v1 : expm1f(v1);
    }
    *reinterpret_cast<float2*>(&out[(size_t)n * C + c0]) = make_float2(v0, v1);
  } else {
    for (; p + 4 <= r1; p += 4) {
      const uint2 i0 = pdInfo[p + 0], i1 = pdInfo[p + 1], i2 = pdInfo[p + 2], i3 = pdInfo[p + 3];
      const float w0 = bf2f(ew[(size_t)i0.x * C + c0]);
      const float w1 = bf2f(ew[(size_t)i1.x * C + c0]);
      const float w2 = bf2f(ew[(size_t)i2.x * C + c0]);
      const float w3 = bf2f(ew[(size_t)i3.x * C + c0]);
      const float g0 = bf2f(gB[(size_t)i0.y * C + c0]);
      const float g1 = bf2f(gB[(size_t)i1.y * C + c0]);
      const float g2 = bf2f(gB[(size_t)i2.y * C + c0]);
      const float g3 = bf2f(gB[(size_t)i3.y * C + c0]);
      a0 = fmaf(w0, g0, a0);
      a0 = fmaf(w1, g1, a0);
      a0 = fmaf(w2, g2, a0);
      a0 = fmaf(w3, g3, a0);
    }
    for (; p < r1; ++p) {
      const uint2 i0 = pdInfo[p];
      a0 = fmaf(bf2f(ew[(size_t)i0.x * C + c0]), bf2f(gB[(size_t)i0.y * C + c0]), a0);
    }
    float v = a0 + bias[c0] + alpha_p[0] * bf2f(pw[(size_t)n * C + c0]);
    if (DO_ELU) v = (v > 0.f) ? v : expm1f(v);
    out[(size_t)n * C + c0] = v;
  }
}

extern "C" void kernel_launch(void* const* d_in, const int* in_sizes, int n_in,
                              void* d_out, int out_size, void* d_ws, size_t ws_size,
                              hipStream_t stream) {
  const float* x    = (const float*)d_in[0];
  const int*   ei   = (const int*)d_in[1];
  const float* kric = (const float*)d_in[2];
  const float* epoi = (const float*)d_in[3];
  const float* alpha= (const float*)d_in[4];
  const float* W1   = (const float*)d_in[5];
  const float* Wa1  = (const float*)d_in[6];
  const float* Wb1  = (const float*)d_in[7];
  const float* bb1  = (const float*)d_in[8];
  const float* Wc1  = (const float*)d_in[9];
  const float* Wd1  = (const float*)d_in[10];
  const float* bd1  = (const float*)d_in[11];
  const float* b1   = (const float*)d_in[12];
  const float* W2   = (const float*)d_in[13];
  const float* Wa2  = (const float*)d_in[14];
  const float* Wb2  = (const float*)d_in[15];
  const float* bb2  = (const float*)d_in[16];
  const float* Wc2  = (const float*)d_in[17];
  const float* Wd2  = (const float*)d_in[18];
  const float* bd2  = (const float*)d_in[19];
  const float* b2   = (const float*)d_in[20];

  const int N = in_sizes[0] / 512;
  const int E = in_sizes[1] / 2;
  const int* srcI = ei;
  const int* dstI = ei + E;
  const int NB = (N + 255) / 256;

  // ---- workspace layout ----
  char* p = (char*)d_ws;
  int* cnt      = (int*)p; p += (size_t)2 * N * 4;
  int* cur      = (int*)p; p += (size_t)2 * N * 4;
  int* bsum     = (int*)p; p += 512 * 4;
  int* boff     = (int*)p; p += 512 * 4;
  int* row_src  = (int*)p; p += (size_t)(N + 1) * 4;
  int* row_dst  = (int*)p; p += (size_t)(N + 1) * 4;
  p = (char*)(((uintptr_t)p + 255) & ~(uintptr_t)255);
  uint2* pdInfo = (uint2*)p; p += (size_t)E * 8;
  p = (char*)(((uintptr_t)p + 255) & ~(uintptr_t)255);
  u16* WaT1g = (u16*)p; p += 2048 * 2;
  u16* WbT1g = (u16*)p; p += 16384 * 2;
  u16* WcT1g = (u16*)p; p += 2048 * 2;
  u16* WdT1g = (u16*)p; p += 16384 * 2;
  u16* W1Tg  = (u16*)p; p += 65536 * 2;
  u16* WaT2g = (u16*)p; p += 768 * 2;
  u16* WbT2g = (u16*)p; p += 3072 * 2;
  u16* WcT2g = (u16*)p; p += 768 * 2;
  u16* WdT2g = (u16*)p; p += 3072 * 2;
  p = (char*)(((uintptr_t)p + 255) & ~(uintptr_t)255);
  float* bb48 = (float*)p; p += 48 * 4;
  float* bd48 = (float*)p; p += 48 * 4;
  p = (char*)(((uintptr_t)p + 255) & ~(uintptr_t)255);
  u16* kricP = (u16*)p; p += (size_t)E * 16 * 2;   // bf16, src-CSR order
  u16* epoiP = (u16*)p; p += (size_t)N * 16 * 2;   // bf16
  p = (char*)(((uintptr_t)p + 255) & ~(uintptr_t)255);
  float* h1  = (float*)p; p += (size_t)N * 128 * 4;
  u16* g1B   = (u16*)p;  p += (size_t)N * 128 * 2;   // bf16 normalized h1
  float* y1  = (float*)p; p += (size_t)N * 128 * 4;
  float* h2  = (float*)p; p += (size_t)N * 40 * 4;
  u16* g2B   = (u16*)p;  p += (size_t)N * 40 * 2;    // bf16 normalized h2
  u16* pw1   = (u16*)p;  p += (size_t)N * 128 * 2;   // bf16
  u16* pw2   = (u16*)p;  p += (size_t)N * 40 * 2;    // bf16
  p = (char*)(((uintptr_t)p + 255) & ~(uintptr_t)255);
  u16* ew    = (u16*)p;  // E*128 bf16 (layer 1), reused E*40 (layer 2); src-CSR order

  // ---- CSR build + weight/input prep ----
  hipMemsetAsync(cnt, 0, (size_t)2 * N * 4, stream);
  k_prep<<<(110176 + 2 * N + 255) / 256, 256, 0, stream>>>(
      Wa1, Wb1, Wc1, Wd1, W1, Wa2, Wb2, Wc2, Wd2, bb2, bd2, epoi,
      WaT1g, WbT1g, WcT1g, WdT1g, W1Tg, WaT2g, WbT2g, WcT2g, WdT2g, bb48, bd48, epoiP, N);
  k_hist<<<(E + 255) / 256, 256, 0, stream>>>(srcI, dstI, cnt, N, E);
  k_scanA<<<2 * NB, 256, 0, stream>>>(cnt, bsum, N, NB);
  k_scanB<<<1, 256, 0, stream>>>(bsum, boff, NB);
  k_scanC<<<2 * NB, 256, 0, stream>>>(cnt, boff, row_src, row_dst, cur, N, NB);
  k_scatter<<<(E + 255) / 256, 256, 0, stream>>>(srcI, dstI, cur, kric, kricP, pdInfo, N, E);

  // ---------------- layer 1 ----------------
  k_gemm1m<<<(N + 63) / 64, 256, 0, stream>>>(x, W1Tg, h1, N);
  k_emlp<0><<<(E + 63) / 64, 256, 0, stream>>>(kricP, WaT1g, WbT1g, bb1, ew, E);
  k_emlp<1><<<(N + 63) / 64, 256, 0, stream>>>(epoiP, WcT1g, WdT1g, bd1, pw1, N);
  k_norm<128><<<(N + 3) / 4, 256, 0, stream>>>(row_src, ew, h1, g1B, N);
  k_aggf<128, 1><<<(N + 3) / 4, 256, 0, stream>>>(row_dst, pdInfo, ew, g1B, pw1, b1, alpha, y1, N);

  // ---------------- layer 2 ----------------
  k_gemm2<<<(N + 5) / 6, 256, 0, stream>>>(y1, W2, h2, N);
  k_emlp48<0><<<(E + 127) / 128, 256, 0, stream>>>(kricP, WaT2g, WbT2g, bb48, ew, E);
  k_emlp48<1><<<(N + 127) / 128, 256, 0, stream>>>(epoiP, WcT2g, WdT2g, bd48, pw2, N);
  k_norm<40><<<(N + 3) / 4, 256, 0, stream>>>(row_src, ew, h2, g2B, N);
  k_aggf<40, 0><<<(N + 3) / 4, 256, 0, stream>>>(row_dst, pdInfo, ew, g2B, pw2, b2, alpha, (float*)d_out, N);
}

// Round 15
// 576.066 us; speedup vs baseline: 12.2992x; 1.0657x over previous
//
#include <hip/hip_runtime.h>
#include <math.h>

#define SM_EPS 1e-16f

typedef unsigned short u16;
typedef unsigned int u32;
typedef unsigned char u8;
typedef short s16x8 __attribute__((ext_vector_type(8)));
typedef float f32x4 __attribute__((ext_vector_type(4)));

__device__ __forceinline__ u16 f2bfh(float x) {
  __bf16 b = (__bf16)x;
  return __builtin_bit_cast(unsigned short, b);
}
__device__ __forceinline__ float bf2f(u16 u) {
  return __uint_as_float(((u32)u) << 16);
}
// e4m3 for POSITIVE in-range values only (ew = exp(logit) in [0.3, 3])
__device__ __forceinline__ u32 f2e4m3(float v) {
  const u32 b = __float_as_uint(v);
  const u32 m = b - 0x3C000000u;
  return (m + 0x7FFFFu + ((m >> 20) & 1u)) >> 20;  // RNE
}
__device__ __forceinline__ float e4m32f(u32 q) {
  return __uint_as_float(((q & 0x7Fu) << 20) + 0x3C000000u);
}

// -------- weight + epoi prep (once per call) --------
__global__ __launch_bounds__(256) void k_prep(const float* __restrict__ Wa,
                                              const float* __restrict__ Wb,
                                              const float* __restrict__ Wc,
                                              const float* __restrict__ Wd,
                                              const float* __restrict__ W1,
                                              const float* __restrict__ Wa2,
                                              const float* __restrict__ Wb2,
                                              const float* __restrict__ Wc2,
                                              const float* __restrict__ Wd2,
                                              const float* __restrict__ bb2,
                                              const float* __restrict__ bd2,
                                              const float* __restrict__ epoi,
                                              u16* __restrict__ WaTg, u16* __restrict__ WbTg,
                                              u16* __restrict__ WcTg, u16* __restrict__ WdTg,
                                              u16* __restrict__ W1Tg,
                                              u16* __restrict__ WaT2g, u16* __restrict__ WbT2g,
                                              u16* __restrict__ WcT2g, u16* __restrict__ WdT2g,
                                              float* __restrict__ bb48, float* __restrict__ bd48,
                                              u16* __restrict__ epoiP,
                                              int N) {
  const int idx = blockIdx.x * 256 + threadIdx.x;
  if (idx < 2048) {
    const int n = idx >> 4, k = idx & 15;
    WaTg[idx] = f2bfh(Wa[k * 128 + n]);
  } else if (idx < 18432) {
    const int t = idx - 2048;
    const int n = t >> 7, k = t & 127;
    WbTg[t] = f2bfh(Wb[k * 128 + n]);
  } else if (idx < 20480) {
    const int t = idx - 18432;
    const int n = t >> 4, k = t & 15;
    WcTg[t] = f2bfh(Wc[k * 128 + n]);
  } else if (idx < 36864) {
    const int t = idx - 20480;
    const int n = t >> 7, k = t & 127;
    WdTg[t] = f2bfh(Wd[k * 128 + n]);
  } else if (idx < 102400) {
    const int t = idx - 36864;
    const int n = t >> 9, k = t & 511;
    W1Tg[t] = f2bfh(W1[k * 128 + n]);
  } else {
    const int t = idx - 102400;
    if (t < 768) {
      const int n = t >> 4, k = t & 15;
      WaT2g[t] = (n < 40) ? f2bfh(Wa2[k * 40 + n]) : (u16)0;
    } else if (t < 3840) {
      const int t2 = t - 768;
      const int n = t2 >> 6, k = t2 & 63;
      WbT2g[t2] = (n < 40 && k < 40) ? f2bfh(Wb2[k * 40 + n]) : (u16)0;
    } else if (t < 4608) {
      const int t2 = t - 3840;
      const int n = t2 >> 4, k = t2 & 15;
      WcT2g[t2] = (n < 40) ? f2bfh(Wc2[k * 40 + n]) : (u16)0;
    } else if (t < 7680) {
      const int t2 = t - 4608;
      const int n = t2 >> 6, k = t2 & 63;
      WdT2g[t2] = (n < 40 && k < 40) ? f2bfh(Wd2[k * 40 + n]) : (u16)0;
    } else if (t < 7728) {
      const int t2 = t - 7680;
      bb48[t2] = (t2 < 40) ? bb2[t2] : 0.f;
    } else if (t < 7776) {
      const int t2 = t - 7728;
      bd48[t2] = (t2 < 40) ? bd2[t2] : 0.f;
    } else {
      const int t3 = t - 7776;
      if (t3 < 2 * N) {
        const int r = t3 >> 1, half = t3 & 1;
        const float4 f0 = *reinterpret_cast<const float4*>(&epoi[(size_t)r * 16 + half * 8]);
        const float4 f1 = *reinterpret_cast<const float4*>(&epoi[(size_t)r * 16 + half * 8 + 4]);
        u32 pk[4];
        pk[0] = (u32)f2bfh(f0.x) | ((u32)f2bfh(f0.y) << 16);
        pk[1] = (u32)f2bfh(f0.z) | ((u32)f2bfh(f0.w) << 16);
        pk[2] = (u32)f2bfh(f1.x) | ((u32)f2bfh(f1.y) << 16);
        pk[3] = (u32)f2bfh(f1.z) | ((u32)f2bfh(f1.w) << 16);
        *reinterpret_cast<uint4*>(&epoiP[(size_t)r * 16 + half * 8]) = make_uint4(pk[0], pk[1], pk[2], pk[3]);
      }
    }
  }
}

// ---------------- h1 = x @ W1 via MFMA: [M,512]@[512,128], bf16 ----------------
__global__ __launch_bounds__(256) void k_gemm1m(const float* __restrict__ x,
                                                const u16* __restrict__ WT,  // [128][512]
                                                float* __restrict__ C, int M) {
  const int tid = threadIdx.x;
  const int lane = tid & 63;
  const int w = tid >> 6;
  const int wr = w >> 1, wc = w & 1;
  const int lg = lane >> 4;
  const int lm = lane & 15;
  const int r0 = blockIdx.x * 64;

  const f32x4 z4 = {0.f, 0.f, 0.f, 0.f};
  f32x4 acc[2][4];
#pragma unroll
  for (int i = 0; i < 2; ++i)
#pragma unroll
    for (int j = 0; j < 4; ++j) acc[i][j] = z4;

  auto load_chunk = [&](int ch, s16x8 af[2], s16x8 bf_[4]) {
#pragma unroll
    for (int i = 0; i < 2; ++i) {
      const int row = r0 + (wr * 2 + i) * 16 + lm;
      s16x8 a = (s16x8)0;
      if (row < M) {
        const float4 f0 = *reinterpret_cast<const float4*>(&x[(size_t)row * 512 + ch * 32 + lg * 8]);
        const float4 f1 = *reinterpret_cast<const float4*>(&x[(size_t)row * 512 + ch * 32 + lg * 8 + 4]);
        a[0] = (short)f2bfh(f0.x); a[1] = (short)f2bfh(f0.y);
        a[2] = (short)f2bfh(f0.z); a[3] = (short)f2bfh(f0.w);
        a[4] = (short)f2bfh(f1.x); a[5] = (short)f2bfh(f1.y);
        a[6] = (short)f2bfh(f1.z); a[7] = (short)f2bfh(f1.w);
      }
      af[i] = a;
    }
#pragma unroll
    for (int j = 0; j < 4; ++j) {
      const int n = (wc * 4 + j) * 16 + lm;
      bf_[j] = *reinterpret_cast<const s16x8*>(&WT[(size_t)n * 512 + ch * 32 + lg * 8]);
    }
  };

  s16x8 af[2], bf_[4];
  load_chunk(0, af, bf_);
  for (int ch = 0; ch < 16; ++ch) {
    s16x8 naf[2], nbf[4];
    if (ch < 15) load_chunk(ch + 1, naf, nbf);
#pragma unroll
    for (int i = 0; i < 2; ++i)
#pragma unroll
      for (int j = 0; j < 4; ++j)
        acc[i][j] = __builtin_amdgcn_mfma_f32_16x16x32_bf16(af[i], bf_[j], acc[i][j], 0, 0, 0);
    if (ch < 15) {
#pragma unroll
      for (int i = 0; i < 2; ++i) af[i] = naf[i];
#pragma unroll
      for (int j = 0; j < 4; ++j) bf_[j] = nbf[j];
    }
  }

#pragma unroll
  for (int i = 0; i < 2; ++i) {
#pragma unroll
    for (int rr = 0; rr < 4; ++rr) {
      const int row = r0 + (wr * 2 + i) * 16 + lg * 4 + rr;
      if (row < M) {
#pragma unroll
        for (int j = 0; j < 4; ++j)
          C[(size_t)row * 128 + (wc * 4 + j) * 16 + lm] = acc[i][j][rr];
      }
    }
  }
}

// ------- MFMA fused 16->128->128 MLP over bf16 rows -------
// 64 rows/block, 4 waves = 4 col-quadrants. 16KB LDS.
// MODE 0: exp -> fp8 e4m3 out (ew).  MODE 1: lrelu(0.01) -> bf16 out (pw).
template <int MODE>
__global__ __launch_bounds__(256) void k_emlp(
    const u16* __restrict__ inp,              // [R][16] bf16
    const u16* __restrict__ WaTg, const u16* __restrict__ WbTg,
    const float* __restrict__ bbias,
    void* __restrict__ outp, int R) {
  __shared__ __align__(16) unsigned char sU[16384];
  const int tid = threadIdx.x;
  const int lane = tid & 63;
  const int wc = tid >> 6;   // 0..3 col quadrant
  const int lg = lane >> 4;
  const int lm = lane & 15;
  const int r0 = blockIdx.x * 64;

  s16x8 afr[4];
#pragma unroll
  for (int i = 0; i < 4; ++i) {
    s16x8 a = (s16x8)0;
    if (lg < 2) {
      const int r = r0 + i * 16 + lm;
      if (r < R) a = *reinterpret_cast<const s16x8*>(&inp[(size_t)r * 16 + lg * 8]);
    }
    afr[i] = a;
  }

  const f32x4 z4 = {0.f, 0.f, 0.f, 0.f};
  s16x8 bfr1[2];
#pragma unroll
  for (int j = 0; j < 2; ++j) {
    s16x8 b = (s16x8)0;
    if (lg < 2) {
      const int n = wc * 32 + j * 16 + lm;
      b = *reinterpret_cast<const s16x8*>(&WaTg[n * 16 + lg * 8]);
    }
    bfr1[j] = b;
  }

  f32x4 acc1[4][2];
#pragma unroll
  for (int i = 0; i < 4; ++i)
#pragma unroll
    for (int j = 0; j < 2; ++j) acc1[i][j] = z4;
#pragma unroll
  for (int i = 0; i < 4; ++i)
#pragma unroll
    for (int j = 0; j < 2; ++j)
      acc1[i][j] = __builtin_amdgcn_mfma_f32_16x16x32_bf16(afr[i], bfr1[j], acc1[i][j], 0, 0, 0);

#pragma unroll
  for (int i = 0; i < 4; ++i) {
#pragma unroll
    for (int j = 0; j < 2; ++j) {
#pragma unroll
      for (int rr = 0; rr < 4; ++rr) {
        float v = acc1[i][j][rr];
        v = (v >= 0.f) ? v : 0.2f * v;
        const int grow = i * 16 + lg * 4 + rr;
        const int gcol = wc * 32 + j * 16 + lm;
        const int byte = grow * 256 + ((((gcol >> 3) ^ (grow & 15))) << 4) + (gcol & 7) * 2;
        *reinterpret_cast<u16*>(&sU[byte]) = f2bfh(v);
      }
    }
  }
  __syncthreads();

  f32x4 acc[4][2];
#pragma unroll
  for (int i = 0; i < 4; ++i)
#pragma unroll
    for (int j = 0; j < 2; ++j) acc[i][j] = z4;
#pragma unroll
  for (int kb = 0; kb < 4; ++kb) {
    s16x8 af[4], bf_[2];
    const int ch = kb * 4 + lg;
#pragma unroll
    for (int j = 0; j < 2; ++j) {
      const int n = wc * 32 + j * 16 + lm;
      bf_[j] = *reinterpret_cast<const s16x8*>(&WbTg[n * 128 + ch * 8]);
    }
#pragma unroll
    for (int i = 0; i < 4; ++i) {
      const int row = i * 16 + lm;
      af[i] = *reinterpret_cast<const s16x8*>(&sU[row * 256 + ((ch ^ (row & 15)) << 4)]);
    }
#pragma unroll
    for (int i = 0; i < 4; ++i)
#pragma unroll
      for (int j = 0; j < 2; ++j)
        acc[i][j] = __builtin_amdgcn_mfma_f32_16x16x32_bf16(af[i], bf_[j], acc[i][j], 0, 0, 0);
  }
  __syncthreads();

  float bv[2];
#pragma unroll
  for (int j = 0; j < 2; ++j) bv[j] = bbias[wc * 32 + j * 16 + lm];

  if (MODE == 0) {
    // fp8 epilogue: byte = row*128 + (c ^ (((row>>2)&3)<<2))
#pragma unroll
    for (int i = 0; i < 4; ++i) {
#pragma unroll
      for (int j = 0; j < 2; ++j) {
#pragma unroll
        for (int rr = 0; rr < 4; ++rr) {
          const float v = __expf(acc[i][j][rr] + bv[j]);
          const int grow = i * 16 + lg * 4 + rr;
          const int gcol = wc * 32 + j * 16 + lm;
          const int byte = grow * 128 + (gcol ^ (((grow >> 2) & 3) << 2));
          sU[byte] = (u8)f2e4m3(v);
        }
      }
    }
    __syncthreads();
    u8* o8 = (u8*)outp;
    const int rmax = R - r0;
#pragma unroll
    for (int q = 0; q < 8; ++q) {
      const int u = tid + q * 256;
      const int row = u >> 5, c4s = u & 31;
      if (row < rmax) {
        const u32 v = *reinterpret_cast<const u32*>(&sU[row * 128 + c4s * 4]);
        const int c4 = c4s ^ ((row >> 2) & 3);
        *reinterpret_cast<u32*>(&o8[(size_t)(r0 + row) * 128 + c4 * 4]) = v;
      }
    }
  } else {
#pragma unroll
    for (int i = 0; i < 4; ++i) {
#pragma unroll
      for (int j = 0; j < 2; ++j) {
#pragma unroll
        for (int rr = 0; rr < 4; ++rr) {
          float v = acc[i][j][rr] + bv[j];
          v = (v >= 0.f) ? v : 0.01f * v;
          const int grow = i * 16 + lg * 4 + rr;
          const int gcol = wc * 32 + j * 16 + lm;
          const int byte = grow * 256 + ((((gcol >> 3) ^ (grow & 15))) << 4) + (gcol & 7) * 2;
          *reinterpret_cast<u16*>(&sU[byte]) = f2bfh(v);
        }
      }
    }
    __syncthreads();
    u16* o16 = (u16*)outp;
    const int rmax = R - r0;
#pragma unroll
    for (int q = 0; q < 4; ++q) {
      const int u = tid + q * 256;
      const int row = u >> 4, c8 = u & 15;
      if (row < rmax) {
        const uint4 v = *reinterpret_cast<const uint4*>(&sU[row * 256 + ((c8 ^ (row & 15)) << 4)]);
        *reinterpret_cast<uint4*>(&o16[(size_t)(r0 + row) * 128 + c8 * 8]) = v;
      }
    }
  }
}

// ------- MFMA fused 16->40->40 MLP (48-padded), bf16 out -------
template <int MODE>
__global__ __launch_bounds__(256) void k_emlp48(
    const u16* __restrict__ inp,              // [R][16] bf16
    const u16* __restrict__ WaT,              // [48][16]
    const u16* __restrict__ WbT,              // [48][64]
    const float* __restrict__ bias48,         // [48]
    u16* __restrict__ outp, int R) {          // [R][40] bf16
  __shared__ __align__(16) unsigned char sU[16384];
  const int tid = threadIdx.x;
  const int lane = tid & 63;
  const int wv = tid >> 6;
  const int lg = lane >> 4;
  const int lm = lane & 15;
  const int r0 = blockIdx.x * 128;

#pragma unroll
  for (int q = 0; q < 4; ++q) {
    const int u = tid + q * 256;
    const int row = u >> 3;
    const int col = 48 + (u & 7) * 2;
    const int byte = row * 128 + ((((col >> 3) ^ (row & 7))) << 4) + (col & 7) * 2;
    *reinterpret_cast<u32*>(&sU[byte]) = 0;
  }

  s16x8 afr[2];
#pragma unroll
  for (int i = 0; i < 2; ++i) {
    s16x8 a = (s16x8)0;
    if (lg < 2) {
      const int r = r0 + wv * 32 + i * 16 + lm;
      if (r < R) a = *reinterpret_cast<const s16x8*>(&inp[(size_t)r * 16 + lg * 8]);
    }
    afr[i] = a;
  }
  const f32x4 z4 = {0.f, 0.f, 0.f, 0.f};
  s16x8 bfr1[3];
#pragma unroll
  for (int j = 0; j < 3; ++j) {
    s16x8 b = (s16x8)0;
    if (lg < 2) {
      const int n = j * 16 + lm;
      b = *reinterpret_cast<const s16x8*>(&WaT[n * 16 + lg * 8]);
    }
    bfr1[j] = b;
  }
  f32x4 acc1[2][3];
#pragma unroll
  for (int i = 0; i < 2; ++i)
#pragma unroll
    for (int j = 0; j < 3; ++j) acc1[i][j] = z4;
#pragma unroll
  for (int i = 0; i < 2; ++i)
#pragma unroll
    for (int j = 0; j < 3; ++j)
      acc1[i][j] = __builtin_amdgcn_mfma_f32_16x16x32_bf16(afr[i], bfr1[j], acc1[i][j], 0, 0, 0);

#pragma unroll
  for (int i = 0; i < 2; ++i) {
#pragma unroll
    for (int j = 0; j < 3; ++j) {
#pragma unroll
      for (int rr = 0; rr < 4; ++rr) {
        float v = acc1[i][j][rr];
        v = (v >= 0.f) ? v : 0.2f * v;
        const int grow = wv * 32 + i * 16 + lg * 4 + rr;
        const int gcol = j * 16 + lm;
        const int byte = grow * 128 + ((((gcol >> 3) ^ (grow & 7))) << 4) + (gcol & 7) * 2;
        *reinterpret_cast<u16*>(&sU[byte]) = f2bfh(v);
      }
    }
  }
  __syncthreads();

  f32x4 acc[2][3];
#pragma unroll
  for (int i = 0; i < 2; ++i)
#pragma unroll
    for (int j = 0; j < 3; ++j) acc[i][j] = z4;
#pragma unroll
  for (int kb = 0; kb < 2; ++kb) {
    s16x8 af[2], bf_[3];
    const int ch = kb * 4 + lg;
#pragma unroll
    for (int j = 0; j < 3; ++j) {
      const int n = j * 16 + lm;
      bf_[j] = *reinterpret_cast<const s16x8*>(&WbT[n * 64 + ch * 8]);
    }
#pragma unroll
    for (int i = 0; i < 2; ++i) {
      const int row = wv * 32 + i * 16 + lm;
      af[i] = *reinterpret_cast<const s16x8*>(&sU[row * 128 + ((ch ^ (row & 7)) << 4)]);
    }
#pragma unroll
    for (int i = 0; i < 2; ++i)
#pragma unroll
      for (int j = 0; j < 3; ++j)
        acc[i][j] = __builtin_amdgcn_mfma_f32_16x16x32_bf16(af[i], bf_[j], acc[i][j], 0, 0, 0);
  }
  __syncthreads();

  float bv[3];
#pragma unroll
  for (int j = 0; j < 3; ++j) bv[j] = bias48[j * 16 + lm];
#pragma unroll
  for (int i = 0; i < 2; ++i) {
#pragma unroll
    for (int j = 0; j < 3; ++j) {
#pragma unroll
      for (int rr = 0; rr < 4; ++rr) {
        float v = acc[i][j][rr] + bv[j];
        if (MODE == 0) v = __expf(v);
        else v = (v >= 0.f) ? v : 0.01f * v;
        const int grow = wv * 32 + i * 16 + lg * 4 + rr;
        const int gcol = j * 16 + lm;
        const int byte = grow * 128 + ((((gcol >> 3) ^ (grow & 7))) << 4) + (gcol & 7) * 2;
        *reinterpret_cast<u16*>(&sU[byte]) = f2bfh(v);
      }
    }
  }
  __syncthreads();

  const int rmax = R - r0;
  const int row = tid >> 1, half = tid & 1;
  if (row < rmax) {
    const size_t obase = (size_t)(r0 + row) * 40;
#pragma unroll
    for (int q = 0; q < 10; ++q) {
      const int col = (half * 10 + q) * 2;
      const int byte = row * 128 + ((((col >> 3) ^ (row & 7))) << 4) + (col & 7) * 2;
      *reinterpret_cast<u32*>(&outp[obase + col]) = *reinterpret_cast<const u32*>(&sU[byte]);
    }
  }
}

// ------------- h2 = y1 @ W2  [M,128]@[128,40] ----------
__global__ __launch_bounds__(256) void k_gemm2(const float* __restrict__ A,
                                               const float* __restrict__ B,
                                               float* __restrict__ C, int M) {
  __shared__ float Bs[128 * 40];
  const int tid = threadIdx.x;
  for (int i = tid; i < 5120; i += 256) Bs[i] = B[i];
  __syncthreads();
  const int r = blockIdx.x * 6 + tid / 40;
  const int c = tid % 40;
  if (tid >= 240 || r >= M) return;
  const float* arow = &A[(size_t)r * 128];
  float acc = 0.f;
#pragma unroll
  for (int k4 = 0; k4 < 32; ++k4) {
    const float4 av = *reinterpret_cast<const float4*>(&arow[k4 * 4]);
    acc = fmaf(av.x, Bs[(k4 * 4 + 0) * 40 + c], acc);
    acc = fmaf(av.y, Bs[(k4 * 4 + 1) * 40 + c], acc);
    acc = fmaf(av.z, Bs[(k4 * 4 + 2) * 40 + c], acc);
    acc = fmaf(av.w, Bs[(k4 * 4 + 3) * 40 + c], acc);
  }
  C[(size_t)r * 40 + c] = acc;
}

// ================= CSR build =================
__global__ __launch_bounds__(256) void k_hist(const int* __restrict__ src,
                                              const int* __restrict__ dst,
                                              int* __restrict__ cnt, int N, int E) {
  const int e = blockIdx.x * 256 + threadIdx.x;
  if (e >= E) return;
  atomicAdd(&cnt[src[e]], 1);
  atomicAdd(&cnt[N + dst[e]], 1);
}

__global__ __launch_bounds__(256) void k_scanA(const int* __restrict__ cnt,
                                               int* __restrict__ bsum, int N, int NB) {
  const int arr = blockIdx.x / NB, bb = blockIdx.x % NB;
  const int g = bb * 256 + threadIdx.x;
  int v = (g < N) ? cnt[arr * N + g] : 0;
  __shared__ int sd[256];
  sd[threadIdx.x] = v;
  __syncthreads();
  for (int off = 128; off > 0; off >>= 1) {
    if (threadIdx.x < off) sd[threadIdx.x] += sd[threadIdx.x + off];
    __syncthreads();
  }
  if (threadIdx.x == 0) bsum[arr * 256 + bb] = sd[0];
}

__global__ __launch_bounds__(256) void k_scanB(const int* __restrict__ bsum,
                                               int* __restrict__ boff, int NB) {
  __shared__ int sd[256];
  for (int arr = 0; arr < 2; ++arr) {
    const int v = (threadIdx.x < NB) ? bsum[arr * 256 + threadIdx.x] : 0;
    sd[threadIdx.x] = v;
    __syncthreads();
    for (int off = 1; off < 256; off <<= 1) {
      const int t = (threadIdx.x >= off) ? sd[threadIdx.x - off] : 0;
      __syncthreads();
      sd[threadIdx.x] += t;
      __syncthreads();
    }
    if (threadIdx.x < NB) boff[arr * 256 + threadIdx.x] = sd[threadIdx.x] - v;
    __syncthreads();
  }
}

__global__ __launch_bounds__(256) void k_scanC(const int* __restrict__ cnt,
                                               const int* __restrict__ boff,
                                               int* __restrict__ row_src,
                                               int* __restrict__ row_dst,
                                               int* __restrict__ cur, int N, int NB) {
  const int arr = blockIdx.x / NB, bb = blockIdx.x % NB;
  const int g = bb * 256 + threadIdx.x;
  const int v = (g < N) ? cnt[arr * N + g] : 0;
  __shared__ int sd[256];
  sd[threadIdx.x] = v;
  __syncthreads();
  for (int off = 1; off < 256; off <<= 1) {
    const int t = (threadIdx.x >= off) ? sd[threadIdx.x - off] : 0;
    __syncthreads();
    sd[threadIdx.x] += t;
    __syncthreads();
  }
  const int incl = sd[threadIdx.x];
  const int base = boff[arr * 256 + bb];
  int* row = arr ? row_dst : row_src;
  if (g < N) {
    row[g] = base + incl - v;
    cur[arr * N + g] = base + incl - v;
    if (g == N - 1) row[N] = base + incl;
  }
}

// per-edge: ps = src-order position, pd = dst-order position.
__global__ __launch_bounds__(256) void k_scatter(const int* __restrict__ src,
                                                 const int* __restrict__ dst,
                                                 int* __restrict__ cur,
                                                 const float* __restrict__ kric,
                                                 u16* __restrict__ kricP,
                                                 uint2* __restrict__ pdInfo, int N, int E) {
  const int e = blockIdx.x * 256 + threadIdx.x;
  if (e >= E) return;
  const int s = src[e], d = dst[e];
  const float4 f0 = *reinterpret_cast<const float4*>(&kric[(size_t)e * 16]);
  const float4 f1 = *reinterpret_cast<const float4*>(&kric[(size_t)e * 16 + 4]);
  const float4 f2 = *reinterpret_cast<const float4*>(&kric[(size_t)e * 16 + 8]);
  const float4 f3 = *reinterpret_cast<const float4*>(&kric[(size_t)e * 16 + 12]);
  const int ps = atomicAdd(&cur[s], 1);
  const int pd = atomicAdd(&cur[N + d], 1);
  pdInfo[pd] = make_uint2((u32)ps, (u32)s);
  u32 pk[8];
  pk[0] = (u32)f2bfh(f0.x) | ((u32)f2bfh(f0.y) << 16);
  pk[1] = (u32)f2bfh(f0.z) | ((u32)f2bfh(f0.w) << 16);
  pk[2] = (u32)f2bfh(f1.x) | ((u32)f2bfh(f1.y) << 16);
  pk[3] = (u32)f2bfh(f1.z) | ((u32)f2bfh(f1.w) << 16);
  pk[4] = (u32)f2bfh(f2.x) | ((u32)f2bfh(f2.y) << 16);
  pk[5] = (u32)f2bfh(f2.z) | ((u32)f2bfh(f2.w) << 16);
  pk[6] = (u32)f2bfh(f3.x) | ((u32)f2bfh(f3.y) << 16);
  pk[7] = (u32)f2bfh(f3.z) | ((u32)f2bfh(f3.w) << 16);
  u16* outr = &kricP[(size_t)ps * 16];
  *reinterpret_cast<uint4*>(outr) = make_uint4(pk[0], pk[1], pk[2], pk[3]);
  *reinterpret_cast<uint4*>(outr + 8) = make_uint4(pk[4], pk[5], pk[6], pk[7]);
}

// ===== layer1: s = segsum(fp8 ew rows [r0,r1)), gB = bf16(h/(s+eps)) =====
__global__ __launch_bounds__(256) void k_norm128f8(const int* __restrict__ rowp,
                                                   const u8* __restrict__ ew8,
                                                   const float* __restrict__ h,
                                                   u16* __restrict__ gB, int N) {
  const int lane = threadIdx.x & 63;
  const int wv = threadIdx.x >> 6;
  const int n = blockIdx.x * 4 + wv;
  if (n >= N) return;
  const int c0 = lane * 2;
  const int r0 = rowp[n], r1 = rowp[n + 1];
  float a0 = 0.f, a1 = 0.f;
  int p = r0;
  for (; p + 2 <= r1; p += 2) {
    const u32 w0 = *reinterpret_cast<const u16*>(&ew8[(size_t)p * 128 + c0]);
    const u32 w1 = *reinterpret_cast<const u16*>(&ew8[(size_t)(p + 1) * 128 + c0]);
    a0 += e4m32f(w0 & 0xffu) + e4m32f(w1 & 0xffu);
    a1 += e4m32f(w0 >> 8) + e4m32f(w1 >> 8);
  }
  for (; p < r1; ++p) {
    const u32 w0 = *reinterpret_cast<const u16*>(&ew8[(size_t)p * 128 + c0]);
    a0 += e4m32f(w0 & 0xffu);
    a1 += e4m32f(w0 >> 8);
  }
  const float2 hv = *reinterpret_cast<const float2*>(&h[(size_t)n * 128 + c0]);
  const float gx = hv.x / (a0 + SM_EPS);
  const float gy = hv.y / (a1 + SM_EPS);
  *reinterpret_cast<u32*>(&gB[(size_t)n * 128 + c0]) = (u32)f2bfh(gx) | ((u32)f2bfh(gy) << 16);
}

// ===== layer1 agg: out = sum ew8[pd.x]*gB[pd.y] + b + alpha*pw, ELU =====
__global__ __launch_bounds__(256) void k_aggf128f8(const int* __restrict__ rowp,
                                                   const uint2* __restrict__ pdInfo,
                                                   const u8* __restrict__ ew8,
                                                   const u16* __restrict__ gB,
                                                   const u16* __restrict__ pw,
                                                   const float* __restrict__ bias,
                                                   const float* __restrict__ alpha_p,
                                                   float* __restrict__ out, int N) {
  const int lane = threadIdx.x & 63;
  const int wv = threadIdx.x >> 6;
  const int n = blockIdx.x * 4 + wv;
  if (n >= N) return;
  const int c0 = lane * 2;
  const int r0 = rowp[n], r1 = rowp[n + 1];
  float a0 = 0.f, a1 = 0.f;
  int p = r0;
  for (; p + 8 <= r1; p += 8) {
    uint2 ii[8];
    u32 ww[8];
    u32 gg[8];
#pragma unroll
    for (int t = 0; t < 8; ++t) ii[t] = pdInfo[p + t];
#pragma unroll
    for (int t = 0; t < 8; ++t) ww[t] = *reinterpret_cast<const u16*>(&ew8[(size_t)ii[t].x * 128 + c0]);
#pragma unroll
    for (int t = 0; t < 8; ++t) gg[t] = *reinterpret_cast<const u32*>(&gB[(size_t)ii[t].y * 128 + c0]);
#pragma unroll
    for (int t = 0; t < 8; ++t) {
      a0 = fmaf(e4m32f(ww[t] & 0xffu), bf2f((u16)(gg[t] & 0xffffu)), a0);
      a1 = fmaf(e4m32f(ww[t] >> 8), bf2f((u16)(gg[t] >> 16)), a1);
    }
  }
  for (; p < r1; ++p) {
    const uint2 i0 = pdInfo[p];
    const u32 w0 = *reinterpret_cast<const u16*>(&ew8[(size_t)i0.x * 128 + c0]);
    const u32 g0 = *reinterpret_cast<const u32*>(&gB[(size_t)i0.y * 128 + c0]);
    a0 = fmaf(e4m32f(w0 & 0xffu), bf2f((u16)(g0 & 0xffffu)), a0);
    a1 = fmaf(e4m32f(w0 >> 8), bf2f((u16)(g0 >> 16)), a1);
  }
  const float al = alpha_p[0];
  const u32 pv2 = *reinterpret_cast<const u32*>(&pw[(size_t)n * 128 + c0]);
  float v0 = a0 + bias[c0] + al * bf2f((u16)(pv2 & 0xffffu));
  float v1 = a1 + bias[c0 + 1] + al * bf2f((u16)(pv2 >> 16));
  v0 = (v0 > 0.f) ? v0 : expm1f(v0);
  v1 = (v1 > 0.f) ? v1 : expm1f(v1);
  *reinterpret_cast<float2*>(&out[(size_t)n * 128 + c0]) = make_float2(v0, v1);
}

// ===== layer2 (bf16 ew, C=40): s = segsum, gB = bf16(h/(s+eps)) =====
__global__ __launch_bounds__(256) void k_norm40(const int* __restrict__ rowp,
                                                const u16* __restrict__ ew,
                                                const float* __restrict__ h,
                                                u16* __restrict__ gB, int N) {
  const int lane = threadIdx.x & 63;
  const int wv = threadIdx.x >> 6;
  const int n = blockIdx.x * 4 + wv;
  if (n >= N) return;
  const int c0 = lane;
  if (c0 >= 40) return;
  const int r0 = rowp[n], r1 = rowp[n + 1];
  float a0 = 0.f;
  int p = r0;
  for (; p + 2 <= r1; p += 2)
    a0 += bf2f(ew[(size_t)p * 40 + c0]) + bf2f(ew[(size_t)(p + 1) * 40 + c0]);
  for (; p < r1; ++p) a0 += bf2f(ew[(size_t)p * 40 + c0]);
  gB[(size_t)n * 40 + c0] = f2bfh(h[(size_t)n * 40 + c0] / (a0 + SM_EPS));
}

__global__ __launch_bounds__(256) void k_aggf40(const int* __restrict__ rowp,
                                                const uint2* __restrict__ pdInfo,
                                                const u16* __restrict__ ew,
                                                const u16* __restrict__ gB,
                                                const u16* __restrict__ pw,
                                                const float* __restrict__ bias,
                                                const float* __restrict__ alpha_p,
                                                float* __restrict__ out, int N) {
  const int lane = threadIdx.x & 63;
  const int wv = threadIdx.x >> 6;
  const int n = blockIdx.x * 4 + wv;
  if (n >= N) return;
  const int c0 = lane;
  if (c0 >= 40) return;
  const int r0 = rowp[n], r1 = rowp[n + 1];
  float a0 = 0.f;
  int p = r0;
  for (; p + 4 <= r1; p += 4) {
    const uint2 i0 = pdInfo[p + 0], i1 = pdInfo[p + 1], i2 = pdInfo[p + 2], i3 = pdInfo[p + 3];
    const float w0 = bf2f(ew[(size_t)i0.x * 40 + c0]);
    const float w1 = bf2f(ew[(size_t)i1.x * 40 + c0]);
    const float w2 = bf2f(ew[(size_t)i2.x * 40 + c0]);
    const float w3 = bf2f(ew[(size_t)i3.x * 40 + c0]);
    const float g0 = bf2f(gB[(size_t)i0.y * 40 + c0]);
    const float g1 = bf2f(gB[(size_t)i1.y * 40 + c0]);
    const float g2 = bf2f(gB[(size_t)i2.y * 40 + c0]);
    const float g3 = bf2f(gB[(size_t)i3.y * 40 + c0]);
    a0 = fmaf(w0, g0, a0);
    a0 = fmaf(w1, g1, a0);
    a0 = fmaf(w2, g2, a0);
    a0 = fmaf(w3, g3, a0);
  }
  for (; p < r1; ++p) {
    const uint2 i0 = pdInfo[p];
    a0 = fmaf(bf2f(ew[(size_t)i0.x * 40 + c0]), bf2f(gB[(size_t)i0.y * 40 + c0]), a0);
  }
  const float v = a0 + bias[c0] + alpha_p[0] * bf2f(pw[(size_t)n * 40 + c0]);
  out[(size_t)n * 40 + c0] = v;
}

extern "C" void kernel_launch(void* const* d_in, const int* in_sizes, int n_in,
                              void* d_out, int out_size, void* d_ws, size_t ws_size,
                              hipStream_t stream) {
  const float* x    = (const float*)d_in[0];
  const int*   ei   = (const int*)d_in[1];
  const float* kric = (const float*)d_in[2];
  const float* epoi = (const float*)d_in[3];
  const float* alpha= (const float*)d_in[4];
  const float* W1   = (const float*)d_in[5];
  const float* Wa1  = (const float*)d_in[6];
  const float* Wb1  = (const float*)d_in[7];
  const float* bb1  = (const float*)d_in[8];
  const float* Wc1  = (const float*)d_in[9];
  const float* Wd1  = (const float*)d_in[10];
  const float* bd1  = (const float*)d_in[11];
  const float* b1   = (const float*)d_in[12];
  const float* W2   = (const float*)d_in[13];
  const float* Wa2  = (const float*)d_in[14];
  const float* Wb2  = (const float*)d_in[15];
  const float* bb2  = (const float*)d_in[16];
  const float* Wc2  = (const float*)d_in[17];
  const float* Wd2  = (const float*)d_in[18];
  const float* bd2  = (const float*)d_in[19];
  const float* b2   = (const float*)d_in[20];

  const int N = in_sizes[0] / 512;
  const int E = in_sizes[1] / 2;
  const int* srcI = ei;
  const int* dstI = ei + E;
  const int NB = (N + 255) / 256;

  // ---- workspace layout ----
  char* p = (char*)d_ws;
  int* cnt      = (int*)p; p += (size_t)2 * N * 4;
  int* cur      = (int*)p; p += (size_t)2 * N * 4;
  int* bsum     = (int*)p; p += 512 * 4;
  int* boff     = (int*)p; p += 512 * 4;
  int* row_src  = (int*)p; p += (size_t)(N + 1) * 4;
  int* row_dst  = (int*)p; p += (size_t)(N + 1) * 4;
  p = (char*)(((uintptr_t)p + 255) & ~(uintptr_t)255);
  uint2* pdInfo = (uint2*)p; p += (size_t)E * 8;
  p = (char*)(((uintptr_t)p + 255) & ~(uintptr_t)255);
  u16* WaT1g = (u16*)p; p += 2048 * 2;
  u16* WbT1g = (u16*)p; p += 16384 * 2;
  u16* WcT1g = (u16*)p; p += 2048 * 2;
  u16* WdT1g = (u16*)p; p += 16384 * 2;
  u16* W1Tg  = (u16*)p; p += 65536 * 2;
  u16* WaT2g = (u16*)p; p += 768 * 2;
  u16* WbT2g = (u16*)p; p += 3072 * 2;
  u16* WcT2g = (u16*)p; p += 768 * 2;
  u16* WdT2g = (u16*)p; p += 3072 * 2;
  p = (char*)(((uintptr_t)p + 255) & ~(uintptr_t)255);
  float* bb48 = (float*)p; p += 48 * 4;
  float* bd48 = (float*)p; p += 48 * 4;
  p = (char*)(((uintptr_t)p + 255) & ~(uintptr_t)255);
  u16* kricP = (u16*)p; p += (size_t)E * 16 * 2;   // bf16, src-CSR order
  u16* epoiP = (u16*)p; p += (size_t)N * 16 * 2;   // bf16
  p = (char*)(((uintptr_t)p + 255) & ~(uintptr_t)255);
  float* h1  = (float*)p; p += (size_t)N * 128 * 4;
  u16* g1B   = (u16*)p;  p += (size_t)N * 128 * 2;   // bf16 normalized h1
  float* y1  = (float*)p; p += (size_t)N * 128 * 4;
  float* h2  = (float*)p; p += (size_t)N * 40 * 4;
  u16* g2B   = (u16*)p;  p += (size_t)N * 40 * 2;    // bf16 normalized h2
  u16* pw1   = (u16*)p;  p += (size_t)N * 128 * 2;   // bf16
  u16* pw2   = (u16*)p;  p += (size_t)N * 40 * 2;    // bf16
  p = (char*)(((uintptr_t)p + 255) & ~(uintptr_t)255);
  u8* ew8    = (u8*)p;   // layer1: E*128 fp8; layer2 reuses as E*40 bf16
  u16* ew40  = (u16*)p;

  // ---- CSR build + weight/input prep ----
  hipMemsetAsync(cnt, 0, (size_t)2 * N * 4, stream);
  k_prep<<<(110176 + 2 * N + 255) / 256, 256, 0, stream>>>(
      Wa1, Wb1, Wc1, Wd1, W1, Wa2, Wb2, Wc2, Wd2, bb2, bd2, epoi,
      WaT1g, WbT1g, WcT1g, WdT1g, W1Tg, WaT2g, WbT2g, WcT2g, WdT2g, bb48, bd48, epoiP, N);
  k_hist<<<(E + 255) / 256, 256, 0, stream>>>(srcI, dstI, cnt, N, E);
  k_scanA<<<2 * NB, 256, 0, stream>>>(cnt, bsum, N, NB);
  k_scanB<<<1, 256, 0, stream>>>(bsum, boff, NB);
  k_scanC<<<2 * NB, 256, 0, stream>>>(cnt, boff, row_src, row_dst, cur, N, NB);
  k_scatter<<<(E + 255) / 256, 256, 0, stream>>>(srcI, dstI, cur, kric, kricP, pdInfo, N, E);

  // ---------------- layer 1 ----------------
  k_gemm1m<<<(N + 63) / 64, 256, 0, stream>>>(x, W1Tg, h1, N);
  k_emlp<0><<<(E + 63) / 64, 256, 0, stream>>>(kricP, WaT1g, WbT1g, bb1, (void*)ew8, E);
  k_emlp<1><<<(N + 63) / 64, 256, 0, stream>>>(epoiP, WcT1g, WdT1g, bd1, (void*)pw1, N);
  k_norm128f8<<<(N + 3) / 4, 256, 0, stream>>>(row_src, ew8, h1, g1B, N);
  k_aggf128f8<<<(N + 3) / 4, 256, 0, stream>>>(row_dst, pdInfo, ew8, g1B, pw1, b1, alpha, y1, N);

  // ---------------- layer 2 ----------------
  k_gemm2<<<(N + 5) / 6, 256, 0, stream>>>(y1, W2, h2, N);
  k_emlp48<0><<<(E + 127) / 128, 256, 0, stream>>>(kricP, WaT2g, WbT2g, bb48, ew40, E);
  k_emlp48<1><<<(N + 127) / 128, 256, 0, stream>>>(epoiP, WcT2g, WdT2g, bd48, pw2, N);
  k_norm40<<<(N + 3) / 4, 256, 0, stream>>>(row_src, ew40, h2, g2B, N);
  k_aggf40<<<(N + 3) / 4, 256, 0, stream>>>(row_dst, pdInfo, ew40, g2B, pw2, b2, alpha, (float*)d_out, N);
}